// Round 1
// baseline (520.114 us; speedup 1.0000x reference)
//
#include <hip/hip_runtime.h>
#include <hip/hip_bf16.h>
#include <math.h>

#define N_NODES 50000
#define N_EDGES 800000
#define IN_DIM  256
#define HID     32
#define HEADS   8
#define NCLS    40
#define NEG     0.2f

__device__ __forceinline__ float leaky(float x) { return x >= 0.f ? x : NEG * x; }

// ---------------- GEMM1: feat1[M,256] = x[M,256] @ W1[256,256] ----------------
__global__ __launch_bounds__(256) void gemm1_k(const float* __restrict__ A,
                                               const float* __restrict__ B,
                                               float* __restrict__ C, int M) {
    __shared__ float As[64][17];   // [row][k], padded to kill bank conflicts
    __shared__ float Bs[16][64];
    int tx = threadIdx.x & 15, ty = threadIdx.x >> 4;
    int m0 = blockIdx.x * 64, n0 = blockIdx.y * 64;
    float acc[4][4] = {};
    for (int k0 = 0; k0 < 256; k0 += 16) {
        {   // A tile 64x16, one float4 per thread
            int l = threadIdx.x * 4;
            int r = l >> 4, c = l & 15;
            int m = m0 + r;
            float4 v = make_float4(0.f, 0.f, 0.f, 0.f);
            if (m < M) v = *reinterpret_cast<const float4*>(&A[m * 256 + k0 + c]);
            As[r][c] = v.x; As[r][c + 1] = v.y; As[r][c + 2] = v.z; As[r][c + 3] = v.w;
        }
        {   // B tile 16x64
            int l = threadIdx.x * 4;
            int r = l >> 6, c = l & 63;
            float4 v = *reinterpret_cast<const float4*>(&B[(k0 + r) * 256 + n0 + c]);
            *reinterpret_cast<float4*>(&Bs[r][c]) = v;
        }
        __syncthreads();
#pragma unroll
        for (int kk = 0; kk < 16; ++kk) {
            float a[4], b[4];
#pragma unroll
            for (int i = 0; i < 4; i++) a[i] = As[ty * 4 + i][kk];
#pragma unroll
            for (int j = 0; j < 4; j++) b[j] = Bs[kk][tx * 4 + j];
#pragma unroll
            for (int i = 0; i < 4; i++)
#pragma unroll
                for (int j = 0; j < 4; j++) acc[i][j] += a[i] * b[j];
        }
        __syncthreads();
    }
    for (int i = 0; i < 4; i++) {
        int m = m0 + ty * 4 + i;
        if (m < M) {
#pragma unroll
            for (int j = 0; j < 4; j++) C[m * 256 + n0 + tx * 4 + j] = acc[i][j];
        }
    }
}

// ---------------- GEMM2: feat2[M,40] = h1[M,256] @ W2[256,40] ----------------
__global__ __launch_bounds__(256) void gemm2_k(const float* __restrict__ A,
                                               const float* __restrict__ B,
                                               float* __restrict__ C, int M) {
    __shared__ float As[32][65];   // [k][row]
    __shared__ float Bs[32][40];
    int t = threadIdx.x;
    int row = t & 63, cg = t >> 6;   // 4 col groups x 10 cols
    int m0 = blockIdx.x * 64;
    float acc[10] = {};
    for (int k0 = 0; k0 < 256; k0 += 32) {
#pragma unroll
        for (int i = 0; i < 2; i++) {
            int l = (t * 2 + i) * 4;
            int r = l >> 5, c = l & 31;
            int m = m0 + r;
            float4 v = make_float4(0.f, 0.f, 0.f, 0.f);
            if (m < M) v = *reinterpret_cast<const float4*>(&A[m * 256 + k0 + c]);
            As[c][r] = v.x; As[c + 1][r] = v.y; As[c + 2][r] = v.z; As[c + 3][r] = v.w;
        }
        for (int l = t; l < 32 * 40; l += 256) {
            int r = l / 40, c = l - r * 40;
            Bs[r][c] = B[(k0 + r) * 40 + c];
        }
        __syncthreads();
#pragma unroll
        for (int kk = 0; kk < 32; kk++) {
            float a = As[kk][row];
#pragma unroll
            for (int j = 0; j < 10; j++) acc[j] += a * Bs[kk][cg * 10 + j];
        }
        __syncthreads();
    }
    int m = m0 + row;
    if (m < M) {
#pragma unroll
        for (int j = 0; j < 10; j++) C[m * 40 + cg * 10 + j] = acc[j];
    }
}

// ---------------- el/er for layer 1 ----------------
__global__ void elr1_k(const float* __restrict__ feat, const float* __restrict__ al,
                       const float* __restrict__ ar, float* __restrict__ el,
                       float* __restrict__ er) {
    int idx = blockIdx.x * blockDim.x + threadIdx.x;   // n*8+h
    if (idx >= N_NODES * HEADS) return;
    int h = idx & 7;
    const float* f = feat + (size_t)(idx >> 3) * 256 + h * 32;
    const float* a = al + h * 32;
    const float* b = ar + h * 32;
    float sl = 0.f, sr = 0.f;
#pragma unroll
    for (int d = 0; d < 32; d += 4) {
        float4 v  = *reinterpret_cast<const float4*>(f + d);
        float4 va = *reinterpret_cast<const float4*>(a + d);
        float4 vb = *reinterpret_cast<const float4*>(b + d);
        sl += v.x * va.x + v.y * va.y + v.z * va.z + v.w * va.w;
        sr += v.x * vb.x + v.y * vb.y + v.z * vb.z + v.w * vb.w;
    }
    el[idx] = sl; er[idx] = sr;
}

// ---------------- el/er for layer 2 ----------------
__global__ void elr2_k(const float* __restrict__ feat, const float* __restrict__ al,
                       const float* __restrict__ ar, float* __restrict__ el,
                       float* __restrict__ er) {
    int n = blockIdx.x * blockDim.x + threadIdx.x;
    if (n >= N_NODES) return;
    const float* f = feat + (size_t)n * 40;
    float sl = 0.f, sr = 0.f;
    for (int c = 0; c < 40; c++) { float v = f[c]; sl += v * al[c]; sr += v * ar[c]; }
    el[n] = sl; er[n] = sr;
}

// ---------------- CSR build: histogram, scan, scatter ----------------
__global__ void hist_k(const int* __restrict__ dst, int* __restrict__ deg) {
    int e = blockIdx.x * blockDim.x + threadIdx.x;
    if (e < N_EDGES) atomicAdd(&deg[dst[e]], 1);
}

__global__ void scan1_k(const int* __restrict__ deg, int* __restrict__ offs,
                        int* __restrict__ bsum, int n) {
    __shared__ int s[256];
    int tid = threadIdx.x;
    int i = blockIdx.x * 256 + tid;
    int v = (i < n) ? deg[i] : 0;
    s[tid] = v;
    __syncthreads();
    for (int d = 1; d < 256; d <<= 1) {
        int t = (tid >= d) ? s[tid - d] : 0;
        __syncthreads();
        s[tid] += t;
        __syncthreads();
    }
    if (i < n) offs[i] = s[tid] - v;          // exclusive, partial
    if (tid == 255) bsum[blockIdx.x] = s[255];
}

__global__ void scan2_k(int* __restrict__ bsum, int nb) {
    __shared__ int s[256];
    int tid = threadIdx.x;
    int v = (tid < nb) ? bsum[tid] : 0;
    s[tid] = v;
    __syncthreads();
    for (int d = 1; d < 256; d <<= 1) {
        int t = (tid >= d) ? s[tid - d] : 0;
        __syncthreads();
        s[tid] += t;
        __syncthreads();
    }
    if (tid < nb) bsum[tid] = s[tid] - v;     // exclusive
}

__global__ void scan3_k(int* __restrict__ offs, const int* __restrict__ bsum, int n) {
    int i = blockIdx.x * 256 + threadIdx.x;
    if (i < n) offs[i] += bsum[blockIdx.x];
    if (i == 0) offs[n] = N_EDGES;
}

__global__ void scatter_k(const int* __restrict__ src, const int* __restrict__ dst,
                          const int* __restrict__ offs, int* __restrict__ cur,
                          int* __restrict__ ssorted) {
    int e = blockIdx.x * blockDim.x + threadIdx.x;
    if (e < N_EDGES) {
        int d = dst[e];
        int p = atomicAdd(&cur[d], 1);
        ssorted[offs[d] + p] = src[e];
    }
}

// ---------------- layer-1 attention aggregate: 1 wave per dst node ----------------
__global__ __launch_bounds__(256) void agg1_k(const float* __restrict__ feat,
                                              const float* __restrict__ el,
                                              const float* __restrict__ er,
                                              const int* __restrict__ offs,
                                              const int* __restrict__ ssorted,
                                              float* __restrict__ h1) {
    int wid = (blockIdx.x * blockDim.x + threadIdx.x) >> 6;
    int lane = threadIdx.x & 63;
    if (wid >= N_NODES) return;
    int n = wid;
    int beg = offs[n], end = offs[n + 1];

    float er_nl = (lane < 8) ? er[n * 8 + lane] : 0.f;
    float er_h = __shfl(er_nl, lane & 7);
    int h = lane & 7;

    // phase 1: emax per head (lane = edge_slot*8 + head)
    float m = -INFINITY;
    for (int i = beg + (lane >> 3); i < end; i += 8) {
        int s = ssorted[i];
        m = fmaxf(m, leaky(el[s * 8 + h] + er_h));
    }
    m = fmaxf(m, __shfl_xor(m, 8));
    m = fmaxf(m, __shfl_xor(m, 16));
    m = fmaxf(m, __shfl_xor(m, 32));

    // phase 2: denom per head
    float ssum = 0.f;
    for (int i = beg + (lane >> 3); i < end; i += 8) {
        int s = ssorted[i];
        ssum += __expf(leaky(el[s * 8 + h] + er_h) - m);
    }
    ssum += __shfl_xor(ssum, 8);
    ssum += __shfl_xor(ssum, 16);
    ssum += __shfl_xor(ssum, 32);
    float inv = 1.f / ssum;   // valid per-head; lanes 0..7 hold heads 0..7

    // phase 3: weighted aggregation; lane owns channels lane + {0,64,128,192}
    float acc0 = 0.f, acc1 = 0.f, acc2 = 0.f, acc3 = 0.f;
    int hb = lane >> 5;   // 0 or 1
    for (int i = beg; i < end; ++i) {
        int s = ssorted[i];
        float a8 = 0.f;
        if (lane < 8) {
            float e = leaky(el[s * 8 + lane] + er_nl);
            a8 = __expf(e - m) * inv;
        }
        const float* fr = feat + (size_t)s * 256;
        acc0 += __shfl(a8, hb)     * fr[lane];
        acc1 += __shfl(a8, 2 + hb) * fr[64 + lane];
        acc2 += __shfl(a8, 4 + hb) * fr[128 + lane];
        acc3 += __shfl(a8, 6 + hb) * fr[192 + lane];
    }
    float* o = h1 + (size_t)n * 256;
    o[lane]       = fmaxf(acc0, 0.f);   // fused relu
    o[64 + lane]  = fmaxf(acc1, 0.f);
    o[128 + lane] = fmaxf(acc2, 0.f);
    o[192 + lane] = fmaxf(acc3, 0.f);
}

// ---------------- layer-2 attention aggregate + log_softmax ----------------
__global__ __launch_bounds__(256) void agg2_k(const float* __restrict__ feat2,
                                              const float* __restrict__ el2,
                                              const float* __restrict__ er2,
                                              const int* __restrict__ offs,
                                              const int* __restrict__ ssorted,
                                              float* __restrict__ out) {
    int wid = (blockIdx.x * blockDim.x + threadIdx.x) >> 6;
    int lane = threadIdx.x & 63;
    if (wid >= N_NODES) return;
    int n = wid;
    int beg = offs[n], end = offs[n + 1];
    float ern = er2[n];

    float m = -INFINITY;
    for (int i = beg + lane; i < end; i += 64)
        m = fmaxf(m, leaky(el2[ssorted[i]] + ern));
#pragma unroll
    for (int d = 1; d < 64; d <<= 1) m = fmaxf(m, __shfl_xor(m, d));

    float ssum = 0.f;
    for (int i = beg + lane; i < end; i += 64)
        ssum += __expf(leaky(el2[ssorted[i]] + ern) - m);
#pragma unroll
    for (int d = 1; d < 64; d <<= 1) ssum += __shfl_xor(ssum, d);
    float inv = 1.f / ssum;

    float acc = 0.f;
    for (int i = beg; i < end; ++i) {
        int s = ssorted[i];
        float alpha = __expf(leaky(el2[s] + ern) - m) * inv;
        if (lane < 40) acc += alpha * feat2[(size_t)s * 40 + lane];
    }

    // log_softmax over 40 classes
    float v = (lane < 40) ? acc : -INFINITY;
    float vmax = v;
#pragma unroll
    for (int d = 1; d < 64; d <<= 1) vmax = fmaxf(vmax, __shfl_xor(vmax, d));
    float ex = (lane < 40) ? __expf(acc - vmax) : 0.f;
    float s2 = ex;
#pragma unroll
    for (int d = 1; d < 64; d <<= 1) s2 += __shfl_xor(s2, d);
    if (lane < 40) out[(size_t)n * 40 + lane] = acc - vmax - __logf(s2);
}

extern "C" void kernel_launch(void* const* d_in, const int* in_sizes, int n_in,
                              void* d_out, int out_size, void* d_ws, size_t ws_size,
                              hipStream_t stream) {
    (void)in_sizes; (void)n_in; (void)out_size; (void)ws_size;
    const float* x   = (const float*)d_in[0];
    const int*   src = (const int*)d_in[1];
    const int*   dst = (const int*)d_in[2];
    const float* W1  = (const float*)d_in[3];
    const float* al1 = (const float*)d_in[4];
    const float* ar1 = (const float*)d_in[5];
    const float* W2  = (const float*)d_in[6];
    const float* al2 = (const float*)d_in[7];
    const float* ar2 = (const float*)d_in[8];
    float* out = (float*)d_out;

    char* ws = (char*)d_ws;
    size_t off = 0;
    auto alloc = [&](size_t bytes) {
        void* p = ws + off;
        off += (bytes + 255) & ~(size_t)255;
        return p;
    };
    float* feat1 = (float*)alloc((size_t)N_NODES * 256 * 4);
    float* h1    = (float*)alloc((size_t)N_NODES * 256 * 4);
    float* feat2 = (float*)alloc((size_t)N_NODES * 40 * 4);
    float* el1   = (float*)alloc((size_t)N_NODES * 8 * 4);
    float* er1   = (float*)alloc((size_t)N_NODES * 8 * 4);
    float* el2   = (float*)alloc((size_t)N_NODES * 4);
    float* er2   = (float*)alloc((size_t)N_NODES * 4);
    int* deg     = (int*)alloc((size_t)N_NODES * 4);
    int* offs    = (int*)alloc((size_t)(N_NODES + 1) * 4);
    int* cur     = (int*)alloc((size_t)N_NODES * 4);
    int* bsum    = (int*)alloc(1024 * 4);
    int* ssorted = (int*)alloc((size_t)N_EDGES * 4);

    hipMemsetAsync(deg, 0, (size_t)N_NODES * 4, stream);
    hipMemsetAsync(cur, 0, (size_t)N_NODES * 4, stream);

    // CSR by dst
    hist_k<<<(N_EDGES + 255) / 256, 256, 0, stream>>>(dst, deg);
    int nb = (N_NODES + 255) / 256;   // 196
    scan1_k<<<nb, 256, 0, stream>>>(deg, offs, bsum, N_NODES);
    scan2_k<<<1, 256, 0, stream>>>(bsum, nb);
    scan3_k<<<nb, 256, 0, stream>>>(offs, bsum, N_NODES);
    scatter_k<<<(N_EDGES + 255) / 256, 256, 0, stream>>>(src, dst, offs, cur, ssorted);

    // layer 1
    gemm1_k<<<dim3((N_NODES + 63) / 64, 4), 256, 0, stream>>>(x, W1, feat1, N_NODES);
    elr1_k<<<(N_NODES * 8 + 255) / 256, 256, 0, stream>>>(feat1, al1, ar1, el1, er1);
    agg1_k<<<(N_NODES + 3) / 4, 256, 0, stream>>>(feat1, el1, er1, offs, ssorted, h1);

    // layer 2
    gemm2_k<<<(N_NODES + 63) / 64, 256, 0, stream>>>(h1, W2, feat2, N_NODES);
    elr2_k<<<(N_NODES + 255) / 256, 256, 0, stream>>>(feat2, al2, ar2, el2, er2);
    agg2_k<<<(N_NODES + 3) / 4, 256, 0, stream>>>(feat2, el2, er2, offs, ssorted, out);
}

// Round 2
// 426.900 us; speedup vs baseline: 1.2184x; 1.2184x over previous
//
#include <hip/hip_runtime.h>
#include <hip/hip_bf16.h>
#include <math.h>

#define N_NODES 50000
#define N_EDGES 800000
#define IN_DIM  256
#define HID     32
#define HEADS   8
#define NCLS    40
#define NEG     0.2f

using short8 = __attribute__((ext_vector_type(8))) short;
using f32x4  = __attribute__((ext_vector_type(4))) float;

__device__ __forceinline__ float leaky(float x) { return x >= 0.f ? x : NEG * x; }
__device__ __forceinline__ unsigned short f2b(float f) {
    unsigned int u = __float_as_uint(f);
    unsigned int r = (u + 0x7fffu + ((u >> 16) & 1u)) >> 16;
    return (unsigned short)r;
}
__device__ __forceinline__ float b2f(unsigned short h) {
    return __uint_as_float((unsigned int)h << 16);
}

// ---------------- conversions ----------------
__global__ void cvt_x_k(const float* __restrict__ x, unsigned short* __restrict__ xb) {
    size_t i = ((size_t)blockIdx.x * blockDim.x + threadIdx.x) * 8;
    if (i >= (size_t)N_NODES * IN_DIM) return;
    float4 v0 = *reinterpret_cast<const float4*>(x + i);
    float4 v1 = *reinterpret_cast<const float4*>(x + i + 4);
    ushort4 a, b;
    a.x = f2b(v0.x); a.y = f2b(v0.y); a.z = f2b(v0.z); a.w = f2b(v0.w);
    b.x = f2b(v1.x); b.y = f2b(v1.y); b.z = f2b(v1.z); b.w = f2b(v1.w);
    *reinterpret_cast<ushort4*>(xb + i) = a;
    *reinterpret_cast<ushort4*>(xb + i + 4) = b;
}

// W1T[n][k] = bf16(W1[k][n]); W1 is [256][256]
__global__ void cvt_w1t_k(const float* __restrict__ W1, unsigned short* __restrict__ W1T) {
    int k = blockIdx.x, n = threadIdx.x;
    W1T[n * 256 + k] = f2b(W1[k * 256 + n]);
}

// ---------------- GEMM1 (MFMA bf16): feat1bf[M,256] = xb[M,256] @ W1 ----------------
__global__ __launch_bounds__(256) void gemm1_mfma(const unsigned short* __restrict__ A,
                                                  const unsigned short* __restrict__ BT,
                                                  unsigned short* __restrict__ C, int M) {
    __shared__ unsigned short Asm[128][40];
    __shared__ unsigned short Bsm[128][40];
    int t = threadIdx.x;
    int lane = t & 63, w = t >> 6;
    int wr = w >> 1, wc = w & 1;
    int m0 = blockIdx.x * 128, n0 = blockIdx.y * 128;
    f32x4 acc[4][4] = {};

    for (int k0 = 0; k0 < 256; k0 += 32) {
#pragma unroll
        for (int c = 0; c < 2; c++) {
            int chunk = t + c * 256;
            int row = chunk >> 2, col8 = (chunk & 3) * 8;
            // A tile
            uint4 va = make_uint4(0, 0, 0, 0);
            int gm = m0 + row;
            if (gm < M) va = *reinterpret_cast<const uint4*>(A + (size_t)gm * 256 + k0 + col8);
            *reinterpret_cast<uint4*>(&Asm[row][col8]) = va;
            // B tile (BT is [n][k] row-major)
            uint4 vb = *reinterpret_cast<const uint4*>(BT + (size_t)(n0 + row) * 256 + k0 + col8);
            *reinterpret_cast<uint4*>(&Bsm[row][col8]) = vb;
        }
        __syncthreads();
        int koff = (lane >> 4) * 8;
        int rsub = lane & 15;
        short8 a[4], b[4];
#pragma unroll
        for (int mi = 0; mi < 4; mi++)
            a[mi] = *reinterpret_cast<const short8*>(&Asm[wr * 64 + mi * 16 + rsub][koff]);
#pragma unroll
        for (int ni = 0; ni < 4; ni++)
            b[ni] = *reinterpret_cast<const short8*>(&Bsm[wc * 64 + ni * 16 + rsub][koff]);
#pragma unroll
        for (int mi = 0; mi < 4; mi++)
#pragma unroll
            for (int ni = 0; ni < 4; ni++)
                acc[mi][ni] = __builtin_amdgcn_mfma_f32_16x16x32_bf16(a[mi], b[ni], acc[mi][ni], 0, 0, 0);
        __syncthreads();
    }
    int rgrp = (lane >> 4) * 4, csub = lane & 15;
#pragma unroll
    for (int mi = 0; mi < 4; mi++) {
#pragma unroll
        for (int i = 0; i < 4; i++) {
            int row = m0 + wr * 64 + mi * 16 + rgrp + i;
            if (row < M) {
#pragma unroll
                for (int ni = 0; ni < 4; ni++) {
                    int col = n0 + wc * 64 + ni * 16 + csub;
                    C[(size_t)row * 256 + col] = f2b(acc[mi][ni][i]);
                }
            }
        }
    }
}

// ---------------- GEMM2: feat2bf[M,40] = h1bf[M,256] @ W2[256,40] ----------------
__global__ __launch_bounds__(256) void gemm2_k(const unsigned short* __restrict__ A,
                                               const float* __restrict__ B,
                                               unsigned short* __restrict__ C, int M) {
    __shared__ float As[32][65];   // [k][row]
    __shared__ float Bs[32][40];
    int t = threadIdx.x;
    int row = t & 63, cg = t >> 6;   // 4 col groups x 10 cols
    int m0 = blockIdx.x * 64;
    float acc[10] = {};
    for (int k0 = 0; k0 < 256; k0 += 32) {
        {
            int r = t >> 2, c0 = (t & 3) * 8;
            int m = m0 + r;
            uint4 v = make_uint4(0, 0, 0, 0);
            if (m < M) v = *reinterpret_cast<const uint4*>(A + (size_t)m * 256 + k0 + c0);
            const unsigned short* pv = reinterpret_cast<const unsigned short*>(&v);
#pragma unroll
            for (int i = 0; i < 8; i++) As[c0 + i][r] = b2f(pv[i]);
        }
        for (int l = t; l < 32 * 40; l += 256) {
            int r = l / 40, c = l - r * 40;
            Bs[r][c] = B[(k0 + r) * 40 + c];
        }
        __syncthreads();
#pragma unroll
        for (int kk = 0; kk < 32; kk++) {
            float a = As[kk][row];
#pragma unroll
            for (int j = 0; j < 10; j++) acc[j] += a * Bs[kk][cg * 10 + j];
        }
        __syncthreads();
    }
    int m = m0 + row;
    if (m < M) {
#pragma unroll
        for (int j = 0; j < 10; j++) C[(size_t)m * 40 + cg * 10 + j] = f2b(acc[j]);
    }
}

// ---------------- el/er for layer 1 (bf16 feat) ----------------
__global__ void elr1_k(const unsigned short* __restrict__ feat, const float* __restrict__ al,
                       const float* __restrict__ ar, float* __restrict__ el,
                       float* __restrict__ er) {
    int idx = blockIdx.x * blockDim.x + threadIdx.x;   // n*8+h
    if (idx >= N_NODES * HEADS) return;
    int h = idx & 7;
    const unsigned short* f = feat + (size_t)(idx >> 3) * 256 + h * 32;
    const float* a = al + h * 32;
    const float* b = ar + h * 32;
    float sl = 0.f, sr = 0.f;
#pragma unroll
    for (int d = 0; d < 32; d += 8) {
        uint4 v = *reinterpret_cast<const uint4*>(f + d);
        const unsigned short* pv = reinterpret_cast<const unsigned short*>(&v);
#pragma unroll
        for (int i = 0; i < 8; i++) {
            float fv = b2f(pv[i]);
            sl += fv * a[d + i];
            sr += fv * b[d + i];
        }
    }
    el[idx] = sl; er[idx] = sr;
}

// ---------------- el/er for layer 2 (bf16 feat2) ----------------
__global__ void elr2_k(const unsigned short* __restrict__ feat, const float* __restrict__ al,
                       const float* __restrict__ ar, float* __restrict__ el,
                       float* __restrict__ er) {
    int n = blockIdx.x * blockDim.x + threadIdx.x;
    if (n >= N_NODES) return;
    const unsigned short* f = feat + (size_t)n * 40;
    float sl = 0.f, sr = 0.f;
    for (int c = 0; c < 40; c++) { float v = b2f(f[c]); sl += v * al[c]; sr += v * ar[c]; }
    el[n] = sl; er[n] = sr;
}

// ---------------- CSR build: histogram, scan, scatter ----------------
__global__ void hist_k(const int* __restrict__ dst, int* __restrict__ deg) {
    int e = blockIdx.x * blockDim.x + threadIdx.x;
    if (e < N_EDGES) atomicAdd(&deg[dst[e]], 1);
}

__global__ void scan1_k(const int* __restrict__ deg, int* __restrict__ offs,
                        int* __restrict__ bsum, int n) {
    __shared__ int s[256];
    int tid = threadIdx.x;
    int i = blockIdx.x * 256 + tid;
    int v = (i < n) ? deg[i] : 0;
    s[tid] = v;
    __syncthreads();
    for (int d = 1; d < 256; d <<= 1) {
        int t = (tid >= d) ? s[tid - d] : 0;
        __syncthreads();
        s[tid] += t;
        __syncthreads();
    }
    if (i < n) offs[i] = s[tid] - v;          // exclusive, partial
    if (tid == 255) bsum[blockIdx.x] = s[255];
}

__global__ void scan2_k(int* __restrict__ bsum, int nb) {
    __shared__ int s[256];
    int tid = threadIdx.x;
    int v = (tid < nb) ? bsum[tid] : 0;
    s[tid] = v;
    __syncthreads();
    for (int d = 1; d < 256; d <<= 1) {
        int t = (tid >= d) ? s[tid - d] : 0;
        __syncthreads();
        s[tid] += t;
        __syncthreads();
    }
    if (tid < nb) bsum[tid] = s[tid] - v;     // exclusive
}

__global__ void scan3_k(int* __restrict__ offs, const int* __restrict__ bsum, int n) {
    int i = blockIdx.x * 256 + threadIdx.x;
    if (i < n) offs[i] += bsum[blockIdx.x];
    if (i == 0) offs[n] = N_EDGES;
}

__global__ void scatter_k(const int* __restrict__ src, const int* __restrict__ dst,
                          const int* __restrict__ offs, int* __restrict__ cur,
                          int* __restrict__ ssorted) {
    int e = blockIdx.x * blockDim.x + threadIdx.x;
    if (e < N_EDGES) {
        int d = dst[e];
        int p = atomicAdd(&cur[d], 1);
        ssorted[offs[d] + p] = src[e];
    }
}

// ---------------- layer-1 attention aggregate: 1 wave per dst node ----------------
__global__ __launch_bounds__(256) void agg1_k(const unsigned short* __restrict__ feat,
                                              const float* __restrict__ el,
                                              const float* __restrict__ er,
                                              const int* __restrict__ offs,
                                              const int* __restrict__ ssorted,
                                              unsigned short* __restrict__ h1) {
    int wid = (blockIdx.x * blockDim.x + threadIdx.x) >> 6;
    int lane = threadIdx.x & 63;
    if (wid >= N_NODES) return;
    int n = wid;
    int beg = offs[n], end = offs[n + 1];

    float er_nl = (lane < 8) ? er[n * 8 + lane] : 0.f;
    float er_h = __shfl(er_nl, lane & 7);
    int h = lane & 7;

    // phase 1: emax per head (lane = edge_slot*8 + head)
    float m = -INFINITY;
    for (int i = beg + (lane >> 3); i < end; i += 8) {
        int s = ssorted[i];
        m = fmaxf(m, leaky(el[s * 8 + h] + er_h));
    }
    m = fmaxf(m, __shfl_xor(m, 8));
    m = fmaxf(m, __shfl_xor(m, 16));
    m = fmaxf(m, __shfl_xor(m, 32));

    // phase 2: denom per head
    float ssum = 0.f;
    for (int i = beg + (lane >> 3); i < end; i += 8) {
        int s = ssorted[i];
        ssum += __expf(leaky(el[s * 8 + h] + er_h) - m);
    }
    ssum += __shfl_xor(ssum, 8);
    ssum += __shfl_xor(ssum, 16);
    ssum += __shfl_xor(ssum, 32);
    float inv = 1.f / ssum;   // valid per-head; lanes 0..7 hold heads 0..7

    // phase 3: lane owns channels 4*lane .. 4*lane+3 (one head: lane>>3)
    float acc0 = 0.f, acc1 = 0.f, acc2 = 0.f, acc3 = 0.f;
    int hsrc = lane >> 3;   // shfl source lane holding this channel-group's head
    for (int i = beg; i < end; ++i) {
        int s = ssorted[i];
        float a8 = 0.f;
        if (lane < 8) {
            float e = leaky(el[s * 8 + lane] + er_nl);
            a8 = __expf(e - m) * inv;
        }
        float alpha = __shfl(a8, hsrc);
        ushort4 v = *reinterpret_cast<const ushort4*>(feat + (size_t)s * 256 + 4 * lane);
        acc0 += alpha * b2f(v.x);
        acc1 += alpha * b2f(v.y);
        acc2 += alpha * b2f(v.z);
        acc3 += alpha * b2f(v.w);
    }
    ushort4 o;
    o.x = f2b(fmaxf(acc0, 0.f));   // fused relu
    o.y = f2b(fmaxf(acc1, 0.f));
    o.z = f2b(fmaxf(acc2, 0.f));
    o.w = f2b(fmaxf(acc3, 0.f));
    *reinterpret_cast<ushort4*>(h1 + (size_t)n * 256 + 4 * lane) = o;
}

// ---------------- layer-2 attention aggregate + log_softmax ----------------
__global__ __launch_bounds__(256) void agg2_k(const unsigned short* __restrict__ feat2,
                                              const float* __restrict__ el2,
                                              const float* __restrict__ er2,
                                              const int* __restrict__ offs,
                                              const int* __restrict__ ssorted,
                                              float* __restrict__ out) {
    int wid = (blockIdx.x * blockDim.x + threadIdx.x) >> 6;
    int lane = threadIdx.x & 63;
    if (wid >= N_NODES) return;
    int n = wid;
    int beg = offs[n], end = offs[n + 1];
    float ern = er2[n];

    float m = -INFINITY;
    for (int i = beg + lane; i < end; i += 64)
        m = fmaxf(m, leaky(el2[ssorted[i]] + ern));
#pragma unroll
    for (int d = 1; d < 64; d <<= 1) m = fmaxf(m, __shfl_xor(m, d));

    float ssum = 0.f;
    for (int i = beg + lane; i < end; i += 64)
        ssum += __expf(leaky(el2[ssorted[i]] + ern) - m);
#pragma unroll
    for (int d = 1; d < 64; d <<= 1) ssum += __shfl_xor(ssum, d);
    float inv = 1.f / ssum;

    float acc = 0.f;
    for (int i = beg; i < end; ++i) {
        int s = ssorted[i];
        float alpha = __expf(leaky(el2[s] + ern) - m) * inv;
        if (lane < 40) acc += alpha * b2f(feat2[(size_t)s * 40 + lane]);
    }

    // log_softmax over 40 classes
    float v = (lane < 40) ? acc : -INFINITY;
    float vmax = v;
#pragma unroll
    for (int d = 1; d < 64; d <<= 1) vmax = fmaxf(vmax, __shfl_xor(vmax, d));
    float ex = (lane < 40) ? __expf(acc - vmax) : 0.f;
    float s2 = ex;
#pragma unroll
    for (int d = 1; d < 64; d <<= 1) s2 += __shfl_xor(s2, d);
    if (lane < 40) out[(size_t)n * 40 + lane] = acc - vmax - __logf(s2);
}

extern "C" void kernel_launch(void* const* d_in, const int* in_sizes, int n_in,
                              void* d_out, int out_size, void* d_ws, size_t ws_size,
                              hipStream_t stream) {
    (void)in_sizes; (void)n_in; (void)out_size; (void)ws_size;
    const float* x   = (const float*)d_in[0];
    const int*   src = (const int*)d_in[1];
    const int*   dst = (const int*)d_in[2];
    const float* W1  = (const float*)d_in[3];
    const float* al1 = (const float*)d_in[4];
    const float* ar1 = (const float*)d_in[5];
    const float* W2  = (const float*)d_in[6];
    const float* al2 = (const float*)d_in[7];
    const float* ar2 = (const float*)d_in[8];
    float* out = (float*)d_out;

    char* ws = (char*)d_ws;
    size_t off = 0;
    auto alloc = [&](size_t bytes) {
        void* p = ws + off;
        off += (bytes + 255) & ~(size_t)255;
        return p;
    };
    unsigned short* xb      = (unsigned short*)alloc((size_t)N_NODES * 256 * 2);
    unsigned short* w1t     = (unsigned short*)alloc((size_t)256 * 256 * 2);
    unsigned short* feat1bf = (unsigned short*)alloc((size_t)N_NODES * 256 * 2);
    unsigned short* h1bf    = (unsigned short*)alloc((size_t)N_NODES * 256 * 2);
    unsigned short* feat2bf = (unsigned short*)alloc((size_t)N_NODES * 40 * 2);
    float* el1   = (float*)alloc((size_t)N_NODES * 8 * 4);
    float* er1   = (float*)alloc((size_t)N_NODES * 8 * 4);
    float* el2   = (float*)alloc((size_t)N_NODES * 4);
    float* er2   = (float*)alloc((size_t)N_NODES * 4);
    int* deg     = (int*)alloc((size_t)N_NODES * 4);
    int* offs    = (int*)alloc((size_t)(N_NODES + 1) * 4);
    int* cur     = (int*)alloc((size_t)N_NODES * 4);
    int* bsum    = (int*)alloc(1024 * 4);
    int* ssorted = (int*)alloc((size_t)N_EDGES * 4);

    hipMemsetAsync(deg, 0, (size_t)N_NODES * 4, stream);
    hipMemsetAsync(cur, 0, (size_t)N_NODES * 4, stream);

    // conversions
    cvt_x_k<<<(N_NODES * 256 / 8 + 255) / 256, 256, 0, stream>>>(x, xb);
    cvt_w1t_k<<<256, 256, 0, stream>>>(W1, w1t);

    // CSR by dst
    hist_k<<<(N_EDGES + 255) / 256, 256, 0, stream>>>(dst, deg);
    int nb = (N_NODES + 255) / 256;   // 196
    scan1_k<<<nb, 256, 0, stream>>>(deg, offs, bsum, N_NODES);
    scan2_k<<<1, 256, 0, stream>>>(bsum, nb);
    scan3_k<<<nb, 256, 0, stream>>>(offs, bsum, N_NODES);
    scatter_k<<<(N_EDGES + 255) / 256, 256, 0, stream>>>(src, dst, offs, cur, ssorted);

    // layer 1
    gemm1_mfma<<<dim3((N_NODES + 127) / 128, 2), 256, 0, stream>>>(xb, w1t, feat1bf, N_NODES);
    elr1_k<<<(N_NODES * 8 + 255) / 256, 256, 0, stream>>>(feat1bf, al1, ar1, el1, er1);
    agg1_k<<<(N_NODES + 3) / 4, 256, 0, stream>>>(feat1bf, el1, er1, offs, ssorted, h1bf);

    // layer 2
    gemm2_k<<<(N_NODES + 63) / 64, 256, 0, stream>>>(h1bf, W2, feat2bf, N_NODES);
    elr2_k<<<(N_NODES + 255) / 256, 256, 0, stream>>>(feat2bf, al2, ar2, el2, er2);
    agg2_k<<<(N_NODES + 3) / 4, 256, 0, stream>>>(feat2bf, el2, er2, offs, ssorted, out);
}

// Round 3
// 349.948 us; speedup vs baseline: 1.4863x; 1.2199x over previous
//
#include <hip/hip_runtime.h>
#include <hip/hip_bf16.h>
#include <math.h>

#define N_NODES 50000
#define N_EDGES 800000
#define IN_DIM  256
#define HID     32
#define HEADS   8
#define NCLS    40
#define NEG     0.2f

using short8 = __attribute__((ext_vector_type(8))) short;
using f32x4  = __attribute__((ext_vector_type(4))) float;

__device__ __forceinline__ float leaky(float x) { return x >= 0.f ? x : NEG * x; }
__device__ __forceinline__ unsigned short f2b(float f) {
    unsigned int u = __float_as_uint(f);
    unsigned int r = (u + 0x7fffu + ((u >> 16) & 1u)) >> 16;
    return (unsigned short)r;
}
__device__ __forceinline__ float b2f(unsigned short h) {
    return __uint_as_float((unsigned int)h << 16);
}

// W1T[n][k] = bf16(W1[k][n]); W1 is [256][256]
__global__ void cvt_w1t_k(const float* __restrict__ W1, unsigned short* __restrict__ W1T) {
    int k = blockIdx.x, n = threadIdx.x;
    W1T[n * 256 + k] = f2b(W1[k * 256 + n]);
}

// ---------------- GEMM1 (MFMA bf16, fused f32->bf16 A conversion) ----------------
// feat1bf[M,256] = bf16(x[M,256]) @ W1
__global__ __launch_bounds__(256) void gemm1_mfma(const float* __restrict__ A,
                                                  const unsigned short* __restrict__ BT,
                                                  unsigned short* __restrict__ C, int M) {
    __shared__ unsigned short Asm[128][40];
    __shared__ unsigned short Bsm[128][40];
    int t = threadIdx.x;
    int lane = t & 63, w = t >> 6;
    int wr = w >> 1, wc = w & 1;
    int m0 = blockIdx.x * 128, n0 = blockIdx.y * 128;
    f32x4 acc[4][4] = {};

    for (int k0 = 0; k0 < 256; k0 += 32) {
        // A tile: 128 rows x 32 k, f32 -> bf16
#pragma unroll
        for (int c = 0; c < 4; c++) {
            int idx = c * 256 + t;
            int row = idx >> 3, col4 = (idx & 7) * 4;
            int gm = m0 + row;
            float4 v = make_float4(0.f, 0.f, 0.f, 0.f);
            if (gm < M) v = *reinterpret_cast<const float4*>(A + (size_t)gm * 256 + k0 + col4);
            ushort4 b;
            b.x = f2b(v.x); b.y = f2b(v.y); b.z = f2b(v.z); b.w = f2b(v.w);
            *reinterpret_cast<ushort4*>(&Asm[row][col4]) = b;
        }
        // B tile (BT is [n][k] row-major bf16)
#pragma unroll
        for (int c = 0; c < 2; c++) {
            int chunk = t + c * 256;
            int row = chunk >> 2, col8 = (chunk & 3) * 8;
            uint4 vb = *reinterpret_cast<const uint4*>(BT + (size_t)(n0 + row) * 256 + k0 + col8);
            *reinterpret_cast<uint4*>(&Bsm[row][col8]) = vb;
        }
        __syncthreads();
        int koff = (lane >> 4) * 8;
        int rsub = lane & 15;
        short8 a[4], b[4];
#pragma unroll
        for (int mi = 0; mi < 4; mi++)
            a[mi] = *reinterpret_cast<const short8*>(&Asm[wr * 64 + mi * 16 + rsub][koff]);
#pragma unroll
        for (int ni = 0; ni < 4; ni++)
            b[ni] = *reinterpret_cast<const short8*>(&Bsm[wc * 64 + ni * 16 + rsub][koff]);
#pragma unroll
        for (int mi = 0; mi < 4; mi++)
#pragma unroll
            for (int ni = 0; ni < 4; ni++)
                acc[mi][ni] = __builtin_amdgcn_mfma_f32_16x16x32_bf16(a[mi], b[ni], acc[mi][ni], 0, 0, 0);
        __syncthreads();
    }
    int rgrp = (lane >> 4) * 4, csub = lane & 15;
#pragma unroll
    for (int mi = 0; mi < 4; mi++) {
#pragma unroll
        for (int i = 0; i < 4; i++) {
            int row = m0 + wr * 64 + mi * 16 + rgrp + i;
            if (row < M) {
#pragma unroll
                for (int ni = 0; ni < 4; ni++) {
                    int col = n0 + wc * 64 + ni * 16 + csub;
                    C[(size_t)row * 256 + col] = f2b(acc[mi][ni][i]);
                }
            }
        }
    }
}

// ---------------- GEMM2: feat2bf[M,40] = h1bf[M,256] @ W2[256,40] ----------------
__global__ __launch_bounds__(256) void gemm2_k(const unsigned short* __restrict__ A,
                                               const float* __restrict__ B,
                                               unsigned short* __restrict__ C, int M) {
    __shared__ float As[32][65];   // [k][row]
    __shared__ float Bs[32][40];
    int t = threadIdx.x;
    int row = t & 63, cg = t >> 6;   // 4 col groups x 10 cols
    int m0 = blockIdx.x * 64;
    float acc[10] = {};
    for (int k0 = 0; k0 < 256; k0 += 32) {
        {
            int r = t >> 2, c0 = (t & 3) * 8;
            int m = m0 + r;
            uint4 v = make_uint4(0, 0, 0, 0);
            if (m < M) v = *reinterpret_cast<const uint4*>(A + (size_t)m * 256 + k0 + c0);
            const unsigned short* pv = reinterpret_cast<const unsigned short*>(&v);
#pragma unroll
            for (int i = 0; i < 8; i++) As[c0 + i][r] = b2f(pv[i]);
        }
        for (int l = t; l < 32 * 40; l += 256) {
            int r = l / 40, c = l - r * 40;
            Bs[r][c] = B[(k0 + r) * 40 + c];
        }
        __syncthreads();
#pragma unroll
        for (int kk = 0; kk < 32; kk++) {
            float a = As[kk][row];
#pragma unroll
            for (int j = 0; j < 10; j++) acc[j] += a * Bs[kk][cg * 10 + j];
        }
        __syncthreads();
    }
    int m = m0 + row;
    if (m < M) {
#pragma unroll
        for (int j = 0; j < 10; j++) C[(size_t)m * 40 + cg * 10 + j] = f2b(acc[j]);
    }
}

// ---------------- el/er for layer 1 (bf16 feat) ----------------
__global__ void elr1_k(const unsigned short* __restrict__ feat, const float* __restrict__ al,
                       const float* __restrict__ ar, float* __restrict__ el,
                       float* __restrict__ er) {
    int idx = blockIdx.x * blockDim.x + threadIdx.x;   // n*8+h
    if (idx >= N_NODES * HEADS) return;
    int h = idx & 7;
    const unsigned short* f = feat + (size_t)(idx >> 3) * 256 + h * 32;
    const float* a = al + h * 32;
    const float* b = ar + h * 32;
    float sl = 0.f, sr = 0.f;
#pragma unroll
    for (int d = 0; d < 32; d += 8) {
        uint4 v = *reinterpret_cast<const uint4*>(f + d);
        const unsigned short* pv = reinterpret_cast<const unsigned short*>(&v);
#pragma unroll
        for (int i = 0; i < 8; i++) {
            float fv = b2f(pv[i]);
            sl += fv * a[d + i];
            sr += fv * b[d + i];
        }
    }
    el[idx] = sl; er[idx] = sr;
}

// ---------------- el/er for layer 2 (bf16 feat2) ----------------
__global__ void elr2_k(const unsigned short* __restrict__ feat, const float* __restrict__ al,
                       const float* __restrict__ ar, float* __restrict__ el,
                       float* __restrict__ er) {
    int n = blockIdx.x * blockDim.x + threadIdx.x;
    if (n >= N_NODES) return;
    const unsigned short* f = feat + (size_t)n * 40;
    float sl = 0.f, sr = 0.f;
    for (int c = 0; c < 40; c++) { float v = b2f(f[c]); sl += v * al[c]; sr += v * ar[c]; }
    el[n] = sl; er[n] = sr;
}

// ---------------- CSR build: histogram, scan, scatter ----------------
__global__ void hist_k(const int* __restrict__ dst, int* __restrict__ deg) {
    int e = blockIdx.x * blockDim.x + threadIdx.x;
    if (e < N_EDGES) atomicAdd(&deg[dst[e]], 1);
}

__global__ void scan1_k(const int* __restrict__ deg, int* __restrict__ offs,
                        int* __restrict__ bsum, int n) {
    __shared__ int s[256];
    int tid = threadIdx.x;
    int i = blockIdx.x * 256 + tid;
    int v = (i < n) ? deg[i] : 0;
    s[tid] = v;
    __syncthreads();
    for (int d = 1; d < 256; d <<= 1) {
        int t = (tid >= d) ? s[tid - d] : 0;
        __syncthreads();
        s[tid] += t;
        __syncthreads();
    }
    if (i < n) offs[i] = s[tid] - v;          // exclusive, partial
    if (tid == 255) bsum[blockIdx.x] = s[255];
}

__global__ void scan2_k(int* __restrict__ bsum, int nb) {
    __shared__ int s[256];
    int tid = threadIdx.x;
    int v = (tid < nb) ? bsum[tid] : 0;
    s[tid] = v;
    __syncthreads();
    for (int d = 1; d < 256; d <<= 1) {
        int t = (tid >= d) ? s[tid - d] : 0;
        __syncthreads();
        s[tid] += t;
        __syncthreads();
    }
    if (tid < nb) bsum[tid] = s[tid] - v;     // exclusive
}

__global__ void scan3_k(int* __restrict__ offs, const int* __restrict__ bsum, int n) {
    int i = blockIdx.x * 256 + threadIdx.x;
    if (i < n) offs[i] += bsum[blockIdx.x];
    if (i == 0) offs[n] = N_EDGES;
}

__global__ void scatter_k(const int* __restrict__ src, const int* __restrict__ dst,
                          const int* __restrict__ offs, int* __restrict__ cur,
                          int* __restrict__ ssorted) {
    int e = blockIdx.x * blockDim.x + threadIdx.x;
    if (e < N_EDGES) {
        int d = dst[e];
        int p = atomicAdd(&cur[d], 1);
        ssorted[offs[d] + p] = src[e];
    }
}

// ---------------- layer-1 attention aggregate: 1 wave per dst node ----------------
// Pass A: fused online max+sum over chunks of 8 edges (lane = eloc*8 + head).
// Pass B: per 8-edge chunk, all 64 lanes compute the 8x8 alphas at once, then
//         8 independent feat-row gathers (alpha/src broadcast via shfl).
__global__ __launch_bounds__(256) void agg1_k(const unsigned short* __restrict__ feat,
                                              const float* __restrict__ el,
                                              const float* __restrict__ er,
                                              const int* __restrict__ offs,
                                              const int* __restrict__ ssorted,
                                              unsigned short* __restrict__ h1) {
    int wid = (blockIdx.x * blockDim.x + threadIdx.x) >> 6;
    int lane = threadIdx.x & 63;
    if (wid >= N_NODES) return;
    int n = wid;
    int beg = offs[n], end = offs[n + 1];
    int deg = end - beg;
    int eloc = lane >> 3, h = lane & 7;

    float er_h = er[n * 8 + h];

    // pass A: online softmax statistics (m, ssum) per head, replicated per 8-lane group
    float m = -INFINITY, ssum = 0.f;
    for (int c0 = 0; c0 < deg; c0 += 8) {
        bool act = (c0 + eloc) < deg;
        float e = -INFINITY;
        if (act) {
            int s = ssorted[beg + c0 + eloc];
            e = leaky(el[s * 8 + h] + er_h);
        }
        float mc = e;
        mc = fmaxf(mc, __shfl_xor(mc, 8));
        mc = fmaxf(mc, __shfl_xor(mc, 16));
        mc = fmaxf(mc, __shfl_xor(mc, 32));
        float mn = fmaxf(m, mc);
        float ex = act ? __expf(e - mn) : 0.f;
        float sc = ex;
        sc += __shfl_xor(sc, 8);
        sc += __shfl_xor(sc, 16);
        sc += __shfl_xor(sc, 32);
        ssum = ssum * __expf(m - mn) + sc;
        m = mn;
    }
    float inv = 1.f / ssum;

    // pass B: chunked aggregation; lane owns channels 4*lane..4*lane+3 (head lane>>3)
    int ch_h = lane >> 3;
    float acc0 = 0.f, acc1 = 0.f, acc2 = 0.f, acc3 = 0.f;
    for (int c0 = 0; c0 < deg; c0 += 8) {
        int nr = deg - c0; if (nr > 8) nr = 8;
        int s = 0; float a = 0.f;
        if (eloc < nr) {
            s = ssorted[beg + c0 + eloc];
            a = __expf(leaky(el[s * 8 + h] + er_h) - m) * inv;
        }
#pragma unroll
        for (int j = 0; j < 8; j++) {
            if (j < nr) {
                int   sj = __shfl(s, j * 8);
                float aj = __shfl(a, j * 8 + ch_h);
                ushort4 v = *reinterpret_cast<const ushort4*>(feat + (size_t)sj * 256 + 4 * lane);
                acc0 += aj * b2f(v.x);
                acc1 += aj * b2f(v.y);
                acc2 += aj * b2f(v.z);
                acc3 += aj * b2f(v.w);
            }
        }
    }
    ushort4 o;
    o.x = f2b(fmaxf(acc0, 0.f));   // fused relu
    o.y = f2b(fmaxf(acc1, 0.f));
    o.z = f2b(fmaxf(acc2, 0.f));
    o.w = f2b(fmaxf(acc3, 0.f));
    *reinterpret_cast<ushort4*>(h1 + (size_t)n * 256 + 4 * lane) = o;
}

// ---------------- layer-2 attention aggregate + log_softmax ----------------
__global__ __launch_bounds__(256) void agg2_k(const unsigned short* __restrict__ feat2,
                                              const float* __restrict__ el2,
                                              const float* __restrict__ er2,
                                              const int* __restrict__ offs,
                                              const int* __restrict__ ssorted,
                                              float* __restrict__ out) {
    int wid = (blockIdx.x * blockDim.x + threadIdx.x) >> 6;
    int lane = threadIdx.x & 63;
    if (wid >= N_NODES) return;
    int n = wid;
    int beg = offs[n], end = offs[n + 1];
    int deg = end - beg;
    float ern = er2[n];

    // online max+sum, 64 edges per chunk
    float m = -INFINITY, ssum = 0.f;
    for (int c0 = 0; c0 < deg; c0 += 64) {
        bool act = (c0 + lane) < deg;
        float e = -INFINITY;
        if (act) e = leaky(el2[ssorted[beg + c0 + lane]] + ern);
        float mc = e;
#pragma unroll
        for (int d = 1; d < 64; d <<= 1) mc = fmaxf(mc, __shfl_xor(mc, d));
        float mn = fmaxf(m, mc);
        float ex = act ? __expf(e - mn) : 0.f;
        float sc = ex;
#pragma unroll
        for (int d = 1; d < 64; d <<= 1) sc += __shfl_xor(sc, d);
        ssum = ssum * __expf(m - mn) + sc;
        m = mn;
    }
    float inv = 1.f / ssum;

    // aggregation: 64 alphas batched, then broadcast + independent row loads
    float acc = 0.f;
    for (int c0 = 0; c0 < deg; c0 += 64) {
        int nr = deg - c0; if (nr > 64) nr = 64;
        int s = 0; float a = 0.f;
        if (lane < nr) {
            s = ssorted[beg + c0 + lane];
            a = __expf(leaky(el2[s] + ern) - m) * inv;
        }
#pragma unroll 4
        for (int j = 0; j < nr; j++) {
            int   sj = __shfl(s, j);
            float aj = __shfl(a, j);
            if (lane < 40) acc += aj * b2f(feat2[(size_t)sj * 40 + lane]);
        }
    }

    // log_softmax over 40 classes
    float v = (lane < 40) ? acc : -INFINITY;
    float vmax = v;
#pragma unroll
    for (int d = 1; d < 64; d <<= 1) vmax = fmaxf(vmax, __shfl_xor(vmax, d));
    float ex = (lane < 40) ? __expf(acc - vmax) : 0.f;
    float s2 = ex;
#pragma unroll
    for (int d = 1; d < 64; d <<= 1) s2 += __shfl_xor(s2, d);
    if (lane < 40) out[(size_t)n * 40 + lane] = acc - vmax - __logf(s2);
}

extern "C" void kernel_launch(void* const* d_in, const int* in_sizes, int n_in,
                              void* d_out, int out_size, void* d_ws, size_t ws_size,
                              hipStream_t stream) {
    (void)in_sizes; (void)n_in; (void)out_size; (void)ws_size;
    const float* x   = (const float*)d_in[0];
    const int*   src = (const int*)d_in[1];
    const int*   dst = (const int*)d_in[2];
    const float* W1  = (const float*)d_in[3];
    const float* al1 = (const float*)d_in[4];
    const float* ar1 = (const float*)d_in[5];
    const float* W2  = (const float*)d_in[6];
    const float* al2 = (const float*)d_in[7];
    const float* ar2 = (const float*)d_in[8];
    float* out = (float*)d_out;

    char* ws = (char*)d_ws;
    size_t off = 0;
    auto alloc = [&](size_t bytes) {
        void* p = ws + off;
        off += (bytes + 255) & ~(size_t)255;
        return p;
    };
    unsigned short* w1t     = (unsigned short*)alloc((size_t)256 * 256 * 2);
    unsigned short* feat1bf = (unsigned short*)alloc((size_t)N_NODES * 256 * 2);
    unsigned short* h1bf    = (unsigned short*)alloc((size_t)N_NODES * 256 * 2);
    unsigned short* feat2bf = (unsigned short*)alloc((size_t)N_NODES * 40 * 2);
    float* el1   = (float*)alloc((size_t)N_NODES * 8 * 4);
    float* er1   = (float*)alloc((size_t)N_NODES * 8 * 4);
    float* el2   = (float*)alloc((size_t)N_NODES * 4);
    float* er2   = (float*)alloc((size_t)N_NODES * 4);
    int* deg     = (int*)alloc((size_t)N_NODES * 4);
    int* offs    = (int*)alloc((size_t)(N_NODES + 1) * 4);
    int* cur     = (int*)alloc((size_t)N_NODES * 4);
    int* bsum    = (int*)alloc(1024 * 4);
    int* ssorted = (int*)alloc((size_t)N_EDGES * 4);

    hipMemsetAsync(deg, 0, (size_t)N_NODES * 4, stream);
    hipMemsetAsync(cur, 0, (size_t)N_NODES * 4, stream);

    // conversions
    cvt_w1t_k<<<256, 256, 0, stream>>>(W1, w1t);

    // CSR by dst
    hist_k<<<(N_EDGES + 255) / 256, 256, 0, stream>>>(dst, deg);
    int nb = (N_NODES + 255) / 256;   // 196
    scan1_k<<<nb, 256, 0, stream>>>(deg, offs, bsum, N_NODES);
    scan2_k<<<1, 256, 0, stream>>>(bsum, nb);
    scan3_k<<<nb, 256, 0, stream>>>(offs, bsum, N_NODES);
    scatter_k<<<(N_EDGES + 255) / 256, 256, 0, stream>>>(src, dst, offs, cur, ssorted);

    // layer 1
    gemm1_mfma<<<dim3((N_NODES + 127) / 128, 2), 256, 0, stream>>>(x, w1t, feat1bf, N_NODES);
    elr1_k<<<(N_NODES * 8 + 255) / 256, 256, 0, stream>>>(feat1bf, al1, ar1, el1, er1);
    agg1_k<<<(N_NODES + 3) / 4, 256, 0, stream>>>(feat1bf, el1, er1, offs, ssorted, h1bf);

    // layer 2
    gemm2_k<<<(N_NODES + 63) / 64, 256, 0, stream>>>(h1bf, W2, feat2bf, N_NODES);
    elr2_k<<<(N_NODES + 255) / 256, 256, 0, stream>>>(feat2bf, al2, ar2, el2, er2);
    agg2_k<<<(N_NODES + 3) / 4, 256, 0, stream>>>(feat2bf, el2, er2, offs, ssorted, out);
}

// Round 4
// 321.590 us; speedup vs baseline: 1.6173x; 1.0882x over previous
//
#include <hip/hip_runtime.h>
#include <hip/hip_bf16.h>
#include <math.h>

#define N_NODES 50000
#define N_EDGES 800000
#define IN_DIM  256
#define HID     32
#define HEADS   8
#define NCLS    40
#define NEG     0.2f
#define CAP1    128
#define CAP2    128

using short8 = __attribute__((ext_vector_type(8))) short;
using f32x4  = __attribute__((ext_vector_type(4))) float;

__device__ __forceinline__ float leaky(float x) { return x >= 0.f ? x : NEG * x; }
__device__ __forceinline__ unsigned short f2b(float f) {
    unsigned int u = __float_as_uint(f);
    unsigned int r = (u + 0x7fffu + ((u >> 16) & 1u)) >> 16;
    return (unsigned short)r;
}
__device__ __forceinline__ float b2f(unsigned short h) {
    return __uint_as_float((unsigned int)h << 16);
}

// W1T[n][k] = bf16(W1[k][n]); W1 is [256][256]
__global__ void cvt_w1t_k(const float* __restrict__ W1, unsigned short* __restrict__ W1T) {
    int k = blockIdx.x, n = threadIdx.x;
    W1T[n * 256 + k] = f2b(W1[k * 256 + n]);
}

// ---------------- GEMM1 (MFMA bf16, fused f32->bf16, full N per block) ----------------
// feat1bf[M,256] = bf16(x[M,256]) @ W1;  A read exactly once.
__global__ __launch_bounds__(256) void gemm1_mfma(const float* __restrict__ A,
                                                  const unsigned short* __restrict__ BT,
                                                  unsigned short* __restrict__ C, int M) {
    __shared__ unsigned short Asm[128][40];
    __shared__ unsigned short Bsm[256][40];
    int t = threadIdx.x;
    int lane = t & 63, w = t >> 6;
    int wr = w >> 1, wc = w & 1;          // wave tile: 64 rows x 128 cols
    int m0 = blockIdx.x * 128;
    f32x4 acc[4][8] = {};

    for (int k0 = 0; k0 < 256; k0 += 32) {
        // A tile: 128 rows x 32 k, f32 -> bf16
#pragma unroll
        for (int c = 0; c < 4; c++) {
            int idx = c * 256 + t;
            int row = idx >> 3, col4 = (idx & 7) * 4;
            int gm = m0 + row;
            float4 v = make_float4(0.f, 0.f, 0.f, 0.f);
            if (gm < M) v = *reinterpret_cast<const float4*>(A + (size_t)gm * 256 + k0 + col4);
            ushort4 b;
            b.x = f2b(v.x); b.y = f2b(v.y); b.z = f2b(v.z); b.w = f2b(v.w);
            *reinterpret_cast<ushort4*>(&Asm[row][col4]) = b;
        }
        // B tile: 256 n-rows x 32 k  (BT is [n][k] bf16)
#pragma unroll
        for (int c = 0; c < 4; c++) {
            int chunk = t + c * 256;
            int row = chunk >> 2, col8 = (chunk & 3) * 8;
            uint4 vb = *reinterpret_cast<const uint4*>(BT + (size_t)row * 256 + k0 + col8);
            *reinterpret_cast<uint4*>(&Bsm[row][col8]) = vb;
        }
        __syncthreads();
        int koff = (lane >> 4) * 8;
        int rsub = lane & 15;
        short8 a[4], b[8];
#pragma unroll
        for (int mi = 0; mi < 4; mi++)
            a[mi] = *reinterpret_cast<const short8*>(&Asm[wr * 64 + mi * 16 + rsub][koff]);
#pragma unroll
        for (int ni = 0; ni < 8; ni++)
            b[ni] = *reinterpret_cast<const short8*>(&Bsm[wc * 128 + ni * 16 + rsub][koff]);
#pragma unroll
        for (int mi = 0; mi < 4; mi++)
#pragma unroll
            for (int ni = 0; ni < 8; ni++)
                acc[mi][ni] = __builtin_amdgcn_mfma_f32_16x16x32_bf16(a[mi], b[ni], acc[mi][ni], 0, 0, 0);
        __syncthreads();
    }
    int rgrp = (lane >> 4) * 4, csub = lane & 15;
#pragma unroll
    for (int mi = 0; mi < 4; mi++) {
#pragma unroll
        for (int i = 0; i < 4; i++) {
            int row = m0 + wr * 64 + mi * 16 + rgrp + i;
            if (row < M) {
#pragma unroll
                for (int ni = 0; ni < 8; ni++) {
                    int col = wc * 128 + ni * 16 + csub;
                    C[(size_t)row * 256 + col] = f2b(acc[mi][ni][i]);
                }
            }
        }
    }
}

// ---------------- GEMM2: feat2p[M,64] = h1bf[M,256] @ W2[256,40] (cols 40..63 = 0) ----
__global__ __launch_bounds__(256) void gemm2_k(const unsigned short* __restrict__ A,
                                               const float* __restrict__ B,
                                               unsigned short* __restrict__ C, int M) {
    __shared__ float As[32][65];   // [k][row]
    __shared__ float Bs[32][64];
    int t = threadIdx.x;
    int row = t & 63, cg = t >> 6;   // 4 col groups x 16 cols
    int m0 = blockIdx.x * 64;
    float acc[16] = {};
    for (int k0 = 0; k0 < 256; k0 += 32) {
        {
            int r = t >> 2, c0 = (t & 3) * 8;
            int m = m0 + r;
            uint4 v = make_uint4(0, 0, 0, 0);
            if (m < M) v = *reinterpret_cast<const uint4*>(A + (size_t)m * 256 + k0 + c0);
            const unsigned short* pv = reinterpret_cast<const unsigned short*>(&v);
#pragma unroll
            for (int i = 0; i < 8; i++) As[c0 + i][r] = b2f(pv[i]);
        }
        for (int l = t; l < 32 * 64; l += 256) {
            int r = l >> 6, c = l & 63;
            Bs[r][c] = (c < 40) ? B[(k0 + r) * 40 + c] : 0.f;
        }
        __syncthreads();
#pragma unroll
        for (int kk = 0; kk < 32; kk++) {
            float a = As[kk][row];
#pragma unroll
            for (int j = 0; j < 16; j++) acc[j] += a * Bs[kk][cg * 16 + j];
        }
        __syncthreads();
    }
    int m = m0 + row;
    if (m < M) {
#pragma unroll
        for (int j = 0; j < 16; j++) C[(size_t)m * 64 + cg * 16 + j] = f2b(acc[j]);
    }
}

// ---------------- el/er for layer 1 (bf16 feat) ----------------
__global__ void elr1_k(const unsigned short* __restrict__ feat, const float* __restrict__ al,
                       const float* __restrict__ ar, float* __restrict__ el,
                       float* __restrict__ er) {
    int idx = blockIdx.x * blockDim.x + threadIdx.x;   // n*8+h
    if (idx >= N_NODES * HEADS) return;
    int h = idx & 7;
    const unsigned short* f = feat + (size_t)(idx >> 3) * 256 + h * 32;
    const float* a = al + h * 32;
    const float* b = ar + h * 32;
    float sl = 0.f, sr = 0.f;
#pragma unroll
    for (int d = 0; d < 32; d += 8) {
        uint4 v = *reinterpret_cast<const uint4*>(f + d);
        const unsigned short* pv = reinterpret_cast<const unsigned short*>(&v);
#pragma unroll
        for (int i = 0; i < 8; i++) {
            float fv = b2f(pv[i]);
            sl += fv * a[d + i];
            sr += fv * b[d + i];
        }
    }
    el[idx] = sl; er[idx] = sr;
}

// ---------------- el/er for layer 2 (padded bf16 feat2) ----------------
__global__ void elr2_k(const unsigned short* __restrict__ feat, const float* __restrict__ al,
                       const float* __restrict__ ar, float* __restrict__ el,
                       float* __restrict__ er) {
    int n = blockIdx.x * blockDim.x + threadIdx.x;
    if (n >= N_NODES) return;
    const unsigned short* f = feat + (size_t)n * 64;
    float sl = 0.f, sr = 0.f;
    for (int c = 0; c < 40; c++) { float v = b2f(f[c]); sl += v * al[c]; sr += v * ar[c]; }
    el[n] = sl; er[n] = sr;
}

// ---------------- CSR build: histogram, scan, scatter ----------------
__global__ void hist_k(const int* __restrict__ dst, int* __restrict__ deg) {
    int e = blockIdx.x * blockDim.x + threadIdx.x;
    if (e < N_EDGES) atomicAdd(&deg[dst[e]], 1);
}

__global__ void scan1_k(const int* __restrict__ deg, int* __restrict__ offs,
                        int* __restrict__ bsum, int n) {
    __shared__ int s[256];
    int tid = threadIdx.x;
    int i = blockIdx.x * 256 + tid;
    int v = (i < n) ? deg[i] : 0;
    s[tid] = v;
    __syncthreads();
    for (int d = 1; d < 256; d <<= 1) {
        int t = (tid >= d) ? s[tid - d] : 0;
        __syncthreads();
        s[tid] += t;
        __syncthreads();
    }
    if (i < n) offs[i] = s[tid] - v;
    if (tid == 255) bsum[blockIdx.x] = s[255];
}

__global__ void scan2_k(int* __restrict__ bsum, int nb) {
    __shared__ int s[256];
    int tid = threadIdx.x;
    int v = (tid < nb) ? bsum[tid] : 0;
    s[tid] = v;
    __syncthreads();
    for (int d = 1; d < 256; d <<= 1) {
        int t = (tid >= d) ? s[tid - d] : 0;
        __syncthreads();
        s[tid] += t;
        __syncthreads();
    }
    if (tid < nb) bsum[tid] = s[tid] - v;
}

__global__ void scan3_k(int* __restrict__ offs, const int* __restrict__ bsum, int n) {
    int i = blockIdx.x * 256 + threadIdx.x;
    if (i < n) offs[i] += bsum[blockIdx.x];
    if (i == 0) offs[n] = N_EDGES;
}

__global__ void scatter_k(const int* __restrict__ src, const int* __restrict__ dst,
                          const int* __restrict__ offs, int* __restrict__ cur,
                          int* __restrict__ ssorted) {
    int e = blockIdx.x * blockDim.x + threadIdx.x;
    if (e < N_EDGES) {
        int d = dst[e];
        int p = atomicAdd(&cur[d], 1);
        ssorted[offs[d] + p] = src[e];
    }
}

// ---------------- layer-1 attention aggregate: 1 wave per dst node ----------------
__global__ __launch_bounds__(256) void agg1_k(const unsigned short* __restrict__ feat,
                                              const float* __restrict__ el,
                                              const float* __restrict__ er,
                                              const int* __restrict__ offs,
                                              const int* __restrict__ ssorted,
                                              unsigned short* __restrict__ h1) {
    __shared__ float sa[4][CAP1 * 8];
    __shared__ int   ss[4][CAP1];
    int t = threadIdx.x;
    int wv = t >> 6, lane = t & 63;
    int n = blockIdx.x * 4 + wv;
    if (n >= N_NODES) return;
    int beg = offs[n], end = offs[n + 1];
    int deg = end - beg;
    int eloc = lane >> 3, h = lane & 7;
    float er_h = er[n * 8 + h];

    float acc0 = 0.f, acc1 = 0.f, acc2 = 0.f, acc3 = 0.f;
    int ch_h = lane >> 3;   // head owning channels 4*lane..4*lane+3

    if (deg <= CAP1) {
        // pass A: online max+sum, stash e and src in LDS
        float m = -INFINITY, ssum = 0.f;
        for (int c0 = 0; c0 < deg; c0 += 8) {
            int idx = c0 + eloc;
            bool act = idx < deg;
            float e = -INFINITY;
            if (act) {
                int s = ssorted[beg + idx];
                if (h == 0) ss[wv][idx] = s;
                e = leaky(el[s * 8 + h] + er_h);
                sa[wv][idx * 8 + h] = e;
            }
            float mc = e;
            mc = fmaxf(mc, __shfl_xor(mc, 8));
            mc = fmaxf(mc, __shfl_xor(mc, 16));
            mc = fmaxf(mc, __shfl_xor(mc, 32));
            float mn = fmaxf(m, mc);
            float ex = act ? __expf(e - mn) : 0.f;
            float sc = ex;
            sc += __shfl_xor(sc, 8);
            sc += __shfl_xor(sc, 16);
            sc += __shfl_xor(sc, 32);
            ssum = ssum * __expf(m - mn) + sc;
            m = mn;
        }
        float inv = 1.f / ssum;
        asm volatile("s_waitcnt lgkmcnt(0)" ::: "memory");
        // convert stash to final alphas
        for (int idx = lane; idx < deg * 8; idx += 64) {
            int hh = idx & 7;
            float mi = __shfl(m, hh);
            float iv = __shfl(inv, hh);
            sa[wv][idx] = __expf(sa[wv][idx] - mi) * iv;
        }
        asm volatile("s_waitcnt lgkmcnt(0)" ::: "memory");
        // pass B: 16 edges per batch, all alphas from LDS
        for (int c0 = 0; c0 < deg; c0 += 16) {
            int nr = deg - c0; if (nr > 16) nr = 16;
            ushort4 u[16]; float av[16];
#pragma unroll
            for (int j = 0; j < 16; j++) {
                if (j < nr) {
                    int sj = ss[wv][c0 + j];
                    av[j] = sa[wv][(c0 + j) * 8 + ch_h];
                    u[j] = *reinterpret_cast<const ushort4*>(feat + (size_t)sj * 256 + 4 * lane);
                }
            }
#pragma unroll
            for (int j = 0; j < 16; j++) {
                if (j < nr) {
                    acc0 += av[j] * b2f(u[j].x);
                    acc1 += av[j] * b2f(u[j].y);
                    acc2 += av[j] * b2f(u[j].z);
                    acc3 += av[j] * b2f(u[j].w);
                }
            }
        }
    } else {
        // fallback (deg > CAP1): two-pass gather
        float m = -INFINITY, ssum = 0.f;
        for (int c0 = 0; c0 < deg; c0 += 8) {
            bool act = (c0 + eloc) < deg;
            float e = -INFINITY;
            if (act) {
                int s = ssorted[beg + c0 + eloc];
                e = leaky(el[s * 8 + h] + er_h);
            }
            float mc = e;
            mc = fmaxf(mc, __shfl_xor(mc, 8));
            mc = fmaxf(mc, __shfl_xor(mc, 16));
            mc = fmaxf(mc, __shfl_xor(mc, 32));
            float mn = fmaxf(m, mc);
            float ex = act ? __expf(e - mn) : 0.f;
            float sc = ex;
            sc += __shfl_xor(sc, 8);
            sc += __shfl_xor(sc, 16);
            sc += __shfl_xor(sc, 32);
            ssum = ssum * __expf(m - mn) + sc;
            m = mn;
        }
        float inv = 1.f / ssum;
        for (int c0 = 0; c0 < deg; c0 += 8) {
            int nr = deg - c0; if (nr > 8) nr = 8;
            int s = 0; float a = 0.f;
            if (eloc < nr) {
                s = ssorted[beg + c0 + eloc];
                a = __expf(leaky(el[s * 8 + h] + er_h) - m) * inv;
            }
#pragma unroll
            for (int j = 0; j < 8; j++) {
                if (j < nr) {
                    int   sj = __shfl(s, j * 8);
                    float aj = __shfl(a, j * 8 + ch_h);
                    ushort4 v = *reinterpret_cast<const ushort4*>(feat + (size_t)sj * 256 + 4 * lane);
                    acc0 += aj * b2f(v.x);
                    acc1 += aj * b2f(v.y);
                    acc2 += aj * b2f(v.z);
                    acc3 += aj * b2f(v.w);
                }
            }
        }
    }
    ushort4 o;
    o.x = f2b(fmaxf(acc0, 0.f));   // fused relu
    o.y = f2b(fmaxf(acc1, 0.f));
    o.z = f2b(fmaxf(acc2, 0.f));
    o.w = f2b(fmaxf(acc3, 0.f));
    *reinterpret_cast<ushort4*>(h1 + (size_t)n * 256 + 4 * lane) = o;
}

// ---------------- layer-2 attention aggregate + log_softmax ----------------
// feat2p is [N,64] padded; lane = eloc*8 + c8: 8 edges x 8 channel-chunks.
__global__ __launch_bounds__(256) void agg2_k(const unsigned short* __restrict__ feat2p,
                                              const float* __restrict__ el2,
                                              const float* __restrict__ er2,
                                              const int* __restrict__ offs,
                                              const int* __restrict__ ssorted,
                                              float* __restrict__ out) {
    __shared__ float sa[4][CAP2];
    __shared__ int   ss[4][CAP2];
    int t = threadIdx.x;
    int wv = t >> 6, lane = t & 63;
    int n = blockIdx.x * 4 + wv;
    if (n >= N_NODES) return;
    int beg = offs[n], end = offs[n + 1];
    int deg = end - beg;
    float ern = er2[n];
    int eloc = lane >> 3, c8 = lane & 7;

    float acc[8] = {};
    if (deg <= CAP2) {
        // pass A: online max+sum with stash
        float m = -INFINITY, ssum = 0.f;
        for (int c0 = 0; c0 < deg; c0 += 64) {
            int idx = c0 + lane;
            bool act = idx < deg;
            float e = -INFINITY;
            if (act) {
                int s = ssorted[beg + idx];
                ss[wv][idx] = s;
                e = leaky(el2[s] + ern);
                sa[wv][idx] = e;
            }
            float mc = e;
#pragma unroll
            for (int d = 1; d < 64; d <<= 1) mc = fmaxf(mc, __shfl_xor(mc, d));
            float mn = fmaxf(m, mc);
            float ex = act ? __expf(e - mn) : 0.f;
            float sc = ex;
#pragma unroll
            for (int d = 1; d < 64; d <<= 1) sc += __shfl_xor(sc, d);
            ssum = ssum * __expf(m - mn) + sc;
            m = mn;
        }
        float inv = 1.f / ssum;
        asm volatile("s_waitcnt lgkmcnt(0)" ::: "memory");
        for (int idx = lane; idx < deg; idx += 64)
            sa[wv][idx] = __expf(sa[wv][idx] - m) * inv;
        asm volatile("s_waitcnt lgkmcnt(0)" ::: "memory");
        // pass B: 8 edges per batch, 8-lane group per edge row (128 B coalesced)
        for (int c0 = 0; c0 < deg; c0 += 8) {
            int nr = deg - c0; if (nr > 8) nr = 8;
            if (eloc < nr) {
                int s = ss[wv][c0 + eloc];
                float a = sa[wv][c0 + eloc];
                uint4 v = *reinterpret_cast<const uint4*>(feat2p + (size_t)s * 64 + c8 * 8);
                const unsigned short* pv = reinterpret_cast<const unsigned short*>(&v);
#pragma unroll
                for (int i = 0; i < 8; i++) acc[i] += a * b2f(pv[i]);
            }
        }
    } else {
        // fallback: recompute alphas
        float m = -INFINITY, ssum = 0.f;
        for (int c0 = 0; c0 < deg; c0 += 64) {
            bool act = (c0 + lane) < deg;
            float e = -INFINITY;
            if (act) e = leaky(el2[ssorted[beg + c0 + lane]] + ern);
            float mc = e;
#pragma unroll
            for (int d = 1; d < 64; d <<= 1) mc = fmaxf(mc, __shfl_xor(mc, d));
            float mn = fmaxf(m, mc);
            float ex = act ? __expf(e - mn) : 0.f;
            float sc = ex;
#pragma unroll
            for (int d = 1; d < 64; d <<= 1) sc += __shfl_xor(sc, d);
            ssum = ssum * __expf(m - mn) + sc;
            m = mn;
        }
        float inv = 1.f / ssum;
        for (int c0 = 0; c0 < deg; c0 += 8) {
            int nr = deg - c0; if (nr > 8) nr = 8;
            if (eloc < nr) {
                int s = ssorted[beg + c0 + eloc];
                float a = __expf(leaky(el2[s] + ern) - m) * inv;
                uint4 v = *reinterpret_cast<const uint4*>(feat2p + (size_t)s * 64 + c8 * 8);
                const unsigned short* pv = reinterpret_cast<const unsigned short*>(&v);
#pragma unroll
                for (int i = 0; i < 8; i++) acc[i] += a * b2f(pv[i]);
            }
        }
    }
    // reduce over edge groups (lanes differing in bits 3..5)
#pragma unroll
    for (int i = 0; i < 8; i++) {
        acc[i] += __shfl_xor(acc[i], 8);
        acc[i] += __shfl_xor(acc[i], 16);
        acc[i] += __shfl_xor(acc[i], 32);
    }
    // log_softmax over 40 real cols (c8 < 5)
    float lmax = -INFINITY;
    if (c8 < 5) {
#pragma unroll
        for (int i = 0; i < 8; i++) lmax = fmaxf(lmax, acc[i]);
    }
    lmax = fmaxf(lmax, __shfl_xor(lmax, 1));
    lmax = fmaxf(lmax, __shfl_xor(lmax, 2));
    lmax = fmaxf(lmax, __shfl_xor(lmax, 4));
    float lsum = 0.f;
    if (c8 < 5) {
#pragma unroll
        for (int i = 0; i < 8; i++) lsum += __expf(acc[i] - lmax);
    }
    lsum += __shfl_xor(lsum, 1);
    lsum += __shfl_xor(lsum, 2);
    lsum += __shfl_xor(lsum, 4);
    if (eloc == 0 && c8 < 5) {
        float lg = __logf(lsum);
        float* o = out + (size_t)n * 40 + c8 * 8;
#pragma unroll
        for (int i = 0; i < 8; i++) o[i] = acc[i] - lmax - lg;
    }
}

extern "C" void kernel_launch(void* const* d_in, const int* in_sizes, int n_in,
                              void* d_out, int out_size, void* d_ws, size_t ws_size,
                              hipStream_t stream) {
    (void)in_sizes; (void)n_in; (void)out_size; (void)ws_size;
    const float* x   = (const float*)d_in[0];
    const int*   src = (const int*)d_in[1];
    const int*   dst = (const int*)d_in[2];
    const float* W1  = (const float*)d_in[3];
    const float* al1 = (const float*)d_in[4];
    const float* ar1 = (const float*)d_in[5];
    const float* W2  = (const float*)d_in[6];
    const float* al2 = (const float*)d_in[7];
    const float* ar2 = (const float*)d_in[8];
    float* out = (float*)d_out;

    char* ws = (char*)d_ws;
    size_t off = 0;
    auto alloc = [&](size_t bytes) {
        void* p = ws + off;
        off += (bytes + 255) & ~(size_t)255;
        return p;
    };
    unsigned short* w1t     = (unsigned short*)alloc((size_t)256 * 256 * 2);
    unsigned short* feat1bf = (unsigned short*)alloc((size_t)N_NODES * 256 * 2);
    unsigned short* h1bf    = (unsigned short*)alloc((size_t)N_NODES * 256 * 2);
    unsigned short* feat2p  = (unsigned short*)alloc((size_t)N_NODES * 64 * 2);
    float* el1   = (float*)alloc((size_t)N_NODES * 8 * 4);
    float* er1   = (float*)alloc((size_t)N_NODES * 8 * 4);
    float* el2   = (float*)alloc((size_t)N_NODES * 4);
    float* er2   = (float*)alloc((size_t)N_NODES * 4);
    int* deg     = (int*)alloc((size_t)N_NODES * 4);
    int* offs    = (int*)alloc((size_t)(N_NODES + 1) * 4);
    int* cur     = (int*)alloc((size_t)N_NODES * 4);
    int* bsum    = (int*)alloc(1024 * 4);
    int* ssorted = (int*)alloc((size_t)N_EDGES * 4);

    hipMemsetAsync(deg, 0, (size_t)N_NODES * 4, stream);
    hipMemsetAsync(cur, 0, (size_t)N_NODES * 4, stream);

    cvt_w1t_k<<<256, 256, 0, stream>>>(W1, w1t);

    // CSR by dst
    hist_k<<<(N_EDGES + 255) / 256, 256, 0, stream>>>(dst, deg);
    int nb = (N_NODES + 255) / 256;
    scan1_k<<<nb, 256, 0, stream>>>(deg, offs, bsum, N_NODES);
    scan2_k<<<1, 256, 0, stream>>>(bsum, nb);
    scan3_k<<<nb, 256, 0, stream>>>(offs, bsum, N_NODES);
    scatter_k<<<(N_EDGES + 255) / 256, 256, 0, stream>>>(src, dst, offs, cur, ssorted);

    // layer 1
    gemm1_mfma<<<(N_NODES + 127) / 128, 256, 0, stream>>>(x, w1t, feat1bf, N_NODES);
    elr1_k<<<(N_NODES * 8 + 255) / 256, 256, 0, stream>>>(feat1bf, al1, ar1, el1, er1);
    agg1_k<<<(N_NODES + 3) / 4, 256, 0, stream>>>(feat1bf, el1, er1, offs, ssorted, h1bf);

    // layer 2
    gemm2_k<<<(N_NODES + 63) / 64, 256, 0, stream>>>(h1bf, W2, feat2p, N_NODES);
    elr2_k<<<(N_NODES + 255) / 256, 256, 0, stream>>>(feat2p, al2, ar2, el2, er2);
    agg2_k<<<(N_NODES + 3) / 4, 256, 0, stream>>>(feat2p, el2, er2, offs, ssorted, out);
}

// Round 5
// 274.813 us; speedup vs baseline: 1.8926x; 1.1702x over previous
//
#include <hip/hip_runtime.h>
#include <hip/hip_bf16.h>
#include <math.h>

#define N_NODES 50000
#define N_EDGES 800000
#define IN_DIM  256
#define HID     32
#define HEADS   8
#define NCLS    40
#define NEG     0.2f
#define CAP1    128
#define CAP2    128

using short8  = __attribute__((ext_vector_type(8))) short;
using f32x4   = __attribute__((ext_vector_type(4))) float;
using floatx2 = __attribute__((ext_vector_type(2))) float;

__device__ __forceinline__ float leaky(float x) { return x >= 0.f ? x : NEG * x; }
__device__ __forceinline__ unsigned short f2b(float f) {
    unsigned int u = __float_as_uint(f);
    unsigned int r = (u + 0x7fffu + ((u >> 16) & 1u)) >> 16;
    return (unsigned short)r;
}
__device__ __forceinline__ float b2f(unsigned short h) {
    return __uint_as_float((unsigned int)h << 16);
}
__device__ __forceinline__ unsigned char f2e4m3(float v) {
    int p = __builtin_amdgcn_cvt_pk_fp8_f32(v, v, 0, false);
    return (unsigned char)(p & 0xff);
}

// W1T[n][k] = bf16(W1[k][n]); W1 is [256][256]
__global__ void cvt_w1t_k(const float* __restrict__ W1, unsigned short* __restrict__ W1T) {
    int k = blockIdx.x, n = threadIdx.x;
    W1T[n * 256 + k] = f2b(W1[k * 256 + n]);
}

// ---------------- GEMM1 (MFMA bf16) + fused el1/er1 + fp8 feat1 output ----------------
// feat8[M,256] (e4m3) = quant(bf16(x) @ W1); el1/er1 from f32 accumulators.
__global__ __launch_bounds__(256) void gemm1_mfma(const float* __restrict__ A,
                                                  const unsigned short* __restrict__ BT,
                                                  const float* __restrict__ al,
                                                  const float* __restrict__ ar,
                                                  unsigned char* __restrict__ F8,
                                                  float* __restrict__ el,
                                                  float* __restrict__ er, int M) {
    __shared__ unsigned short Asm[128][40];
    __shared__ unsigned short Bsm[256][40];
    int t = threadIdx.x;
    int lane = t & 63, w = t >> 6;
    int wr = w >> 1, wc = w & 1;          // wave tile: 64 rows x 128 cols
    int m0 = blockIdx.x * 128;
    f32x4 acc[4][8] = {};

    for (int k0 = 0; k0 < 256; k0 += 32) {
#pragma unroll
        for (int c = 0; c < 4; c++) {
            int idx = c * 256 + t;
            int row = idx >> 3, col4 = (idx & 7) * 4;
            int gm = m0 + row;
            float4 v = make_float4(0.f, 0.f, 0.f, 0.f);
            if (gm < M) v = *reinterpret_cast<const float4*>(A + (size_t)gm * 256 + k0 + col4);
            ushort4 b;
            b.x = f2b(v.x); b.y = f2b(v.y); b.z = f2b(v.z); b.w = f2b(v.w);
            *reinterpret_cast<ushort4*>(&Asm[row][col4]) = b;
        }
#pragma unroll
        for (int c = 0; c < 4; c++) {
            int chunk = t + c * 256;
            int row = chunk >> 2, col8 = (chunk & 3) * 8;
            uint4 vb = *reinterpret_cast<const uint4*>(BT + (size_t)row * 256 + k0 + col8);
            *reinterpret_cast<uint4*>(&Bsm[row][col8]) = vb;
        }
        __syncthreads();
        int koff = (lane >> 4) * 8;
        int rsub = lane & 15;
        short8 a[4], b[8];
#pragma unroll
        for (int mi = 0; mi < 4; mi++)
            a[mi] = *reinterpret_cast<const short8*>(&Asm[wr * 64 + mi * 16 + rsub][koff]);
#pragma unroll
        for (int ni = 0; ni < 8; ni++)
            b[ni] = *reinterpret_cast<const short8*>(&Bsm[wc * 128 + ni * 16 + rsub][koff]);
#pragma unroll
        for (int mi = 0; mi < 4; mi++)
#pragma unroll
            for (int ni = 0; ni < 8; ni++)
                acc[mi][ni] = __builtin_amdgcn_mfma_f32_16x16x32_bf16(a[mi], b[ni], acc[mi][ni], 0, 0, 0);
        __syncthreads();
    }
    int rgrp = (lane >> 4) * 4, csub = lane & 15;

    // attention-coefficient registers for this wave's 4 heads (wc*4 .. wc*4+3)
    float cal[4][2], car[4][2];
#pragma unroll
    for (int hp = 0; hp < 4; hp++) {
        int h = wc * 4 + hp;
        cal[hp][0] = al[h * 32 + csub];      cal[hp][1] = al[h * 32 + 16 + csub];
        car[hp][0] = ar[h * 32 + csub];      car[hp][1] = ar[h * 32 + 16 + csub];
    }

#pragma unroll
    for (int mi = 0; mi < 4; mi++) {
#pragma unroll
        for (int i = 0; i < 4; i++) {
            int r = m0 + wr * 64 + mi * 16 + rgrp + i;
            bool ok = r < M;
            // fp8 feature write (standard channel order)
            if (ok) {
                size_t base = (size_t)r * 256 + wc * 128 + csub;
#pragma unroll
                for (int ni = 0; ni < 8; ni++)
                    F8[base + ni * 16] = f2e4m3(acc[mi][ni][i]);
            }
            // el/er: per head hp, cols {2hp,2hp+1}*16+csub, reduce over csub
#pragma unroll
            for (int hp = 0; hp < 4; hp++) {
                float pl = acc[mi][2 * hp][i] * cal[hp][0] + acc[mi][2 * hp + 1][i] * cal[hp][1];
                float pr = acc[mi][2 * hp][i] * car[hp][0] + acc[mi][2 * hp + 1][i] * car[hp][1];
                pl += __shfl_xor(pl, 1); pl += __shfl_xor(pl, 2);
                pl += __shfl_xor(pl, 4); pl += __shfl_xor(pl, 8);
                pr += __shfl_xor(pr, 1); pr += __shfl_xor(pr, 2);
                pr += __shfl_xor(pr, 4); pr += __shfl_xor(pr, 8);
                if (csub == 0 && ok) {
                    el[r * 8 + wc * 4 + hp] = pl;
                    er[r * 8 + wc * 4 + hp] = pr;
                }
            }
        }
    }
}

// ---------------- GEMM2 + fused el2/er2: feat2p[M,64] = h1bf[M,256] @ W2 ----------------
__global__ __launch_bounds__(256) void gemm2_k(const unsigned short* __restrict__ A,
                                               const float* __restrict__ B,
                                               const float* __restrict__ al2,
                                               const float* __restrict__ ar2,
                                               unsigned short* __restrict__ C,
                                               float* __restrict__ el2,
                                               float* __restrict__ er2, int M) {
    __shared__ float As[32][65];   // [k][row]
    __shared__ float Bs[32][64];
    __shared__ float Pl[4][64], Pr[4][64];
    int t = threadIdx.x;
    int row = t & 63, cg = t >> 6;   // 4 col groups x 16 cols
    int m0 = blockIdx.x * 64;
    float acc[16] = {};
    for (int k0 = 0; k0 < 256; k0 += 32) {
        {
            int r = t >> 2, c0 = (t & 3) * 8;
            int m = m0 + r;
            uint4 v = make_uint4(0, 0, 0, 0);
            if (m < M) v = *reinterpret_cast<const uint4*>(A + (size_t)m * 256 + k0 + c0);
            const unsigned short* pv = reinterpret_cast<const unsigned short*>(&v);
#pragma unroll
            for (int i = 0; i < 8; i++) As[c0 + i][r] = b2f(pv[i]);
        }
        for (int l = t; l < 32 * 64; l += 256) {
            int r = l >> 6, c = l & 63;
            Bs[r][c] = (c < 40) ? B[(k0 + r) * 40 + c] : 0.f;
        }
        __syncthreads();
#pragma unroll
        for (int kk = 0; kk < 32; kk++) {
            float a = As[kk][row];
#pragma unroll
            for (int j = 0; j < 16; j++) acc[j] += a * Bs[kk][cg * 16 + j];
        }
        __syncthreads();
    }
    int m = m0 + row;
    float pl = 0.f, pr = 0.f;
#pragma unroll
    for (int j = 0; j < 16; j++) {
        int col = cg * 16 + j;
        if (col < 40) { pl += acc[j] * al2[col]; pr += acc[j] * ar2[col]; }
    }
    Pl[cg][row] = pl; Pr[cg][row] = pr;
    if (m < M) {
#pragma unroll
        for (int j = 0; j < 16; j++) C[(size_t)m * 64 + cg * 16 + j] = f2b(acc[j]);
    }
    __syncthreads();
    if (cg == 0 && m < M) {
        el2[m] = Pl[0][row] + Pl[1][row] + Pl[2][row];
        er2[m] = Pr[0][row] + Pr[1][row] + Pr[2][row];
    }
}

// ---------------- CSR build: histogram, scan, scatter ----------------
__global__ void hist_k(const int* __restrict__ dst, int* __restrict__ deg) {
    int e = blockIdx.x * blockDim.x + threadIdx.x;
    if (e < N_EDGES) atomicAdd(&deg[dst[e]], 1);
}

__global__ void scan1_k(const int* __restrict__ deg, int* __restrict__ offs,
                        int* __restrict__ bsum, int n) {
    __shared__ int s[256];
    int tid = threadIdx.x;
    int i = blockIdx.x * 256 + tid;
    int v = (i < n) ? deg[i] : 0;
    s[tid] = v;
    __syncthreads();
    for (int d = 1; d < 256; d <<= 1) {
        int t = (tid >= d) ? s[tid - d] : 0;
        __syncthreads();
        s[tid] += t;
        __syncthreads();
    }
    if (i < n) offs[i] = s[tid] - v;
    if (tid == 255) bsum[blockIdx.x] = s[255];
}

__global__ void scan2_k(int* __restrict__ bsum, int nb) {
    __shared__ int s[256];
    int tid = threadIdx.x;
    int v = (tid < nb) ? bsum[tid] : 0;
    s[tid] = v;
    __syncthreads();
    for (int d = 1; d < 256; d <<= 1) {
        int t = (tid >= d) ? s[tid - d] : 0;
        __syncthreads();
        s[tid] += t;
        __syncthreads();
    }
    if (tid < nb) bsum[tid] = s[tid] - v;
}

__global__ void scan3_k(int* __restrict__ offs, const int* __restrict__ bsum,
                        int* __restrict__ cur, int n) {
    int i = blockIdx.x * 256 + threadIdx.x;
    if (i < n) { offs[i] += bsum[blockIdx.x]; cur[i] = 0; }
    if (i == 0) offs[n] = N_EDGES;
}

__global__ void scatter_k(const int* __restrict__ src, const int* __restrict__ dst,
                          const int* __restrict__ offs, int* __restrict__ cur,
                          int* __restrict__ ssorted) {
    int e = blockIdx.x * blockDim.x + threadIdx.x;
    if (e < N_EDGES) {
        int d = dst[e];
        int p = atomicAdd(&cur[d], 1);
        ssorted[offs[d] + p] = src[e];
    }
}

// ---------------- layer-1 attention aggregate (fp8 gather): 1 wave per dst node ------
__global__ __launch_bounds__(256) void agg1_k(const unsigned char* __restrict__ feat8,
                                              const float* __restrict__ el,
                                              const float* __restrict__ er,
                                              const int* __restrict__ offs,
                                              const int* __restrict__ ssorted,
                                              unsigned short* __restrict__ h1) {
    __shared__ float sa[4][CAP1 * 8];
    __shared__ int   ss[4][CAP1];
    int t = threadIdx.x;
    int wv = t >> 6, lane = t & 63;
    int n = blockIdx.x * 4 + wv;
    if (n >= N_NODES) return;
    int beg = offs[n];
    int deg = offs[n + 1] - beg;
    int eloc = lane >> 3, h = lane & 7, ch_h = lane >> 3;
    float er_h = er[n * 8 + h];

    float acc0 = 0.f, acc1 = 0.f, acc2 = 0.f, acc3 = 0.f;

    if (deg <= CAP1) {
        // pass A: exp-sum (no max-sub: e bounded), stash ee and src in LDS
        float ssum = 0.f;
        for (int c0 = 0; c0 < deg; c0 += 8) {
            int idx = c0 + eloc;
            bool act = idx < deg;
            float ee = 0.f;
            if (act) {
                int s = ssorted[beg + idx];
                if (h == 0) ss[wv][idx] = s;
                ee = __expf(leaky(el[s * 8 + h] + er_h));
                sa[wv][idx * 8 + h] = ee;
            }
            float sc = ee;
            sc += __shfl_xor(sc, 8);
            sc += __shfl_xor(sc, 16);
            sc += __shfl_xor(sc, 32);
            ssum += sc;
        }
        float inv = 1.f / ssum;
        float iv = __shfl(inv, ch_h);   // inverse denominator for this lane's channel-head
        asm volatile("s_waitcnt lgkmcnt(0)" ::: "memory");
        // pass B: 16 edges per batch, 4B fp8 per lane (channels 4*lane..4*lane+3)
        for (int c0 = 0; c0 < deg; c0 += 16) {
            int nr = deg - c0; if (nr > 16) nr = 16;
            unsigned u[16]; float av[16];
#pragma unroll
            for (int j = 0; j < 16; j++) {
                if (j < nr) {
                    int sj = ss[wv][c0 + j];
                    av[j] = sa[wv][(c0 + j) * 8 + ch_h];
                    u[j] = *reinterpret_cast<const unsigned*>(feat8 + (size_t)sj * 256 + 4 * lane);
                }
            }
#pragma unroll
            for (int j = 0; j < 16; j++) {
                if (j < nr) {
                    float wj = av[j] * iv;
                    floatx2 lo = __builtin_amdgcn_cvt_pk_f32_fp8((int)u[j], false);
                    floatx2 hi = __builtin_amdgcn_cvt_pk_f32_fp8((int)u[j], true);
                    acc0 += wj * lo.x;
                    acc1 += wj * lo.y;
                    acc2 += wj * hi.x;
                    acc3 += wj * hi.y;
                }
            }
        }
    } else {
        // fallback (deg > CAP1): recompute alphas
        float ssum = 0.f;
        for (int c0 = 0; c0 < deg; c0 += 8) {
            bool act = (c0 + eloc) < deg;
            float ee = 0.f;
            if (act) {
                int s = ssorted[beg + c0 + eloc];
                ee = __expf(leaky(el[s * 8 + h] + er_h));
            }
            float sc = ee;
            sc += __shfl_xor(sc, 8);
            sc += __shfl_xor(sc, 16);
            sc += __shfl_xor(sc, 32);
            ssum += sc;
        }
        float inv = 1.f / ssum;
        float iv = __shfl(inv, ch_h);
        for (int c0 = 0; c0 < deg; c0 += 8) {
            int nr = deg - c0; if (nr > 8) nr = 8;
            int s = 0; float a = 0.f;
            if (eloc < nr) {
                s = ssorted[beg + c0 + eloc];
                a = __expf(leaky(el[s * 8 + h] + er_h));
            }
#pragma unroll
            for (int j = 0; j < 8; j++) {
                if (j < nr) {
                    int   sj = __shfl(s, j * 8);
                    float aj = __shfl(a, j * 8 + ch_h) * iv;
                    unsigned u = *reinterpret_cast<const unsigned*>(feat8 + (size_t)sj * 256 + 4 * lane);
                    floatx2 lo = __builtin_amdgcn_cvt_pk_f32_fp8((int)u, false);
                    floatx2 hi = __builtin_amdgcn_cvt_pk_f32_fp8((int)u, true);
                    acc0 += aj * lo.x;
                    acc1 += aj * lo.y;
                    acc2 += aj * hi.x;
                    acc3 += aj * hi.y;
                }
            }
        }
    }
    ushort4 o;
    o.x = f2b(fmaxf(acc0, 0.f));   // fused relu
    o.y = f2b(fmaxf(acc1, 0.f));
    o.z = f2b(fmaxf(acc2, 0.f));
    o.w = f2b(fmaxf(acc3, 0.f));
    *reinterpret_cast<ushort4*>(h1 + (size_t)n * 256 + 4 * lane) = o;
}

// ---------------- layer-2 attention aggregate + log_softmax ----------------
__global__ __launch_bounds__(256) void agg2_k(const unsigned short* __restrict__ feat2p,
                                              const float* __restrict__ el2,
                                              const float* __restrict__ er2,
                                              const int* __restrict__ offs,
                                              const int* __restrict__ ssorted,
                                              float* __restrict__ out) {
    __shared__ float sa[4][CAP2];
    __shared__ int   ss[4][CAP2];
    int t = threadIdx.x;
    int wv = t >> 6, lane = t & 63;
    int n = blockIdx.x * 4 + wv;
    if (n >= N_NODES) return;
    int beg = offs[n];
    int deg = offs[n + 1] - beg;
    float ern = er2[n];
    int eloc = lane >> 3, c8 = lane & 7;

    float acc[8] = {};
    if (deg <= CAP2) {
        float ssum = 0.f;
        for (int c0 = 0; c0 < deg; c0 += 64) {
            int idx = c0 + lane;
            bool act = idx < deg;
            float ee = 0.f;
            if (act) {
                int s = ssorted[beg + idx];
                ss[wv][idx] = s;
                ee = __expf(leaky(el2[s] + ern));
                sa[wv][idx] = ee;
            }
            float sc = ee;
#pragma unroll
            for (int d = 1; d < 64; d <<= 1) sc += __shfl_xor(sc, d);
            ssum += sc;
        }
        float inv = 1.f / ssum;
        asm volatile("s_waitcnt lgkmcnt(0)" ::: "memory");
        // pass B: 16 edges per batch, 2 independent 16B row-chunk loads per lane
        for (int c0 = 0; c0 < deg; c0 += 16) {
            int i0 = c0 + eloc, i1 = c0 + 8 + eloc;
            uint4 v0 = make_uint4(0, 0, 0, 0), v1 = make_uint4(0, 0, 0, 0);
            float w0 = 0.f, w1 = 0.f;
            if (i0 < deg) {
                int s = ss[wv][i0]; w0 = sa[wv][i0] * inv;
                v0 = *reinterpret_cast<const uint4*>(feat2p + (size_t)s * 64 + c8 * 8);
            }
            if (i1 < deg) {
                int s = ss[wv][i1]; w1 = sa[wv][i1] * inv;
                v1 = *reinterpret_cast<const uint4*>(feat2p + (size_t)s * 64 + c8 * 8);
            }
            const unsigned short* p0 = reinterpret_cast<const unsigned short*>(&v0);
            const unsigned short* p1 = reinterpret_cast<const unsigned short*>(&v1);
#pragma unroll
            for (int i = 0; i < 8; i++) acc[i] += w0 * b2f(p0[i]) + w1 * b2f(p1[i]);
        }
    } else {
        float ssum = 0.f;
        for (int c0 = 0; c0 < deg; c0 += 64) {
            bool act = (c0 + lane) < deg;
            float ee = 0.f;
            if (act) ee = __expf(leaky(el2[ssorted[beg + c0 + lane]] + ern));
            float sc = ee;
#pragma unroll
            for (int d = 1; d < 64; d <<= 1) sc += __shfl_xor(sc, d);
            ssum += sc;
        }
        float inv = 1.f / ssum;
        for (int c0 = 0; c0 < deg; c0 += 8) {
            int nr = deg - c0; if (nr > 8) nr = 8;
            if (eloc < nr) {
                int s = ssorted[beg + c0 + eloc];
                float a = __expf(leaky(el2[s] + ern)) * inv;
                uint4 v = *reinterpret_cast<const uint4*>(feat2p + (size_t)s * 64 + c8 * 8);
                const unsigned short* pv = reinterpret_cast<const unsigned short*>(&v);
#pragma unroll
                for (int i = 0; i < 8; i++) acc[i] += a * b2f(pv[i]);
            }
        }
    }
    // reduce over edge groups (lanes differing in bits 3..5)
#pragma unroll
    for (int i = 0; i < 8; i++) {
        acc[i] += __shfl_xor(acc[i], 8);
        acc[i] += __shfl_xor(acc[i], 16);
        acc[i] += __shfl_xor(acc[i], 32);
    }
    // log_softmax over 40 real cols (c8 < 5)
    float lmax = -INFINITY;
    if (c8 < 5) {
#pragma unroll
        for (int i = 0; i < 8; i++) lmax = fmaxf(lmax, acc[i]);
    }
    lmax = fmaxf(lmax, __shfl_xor(lmax, 1));
    lmax = fmaxf(lmax, __shfl_xor(lmax, 2));
    lmax = fmaxf(lmax, __shfl_xor(lmax, 4));
    float lsum = 0.f;
    if (c8 < 5) {
#pragma unroll
        for (int i = 0; i < 8; i++) lsum += __expf(acc[i] - lmax);
    }
    lsum += __shfl_xor(lsum, 1);
    lsum += __shfl_xor(lsum, 2);
    lsum += __shfl_xor(lsum, 4);
    if (eloc == 0 && c8 < 5) {
        float lg = __logf(lsum);
        float* o = out + (size_t)n * 40 + c8 * 8;
#pragma unroll
        for (int i = 0; i < 8; i++) o[i] = acc[i] - lmax - lg;
    }
}

extern "C" void kernel_launch(void* const* d_in, const int* in_sizes, int n_in,
                              void* d_out, int out_size, void* d_ws, size_t ws_size,
                              hipStream_t stream) {
    (void)in_sizes; (void)n_in; (void)out_size; (void)ws_size;
    const float* x   = (const float*)d_in[0];
    const int*   src = (const int*)d_in[1];
    const int*   dst = (const int*)d_in[2];
    const float* W1  = (const float*)d_in[3];
    const float* al1 = (const float*)d_in[4];
    const float* ar1 = (const float*)d_in[5];
    const float* W2  = (const float*)d_in[6];
    const float* al2 = (const float*)d_in[7];
    const float* ar2 = (const float*)d_in[8];
    float* out = (float*)d_out;

    char* ws = (char*)d_ws;
    size_t off = 0;
    auto alloc = [&](size_t bytes) {
        void* p = ws + off;
        off += (bytes + 255) & ~(size_t)255;
        return p;
    };
    unsigned short* w1t    = (unsigned short*)alloc((size_t)256 * 256 * 2);
    unsigned char*  feat8  = (unsigned char*)alloc((size_t)N_NODES * 256);
    unsigned short* h1bf   = (unsigned short*)alloc((size_t)N_NODES * 256 * 2);
    unsigned short* feat2p = (unsigned short*)alloc((size_t)N_NODES * 64 * 2);
    float* el1   = (float*)alloc((size_t)N_NODES * 8 * 4);
    float* er1   = (float*)alloc((size_t)N_NODES * 8 * 4);
    float* el2   = (float*)alloc((size_t)N_NODES * 4);
    float* er2   = (float*)alloc((size_t)N_NODES * 4);
    int* deg     = (int*)alloc((size_t)N_NODES * 4);
    int* offs    = (int*)alloc((size_t)(N_NODES + 1) * 4);
    int* cur     = (int*)alloc((size_t)N_NODES * 4);
    int* bsum    = (int*)alloc(1024 * 4);
    int* ssorted = (int*)alloc((size_t)N_EDGES * 4);

    hipMemsetAsync(deg, 0, (size_t)N_NODES * 4, stream);

    cvt_w1t_k<<<256, 256, 0, stream>>>(W1, w1t);

    // CSR by dst
    hist_k<<<(N_EDGES + 255) / 256, 256, 0, stream>>>(dst, deg);
    int nb = (N_NODES + 255) / 256;
    scan1_k<<<nb, 256, 0, stream>>>(deg, offs, bsum, N_NODES);
    scan2_k<<<1, 256, 0, stream>>>(bsum, nb);
    scan3_k<<<nb, 256, 0, stream>>>(offs, bsum, cur, N_NODES);
    scatter_k<<<(N_EDGES + 255) / 256, 256, 0, stream>>>(src, dst, offs, cur, ssorted);

    // layer 1
    gemm1_mfma<<<(N_NODES + 127) / 128, 256, 0, stream>>>(x, w1t, al1, ar1, feat8, el1, er1, N_NODES);
    agg1_k<<<(N_NODES + 3) / 4, 256, 0, stream>>>(feat8, el1, er1, offs, ssorted, h1bf);

    // layer 2
    gemm2_k<<<(N_NODES + 63) / 64, 256, 0, stream>>>(h1bf, W2, al2, ar2, feat2p, el2, er2, N_NODES);
    agg2_k<<<(N_NODES + 3) / 4, 256, 0, stream>>>(feat2p, el2, er2, offs, ssorted, out);
}

// Round 6
// 272.846 us; speedup vs baseline: 1.9063x; 1.0072x over previous
//
#include <hip/hip_runtime.h>
#include <hip/hip_bf16.h>
#include <math.h>

#define N_NODES 50000
#define N_EDGES 800000
#define IN_DIM  256
#define HID     32
#define HEADS   8
#define NCLS    40
#define NEG     0.2f
#define CAP1    128
#define CAP2    128

using short8  = __attribute__((ext_vector_type(8))) short;
using f32x4   = __attribute__((ext_vector_type(4))) float;
using floatx2 = __attribute__((ext_vector_type(2))) float;

__device__ __forceinline__ float leaky(float x) { return x >= 0.f ? x : NEG * x; }
__device__ __forceinline__ unsigned short f2b(float f) {
    unsigned int u = __float_as_uint(f);
    unsigned int r = (u + 0x7fffu + ((u >> 16) & 1u)) >> 16;
    return (unsigned short)r;
}
__device__ __forceinline__ float b2f(unsigned short h) {
    return __uint_as_float((unsigned int)h << 16);
}
__device__ __forceinline__ unsigned char f2e4m3(float v) {
    int p = __builtin_amdgcn_cvt_pk_fp8_f32(v, v, 0, false);
    return (unsigned char)(p & 0xff);
}

// W1T[n][k] = bf16(W1[k][n]); W1 is [256][256]
__global__ void cvt_w1t_k(const float* __restrict__ W1, unsigned short* __restrict__ W1T) {
    int k = blockIdx.x, n = threadIdx.x;
    W1T[n * 256 + k] = f2b(W1[k * 256 + n]);
}

// ---------------- GEMM1 (MFMA bf16) -> fp8 feat1 ----------------
// feat8[M,256] (e4m3) = quant(bf16(x) @ W1)
__global__ __launch_bounds__(256) void gemm1_mfma(const float* __restrict__ A,
                                                  const unsigned short* __restrict__ BT,
                                                  unsigned char* __restrict__ F8, int M) {
    __shared__ unsigned short Asm[128][40];
    __shared__ unsigned short Bsm[256][40];
    int t = threadIdx.x;
    int lane = t & 63, w = t >> 6;
    int wr = w >> 1, wc = w & 1;          // wave tile: 64 rows x 128 cols
    int m0 = blockIdx.x * 128;
    f32x4 acc[4][8] = {};

    for (int k0 = 0; k0 < 256; k0 += 32) {
#pragma unroll
        for (int c = 0; c < 4; c++) {
            int idx = c * 256 + t;
            int row = idx >> 3, col4 = (idx & 7) * 4;
            int gm = m0 + row;
            float4 v = make_float4(0.f, 0.f, 0.f, 0.f);
            if (gm < M) v = *reinterpret_cast<const float4*>(A + (size_t)gm * 256 + k0 + col4);
            ushort4 b;
            b.x = f2b(v.x); b.y = f2b(v.y); b.z = f2b(v.z); b.w = f2b(v.w);
            *reinterpret_cast<ushort4*>(&Asm[row][col4]) = b;
        }
#pragma unroll
        for (int c = 0; c < 4; c++) {
            int chunk = t + c * 256;
            int row = chunk >> 2, col8 = (chunk & 3) * 8;
            uint4 vb = *reinterpret_cast<const uint4*>(BT + (size_t)row * 256 + k0 + col8);
            *reinterpret_cast<uint4*>(&Bsm[row][col8]) = vb;
        }
        __syncthreads();
        int koff = (lane >> 4) * 8;
        int rsub = lane & 15;
        short8 a[4], b[8];
#pragma unroll
        for (int mi = 0; mi < 4; mi++)
            a[mi] = *reinterpret_cast<const short8*>(&Asm[wr * 64 + mi * 16 + rsub][koff]);
#pragma unroll
        for (int ni = 0; ni < 8; ni++)
            b[ni] = *reinterpret_cast<const short8*>(&Bsm[wc * 128 + ni * 16 + rsub][koff]);
#pragma unroll
        for (int mi = 0; mi < 4; mi++)
#pragma unroll
            for (int ni = 0; ni < 8; ni++)
                acc[mi][ni] = __builtin_amdgcn_mfma_f32_16x16x32_bf16(a[mi], b[ni], acc[mi][ni], 0, 0, 0);
        __syncthreads();
    }
    int rgrp = (lane >> 4) * 4, csub = lane & 15;
#pragma unroll
    for (int mi = 0; mi < 4; mi++) {
#pragma unroll
        for (int i = 0; i < 4; i++) {
            int r = m0 + wr * 64 + mi * 16 + rgrp + i;
            if (r < M) {
                size_t base = (size_t)r * 256 + wc * 128 + csub;
#pragma unroll
                for (int ni = 0; ni < 8; ni++)
                    F8[base + ni * 16] = f2e4m3(acc[mi][ni][i]);
            }
        }
    }
}

// ---------------- el/er for layer 1 from fp8 feat ----------------
__global__ void elr1_k(const unsigned char* __restrict__ feat8, const float* __restrict__ al,
                       const float* __restrict__ ar, float* __restrict__ el,
                       float* __restrict__ er) {
    int idx = blockIdx.x * blockDim.x + threadIdx.x;   // n*8+h
    if (idx >= N_NODES * HEADS) return;
    int h = idx & 7;
    const uint4* p = reinterpret_cast<const uint4*>(feat8 + (size_t)(idx >> 3) * 256 + h * 32);
    uint4 v0 = p[0], v1 = p[1];
    const float* a = al + h * 32;
    const float* b = ar + h * 32;
    unsigned uu[8] = {v0.x, v0.y, v0.z, v0.w, v1.x, v1.y, v1.z, v1.w};
    float sl = 0.f, sr = 0.f;
#pragma unroll
    for (int q = 0; q < 8; q++) {
        floatx2 lo = __builtin_amdgcn_cvt_pk_f32_fp8((int)uu[q], false);
        floatx2 hi = __builtin_amdgcn_cvt_pk_f32_fp8((int)uu[q], true);
        sl += lo.x * a[q * 4] + lo.y * a[q * 4 + 1] + hi.x * a[q * 4 + 2] + hi.y * a[q * 4 + 3];
        sr += lo.x * b[q * 4] + lo.y * b[q * 4 + 1] + hi.x * b[q * 4 + 2] + hi.y * b[q * 4 + 3];
    }
    el[idx] = sl; er[idx] = sr;
}

// ---------------- GEMM2 + fused el2/er2: feat2p[M,64] = h1bf[M,256] @ W2 ----------------
__global__ __launch_bounds__(256) void gemm2_k(const unsigned short* __restrict__ A,
                                               const float* __restrict__ B,
                                               const float* __restrict__ al2,
                                               const float* __restrict__ ar2,
                                               unsigned short* __restrict__ C,
                                               float* __restrict__ el2,
                                               float* __restrict__ er2, int M) {
    __shared__ float As[32][65];   // [k][row]
    __shared__ float Bs[32][64];
    __shared__ float Pl[4][64], Pr[4][64];
    int t = threadIdx.x;
    int row = t & 63, cg = t >> 6;   // 4 col groups x 16 cols
    int m0 = blockIdx.x * 64;
    float acc[16] = {};
    for (int k0 = 0; k0 < 256; k0 += 32) {
        {
            int r = t >> 2, c0 = (t & 3) * 8;
            int m = m0 + r;
            uint4 v = make_uint4(0, 0, 0, 0);
            if (m < M) v = *reinterpret_cast<const uint4*>(A + (size_t)m * 256 + k0 + c0);
            const unsigned short* pv = reinterpret_cast<const unsigned short*>(&v);
#pragma unroll
            for (int i = 0; i < 8; i++) As[c0 + i][r] = b2f(pv[i]);
        }
        for (int l = t; l < 32 * 64; l += 256) {
            int r = l >> 6, c = l & 63;
            Bs[r][c] = (c < 40) ? B[(k0 + r) * 40 + c] : 0.f;
        }
        __syncthreads();
#pragma unroll
        for (int kk = 0; kk < 32; kk++) {
            float a = As[kk][row];
#pragma unroll
            for (int j = 0; j < 16; j++) acc[j] += a * Bs[kk][cg * 16 + j];
        }
        __syncthreads();
    }
    int m = m0 + row;
    float pl = 0.f, pr = 0.f;
#pragma unroll
    for (int j = 0; j < 16; j++) {
        int col = cg * 16 + j;
        if (col < 40) { pl += acc[j] * al2[col]; pr += acc[j] * ar2[col]; }
    }
    Pl[cg][row] = pl; Pr[cg][row] = pr;
    if (m < M) {
#pragma unroll
        for (int j = 0; j < 16; j++) C[(size_t)m * 64 + cg * 16 + j] = f2b(acc[j]);
    }
    __syncthreads();
    if (cg == 0 && m < M) {
        el2[m] = Pl[0][row] + Pl[1][row] + Pl[2][row];
        er2[m] = Pr[0][row] + Pr[1][row] + Pr[2][row];
    }
}

// ---------------- CSR build: histogram, scan, scatter ----------------
__global__ void hist_k(const int* __restrict__ dst, int* __restrict__ deg) {
    int e = blockIdx.x * blockDim.x + threadIdx.x;
    if (e < N_EDGES) atomicAdd(&deg[dst[e]], 1);
}

__global__ void scan1_k(const int* __restrict__ deg, int* __restrict__ offs,
                        int* __restrict__ bsum, int n) {
    __shared__ int s[256];
    int tid = threadIdx.x;
    int i = blockIdx.x * 256 + tid;
    int v = (i < n) ? deg[i] : 0;
    s[tid] = v;
    __syncthreads();
    for (int d = 1; d < 256; d <<= 1) {
        int t = (tid >= d) ? s[tid - d] : 0;
        __syncthreads();
        s[tid] += t;
        __syncthreads();
    }
    if (i < n) offs[i] = s[tid] - v;
    if (tid == 255) bsum[blockIdx.x] = s[255];
}

__global__ void scan2_k(int* __restrict__ bsum, int nb) {
    __shared__ int s[256];
    int tid = threadIdx.x;
    int v = (tid < nb) ? bsum[tid] : 0;
    s[tid] = v;
    __syncthreads();
    for (int d = 1; d < 256; d <<= 1) {
        int t = (tid >= d) ? s[tid - d] : 0;
        __syncthreads();
        s[tid] += t;
        __syncthreads();
    }
    if (tid < nb) bsum[tid] = s[tid] - v;
}

__global__ void scan3_k(int* __restrict__ offs, const int* __restrict__ bsum,
                        int* __restrict__ cur, int n) {
    int i = blockIdx.x * 256 + threadIdx.x;
    if (i < n) { offs[i] += bsum[blockIdx.x]; cur[i] = 0; }
    if (i == 0) offs[n] = N_EDGES;
}

__global__ void scatter_k(const int* __restrict__ src, const int* __restrict__ dst,
                          const int* __restrict__ offs, int* __restrict__ cur,
                          int* __restrict__ ssorted) {
    int e = blockIdx.x * blockDim.x + threadIdx.x;
    if (e < N_EDGES) {
        int d = dst[e];
        int p = atomicAdd(&cur[d], 1);
        ssorted[offs[d] + p] = src[e];
    }
}

// ---------------- layer-1 attention aggregate (fp8 gather): 1 wave per dst node ------
__global__ __launch_bounds__(256) void agg1_k(const unsigned char* __restrict__ feat8,
                                              const float* __restrict__ el,
                                              const float* __restrict__ er,
                                              const int* __restrict__ offs,
                                              const int* __restrict__ ssorted,
                                              unsigned short* __restrict__ h1) {
    __shared__ float sa[4][CAP1 * 8];
    __shared__ int   ss[4][CAP1];
    int t = threadIdx.x;
    int wv = t >> 6, lane = t & 63;
    int n = blockIdx.x * 4 + wv;
    if (n >= N_NODES) return;
    int beg = offs[n];
    int deg = offs[n + 1] - beg;
    int eloc = lane >> 3, h = lane & 7, ch_h = lane >> 3;
    float er_h = er[n * 8 + h];

    float acc0 = 0.f, acc1 = 0.f, acc2 = 0.f, acc3 = 0.f;

    if (deg <= CAP1) {
        // pass A: exp-sum (no max-sub: e bounded), stash ee and src in LDS
        float ssum = 0.f;
        for (int c0 = 0; c0 < deg; c0 += 8) {
            int idx = c0 + eloc;
            bool act = idx < deg;
            float ee = 0.f;
            if (act) {
                int s = ssorted[beg + idx];
                if (h == 0) ss[wv][idx] = s;
                ee = __expf(leaky(el[s * 8 + h] + er_h));
                sa[wv][idx * 8 + h] = ee;
            }
            float sc = ee;
            sc += __shfl_xor(sc, 8);
            sc += __shfl_xor(sc, 16);
            sc += __shfl_xor(sc, 32);
            ssum += sc;
        }
        float inv = 1.f / ssum;
        float iv = __shfl(inv, ch_h);   // inverse denominator for this lane's channel-head
        asm volatile("s_waitcnt lgkmcnt(0)" ::: "memory");
        // pass B: 16 edges per batch, 4B fp8 per lane (channels 4*lane..4*lane+3)
        for (int c0 = 0; c0 < deg; c0 += 16) {
            int nr = deg - c0; if (nr > 16) nr = 16;
            unsigned u[16]; float av[16];
#pragma unroll
            for (int j = 0; j < 16; j++) {
                if (j < nr) {
                    int sj = ss[wv][c0 + j];
                    av[j] = sa[wv][(c0 + j) * 8 + ch_h];
                    u[j] = *reinterpret_cast<const unsigned*>(feat8 + (size_t)sj * 256 + 4 * lane);
                }
            }
#pragma unroll
            for (int j = 0; j < 16; j++) {
                if (j < nr) {
                    float wj = av[j] * iv;
                    floatx2 lo = __builtin_amdgcn_cvt_pk_f32_fp8((int)u[j], false);
                    floatx2 hi = __builtin_amdgcn_cvt_pk_f32_fp8((int)u[j], true);
                    acc0 += wj * lo.x;
                    acc1 += wj * lo.y;
                    acc2 += wj * hi.x;
                    acc3 += wj * hi.y;
                }
            }
        }
    } else {
        // fallback (deg > CAP1): recompute alphas
        float ssum = 0.f;
        for (int c0 = 0; c0 < deg; c0 += 8) {
            bool act = (c0 + eloc) < deg;
            float ee = 0.f;
            if (act) {
                int s = ssorted[beg + c0 + eloc];
                ee = __expf(leaky(el[s * 8 + h] + er_h));
            }
            float sc = ee;
            sc += __shfl_xor(sc, 8);
            sc += __shfl_xor(sc, 16);
            sc += __shfl_xor(sc, 32);
            ssum += sc;
        }
        float inv = 1.f / ssum;
        float iv = __shfl(inv, ch_h);
        for (int c0 = 0; c0 < deg; c0 += 8) {
            int nr = deg - c0; if (nr > 8) nr = 8;
            int s = 0; float a = 0.f;
            if (eloc < nr) {
                s = ssorted[beg + c0 + eloc];
                a = __expf(leaky(el[s * 8 + h] + er_h));
            }
#pragma unroll
            for (int j = 0; j < 8; j++) {
                if (j < nr) {
                    int   sj = __shfl(s, j * 8);
                    float aj = __shfl(a, j * 8 + ch_h) * iv;
                    unsigned u = *reinterpret_cast<const unsigned*>(feat8 + (size_t)sj * 256 + 4 * lane);
                    floatx2 lo = __builtin_amdgcn_cvt_pk_f32_fp8((int)u, false);
                    floatx2 hi = __builtin_amdgcn_cvt_pk_f32_fp8((int)u, true);
                    acc0 += aj * lo.x;
                    acc1 += aj * lo.y;
                    acc2 += aj * hi.x;
                    acc3 += aj * hi.y;
                }
            }
        }
    }
    ushort4 o;
    o.x = f2b(fmaxf(acc0, 0.f));   // fused relu
    o.y = f2b(fmaxf(acc1, 0.f));
    o.z = f2b(fmaxf(acc2, 0.f));
    o.w = f2b(fmaxf(acc3, 0.f));
    *reinterpret_cast<ushort4*>(h1 + (size_t)n * 256 + 4 * lane) = o;
}

// ---------------- layer-2 attention aggregate + log_softmax ----------------
__global__ __launch_bounds__(256) void agg2_k(const unsigned short* __restrict__ feat2p,
                                              const float* __restrict__ el2,
                                              const float* __restrict__ er2,
                                              const int* __restrict__ offs,
                                              const int* __restrict__ ssorted,
                                              float* __restrict__ out) {
    __shared__ float sa[4][CAP2];
    __shared__ int   ss[4][CAP2];
    int t = threadIdx.x;
    int wv = t >> 6, lane = t & 63;
    int n = blockIdx.x * 4 + wv;
    if (n >= N_NODES) return;
    int beg = offs[n];
    int deg = offs[n + 1] - beg;
    float ern = er2[n];
    int eloc = lane >> 3, c8 = lane & 7;

    float acc[8] = {};
    if (deg <= CAP2) {
        float ssum = 0.f;
        for (int c0 = 0; c0 < deg; c0 += 64) {
            int idx = c0 + lane;
            bool act = idx < deg;
            float ee = 0.f;
            if (act) {
                int s = ssorted[beg + idx];
                ss[wv][idx] = s;
                ee = __expf(leaky(el2[s] + ern));
                sa[wv][idx] = ee;
            }
            float sc = ee;
#pragma unroll
            for (int d = 1; d < 64; d <<= 1) sc += __shfl_xor(sc, d);
            ssum += sc;
        }
        float inv = 1.f / ssum;
        asm volatile("s_waitcnt lgkmcnt(0)" ::: "memory");
        // pass B: 16 edges per batch, 2 independent 16B row-chunk loads per lane
        for (int c0 = 0; c0 < deg; c0 += 16) {
            int i0 = c0 + eloc, i1 = c0 + 8 + eloc;
            uint4 v0 = make_uint4(0, 0, 0, 0), v1 = make_uint4(0, 0, 0, 0);
            float w0 = 0.f, w1 = 0.f;
            if (i0 < deg) {
                int s = ss[wv][i0]; w0 = sa[wv][i0] * inv;
                v0 = *reinterpret_cast<const uint4*>(feat2p + (size_t)s * 64 + c8 * 8);
            }
            if (i1 < deg) {
                int s = ss[wv][i1]; w1 = sa[wv][i1] * inv;
                v1 = *reinterpret_cast<const uint4*>(feat2p + (size_t)s * 64 + c8 * 8);
            }
            const unsigned short* p0 = reinterpret_cast<const unsigned short*>(&v0);
            const unsigned short* p1 = reinterpret_cast<const unsigned short*>(&v1);
#pragma unroll
            for (int i = 0; i < 8; i++) acc[i] += w0 * b2f(p0[i]) + w1 * b2f(p1[i]);
        }
    } else {
        float ssum = 0.f;
        for (int c0 = 0; c0 < deg; c0 += 64) {
            bool act = (c0 + lane) < deg;
            float ee = 0.f;
            if (act) ee = __expf(leaky(el2[ssorted[beg + c0 + lane]] + ern));
            float sc = ee;
#pragma unroll
            for (int d = 1; d < 64; d <<= 1) sc += __shfl_xor(sc, d);
            ssum += sc;
        }
        float inv = 1.f / ssum;
        for (int c0 = 0; c0 < deg; c0 += 8) {
            int nr = deg - c0; if (nr > 8) nr = 8;
            if (eloc < nr) {
                int s = ssorted[beg + c0 + eloc];
                float a = __expf(leaky(el2[s] + ern)) * inv;
                uint4 v = *reinterpret_cast<const uint4*>(feat2p + (size_t)s * 64 + c8 * 8);
                const unsigned short* pv = reinterpret_cast<const unsigned short*>(&v);
#pragma unroll
                for (int i = 0; i < 8; i++) acc[i] += a * b2f(pv[i]);
            }
        }
    }
    // reduce over edge groups (lanes differing in bits 3..5)
#pragma unroll
    for (int i = 0; i < 8; i++) {
        acc[i] += __shfl_xor(acc[i], 8);
        acc[i] += __shfl_xor(acc[i], 16);
        acc[i] += __shfl_xor(acc[i], 32);
    }
    // log_softmax over 40 real cols (c8 < 5)
    float lmax = -INFINITY;
    if (c8 < 5) {
#pragma unroll
        for (int i = 0; i < 8; i++) lmax = fmaxf(lmax, acc[i]);
    }
    lmax = fmaxf(lmax, __shfl_xor(lmax, 1));
    lmax = fmaxf(lmax, __shfl_xor(lmax, 2));
    lmax = fmaxf(lmax, __shfl_xor(lmax, 4));
    float lsum = 0.f;
    if (c8 < 5) {
#pragma unroll
        for (int i = 0; i < 8; i++) lsum += __expf(acc[i] - lmax);
    }
    lsum += __shfl_xor(lsum, 1);
    lsum += __shfl_xor(lsum, 2);
    lsum += __shfl_xor(lsum, 4);
    if (eloc == 0 && c8 < 5) {
        float lg = __logf(lsum);
        float* o = out + (size_t)n * 40 + c8 * 8;
#pragma unroll
        for (int i = 0; i < 8; i++) o[i] = acc[i] - lmax - lg;
    }
}

extern "C" void kernel_launch(void* const* d_in, const int* in_sizes, int n_in,
                              void* d_out, int out_size, void* d_ws, size_t ws_size,
                              hipStream_t stream) {
    (void)in_sizes; (void)n_in; (void)out_size; (void)ws_size;
    const float* x   = (const float*)d_in[0];
    const int*   src = (const int*)d_in[1];
    const int*   dst = (const int*)d_in[2];
    const float* W1  = (const float*)d_in[3];
    const float* al1 = (const float*)d_in[4];
    const float* ar1 = (const float*)d_in[5];
    const float* W2  = (const float*)d_in[6];
    const float* al2 = (const float*)d_in[7];
    const float* ar2 = (const float*)d_in[8];
    float* out = (float*)d_out;

    char* ws = (char*)d_ws;
    size_t off = 0;
    auto alloc = [&](size_t bytes) {
        void* p = ws + off;
        off += (bytes + 255) & ~(size_t)255;
        return p;
    };
    unsigned short* w1t    = (unsigned short*)alloc((size_t)256 * 256 * 2);
    unsigned char*  feat8  = (unsigned char*)alloc((size_t)N_NODES * 256);
    unsigned short* h1bf   = (unsigned short*)alloc((size_t)N_NODES * 256 * 2);
    unsigned short* feat2p = (unsigned short*)alloc((size_t)N_NODES * 64 * 2);
    float* el1   = (float*)alloc((size_t)N_NODES * 8 * 4);
    float* er1   = (float*)alloc((size_t)N_NODES * 8 * 4);
    float* el2   = (float*)alloc((size_t)N_NODES * 4);
    float* er2   = (float*)alloc((size_t)N_NODES * 4);
    int* deg     = (int*)alloc((size_t)N_NODES * 4);
    int* offs    = (int*)alloc((size_t)(N_NODES + 1) * 4);
    int* cur     = (int*)alloc((size_t)N_NODES * 4);
    int* bsum    = (int*)alloc(1024 * 4);
    int* ssorted = (int*)alloc((size_t)N_EDGES * 4);

    hipMemsetAsync(deg, 0, (size_t)N_NODES * 4, stream);

    cvt_w1t_k<<<256, 256, 0, stream>>>(W1, w1t);

    // CSR by dst
    hist_k<<<(N_EDGES + 255) / 256, 256, 0, stream>>>(dst, deg);
    int nb = (N_NODES + 255) / 256;
    scan1_k<<<nb, 256, 0, stream>>>(deg, offs, bsum, N_NODES);
    scan2_k<<<1, 256, 0, stream>>>(bsum, nb);
    scan3_k<<<nb, 256, 0, stream>>>(offs, bsum, cur, N_NODES);
    scatter_k<<<(N_EDGES + 255) / 256, 256, 0, stream>>>(src, dst, offs, cur, ssorted);

    // layer 1
    gemm1_mfma<<<(N_NODES + 127) / 128, 256, 0, stream>>>(x, w1t, feat8, N_NODES);
    elr1_k<<<(N_NODES * 8 + 255) / 256, 256, 0, stream>>>(feat8, al1, ar1, el1, er1);
    agg1_k<<<(N_NODES + 3) / 4, 256, 0, stream>>>(feat8, el1, er1, offs, ssorted, h1bf);

    // layer 2
    gemm2_k<<<(N_NODES + 63) / 64, 256, 0, stream>>>(h1bf, W2, al2, ar2, feat2p, el2, er2, N_NODES);
    agg2_k<<<(N_NODES + 3) / 4, 256, 0, stream>>>(feat2p, el2, er2, offs, ssorted, out);
}

// Round 7
// 271.880 us; speedup vs baseline: 1.9130x; 1.0036x over previous
//
#include <hip/hip_runtime.h>
#include <hip/hip_bf16.h>
#include <math.h>

#define N_NODES 50000
#define N_EDGES 800000
#define IN_DIM  256
#define HID     32
#define HEADS   8
#define NCLS    40
#define NEG     0.2f
#define CAP1    128
#define CAP2    128

using short8  = __attribute__((ext_vector_type(8))) short;
using f32x4   = __attribute__((ext_vector_type(4))) float;
using floatx2 = __attribute__((ext_vector_type(2))) float;

__device__ __forceinline__ float leaky(float x) { return x >= 0.f ? x : NEG * x; }
__device__ __forceinline__ unsigned short f2b(float f) {
    unsigned int u = __float_as_uint(f);
    unsigned int r = (u + 0x7fffu + ((u >> 16) & 1u)) >> 16;
    return (unsigned short)r;
}
__device__ __forceinline__ float b2f(unsigned short h) {
    return __uint_as_float((unsigned int)h << 16);
}

// Permuted fp8 storage: channel c = half*128 + ni*16 + csub  (half=c>>7, ni 0..7, csub 0..15)
// stored at offset        s = half*128 + csub*8 + ni
// => a lane reading 4B at s=4L gets csub=(L&31)>>1, ni=4*(L&1)+q, heads h0=(L>>5)*4+2*(L&1) (+1 for q>=2)

// W1T[n][k] = bf16(W1[k][n]); W1 is [256][256]
__global__ void cvt_w1t_k(const float* __restrict__ W1, unsigned short* __restrict__ W1T) {
    int k = blockIdx.x, n = threadIdx.x;
    W1T[n * 256 + k] = f2b(W1[k * 256 + n]);
}

// ---------------- GEMM1 (MFMA bf16) -> permuted fp8 feat1 ----------------
// 64-row tile, 4 waves (wave = 32 rows x 128 cols), B direct from L2, A LDS dbuf.
__global__ __launch_bounds__(256) void gemm1_mfma(const float* __restrict__ A,
                                                  const unsigned short* __restrict__ BT,
                                                  unsigned char* __restrict__ F8, int M) {
    __shared__ unsigned short Asm[2][64][40];
    int t = threadIdx.x;
    int lane = t & 63, w = t >> 6;
    int wr = w >> 1, wc = w & 1;          // wave tile: 32 rows x 128 cols
    int m0 = blockIdx.x * 64;
    int rsub = lane & 15, koff = (lane >> 4) * 8;
    f32x4 acc[2][8] = {};

    // A staging map: thread covers row r_t = t>>2, cols (t&3)*8 .. +7
    int r_t = t >> 2, c8 = (t & 3) * 8;
    const float* ap = A + (size_t)(m0 + r_t) * 256 + c8;
    bool arow_ok = (m0 + r_t) < M;

    float4 s0 = make_float4(0.f, 0.f, 0.f, 0.f), s1 = s0;
    if (arow_ok) { s0 = *reinterpret_cast<const float4*>(ap); s1 = *reinterpret_cast<const float4*>(ap + 4); }
    {
        short8 bb;
        bb[0] = (short)f2b(s0.x); bb[1] = (short)f2b(s0.y); bb[2] = (short)f2b(s0.z); bb[3] = (short)f2b(s0.w);
        bb[4] = (short)f2b(s1.x); bb[5] = (short)f2b(s1.y); bb[6] = (short)f2b(s1.z); bb[7] = (short)f2b(s1.w);
        *reinterpret_cast<short8*>(&Asm[0][r_t][c8]) = bb;
    }
    __syncthreads();

    for (int kt = 0; kt < 8; ++kt) {
        if (kt < 7) {
            s0 = make_float4(0.f, 0.f, 0.f, 0.f); s1 = s0;
            if (arow_ok) {
                const float* p = ap + (kt + 1) * 32;
                s0 = *reinterpret_cast<const float4*>(p);
                s1 = *reinterpret_cast<const float4*>(p + 4);
            }
        }
        short8 b[8], a[2];
#pragma unroll
        for (int ni = 0; ni < 8; ni++)
            b[ni] = *reinterpret_cast<const short8*>(BT + (size_t)(wc * 128 + ni * 16 + rsub) * 256 + kt * 32 + koff);
#pragma unroll
        for (int mi = 0; mi < 2; mi++)
            a[mi] = *reinterpret_cast<const short8*>(&Asm[kt & 1][wr * 32 + mi * 16 + rsub][koff]);
#pragma unroll
        for (int mi = 0; mi < 2; mi++)
#pragma unroll
            for (int ni = 0; ni < 8; ni++)
                acc[mi][ni] = __builtin_amdgcn_mfma_f32_16x16x32_bf16(a[mi], b[ni], acc[mi][ni], 0, 0, 0);
        if (kt < 7) {
            short8 bb;
            bb[0] = (short)f2b(s0.x); bb[1] = (short)f2b(s0.y); bb[2] = (short)f2b(s0.z); bb[3] = (short)f2b(s0.w);
            bb[4] = (short)f2b(s1.x); bb[5] = (short)f2b(s1.y); bb[6] = (short)f2b(s1.z); bb[7] = (short)f2b(s1.w);
            *reinterpret_cast<short8*>(&Asm[(kt + 1) & 1][r_t][c8]) = bb;
            __syncthreads();
        }
    }

    // epilogue: permuted layout -> lane's 8 values are 8 contiguous bytes
    int rgrp = (lane >> 4) * 4, csub = lane & 15;
#pragma unroll
    for (int mi = 0; mi < 2; mi++) {
#pragma unroll
        for (int i = 0; i < 4; i++) {
            int r = m0 + wr * 32 + mi * 16 + rgrp + i;
            if (r < M) {
                int d0 = __builtin_amdgcn_cvt_pk_fp8_f32(acc[mi][0][i], acc[mi][1][i], 0, false);
                d0 = __builtin_amdgcn_cvt_pk_fp8_f32(acc[mi][2][i], acc[mi][3][i], d0, true);
                int d1 = __builtin_amdgcn_cvt_pk_fp8_f32(acc[mi][4][i], acc[mi][5][i], 0, false);
                d1 = __builtin_amdgcn_cvt_pk_fp8_f32(acc[mi][6][i], acc[mi][7][i], d1, true);
                uint2 st; st.x = (unsigned)d0; st.y = (unsigned)d1;
                *reinterpret_cast<uint2*>(F8 + (size_t)r * 256 + wc * 128 + csub * 8) = st;
            }
        }
    }
}

// ---------------- el/er layer 1 from permuted fp8: 1 wave per node, coalesced ------
__global__ __launch_bounds__(256) void elr1_k(const unsigned char* __restrict__ feat8,
                                              const float* __restrict__ al,
                                              const float* __restrict__ ar,
                                              float* __restrict__ el, float* __restrict__ er) {
    int wid = (blockIdx.x * blockDim.x + threadIdx.x) >> 6;
    int lane = threadIdx.x & 63;
    if (wid >= N_NODES) return;
    unsigned u = *reinterpret_cast<const unsigned*>(feat8 + (size_t)wid * 256 + 4 * lane);
    floatx2 lo = __builtin_amdgcn_cvt_pk_f32_fp8((int)u, false);
    floatx2 hi = __builtin_amdgcn_cvt_pk_f32_fp8((int)u, true);
    int csub = (lane & 31) >> 1;
    int h0 = (lane >> 5) * 4 + 2 * (lane & 1);
    float pl0 = lo.x * al[h0 * 32 + csub] + lo.y * al[h0 * 32 + 16 + csub];
    float pr0 = lo.x * ar[h0 * 32 + csub] + lo.y * ar[h0 * 32 + 16 + csub];
    float pl1 = hi.x * al[(h0 + 1) * 32 + csub] + hi.y * al[(h0 + 1) * 32 + 16 + csub];
    float pr1 = hi.x * ar[(h0 + 1) * 32 + csub] + hi.y * ar[(h0 + 1) * 32 + 16 + csub];
#pragma unroll
    for (int d = 2; d <= 16; d <<= 1) {
        pl0 += __shfl_xor(pl0, d); pr0 += __shfl_xor(pr0, d);
        pl1 += __shfl_xor(pl1, d); pr1 += __shfl_xor(pr1, d);
    }
    if (csub == 0) {
        el[wid * 8 + h0] = pl0; el[wid * 8 + h0 + 1] = pl1;
        er[wid * 8 + h0] = pr0; er[wid * 8 + h0 + 1] = pr1;
    }
}

// ---------------- GEMM2 + fused el2/er2: feat2p[M,64] = h1p[M,256] @ W2 ----------------
// h1p is in the permuted channel order; W2 rows are indexed through the permutation.
__global__ __launch_bounds__(256) void gemm2_k(const unsigned short* __restrict__ A,
                                               const float* __restrict__ B,
                                               const float* __restrict__ al2,
                                               const float* __restrict__ ar2,
                                               unsigned short* __restrict__ C,
                                               float* __restrict__ el2,
                                               float* __restrict__ er2, int M) {
    __shared__ float As[32][65];   // [k][row]
    __shared__ float Bs[32][64];
    __shared__ float Pl[4][64], Pr[4][64];
    int t = threadIdx.x;
    int row = t & 63, cg = t >> 6;   // 4 col groups x 16 cols
    int m0 = blockIdx.x * 64;
    float acc[16] = {};
    for (int k0 = 0; k0 < 256; k0 += 32) {
        {
            int r = t >> 2, c0 = (t & 3) * 8;
            int m = m0 + r;
            uint4 v = make_uint4(0, 0, 0, 0);
            if (m < M) v = *reinterpret_cast<const uint4*>(A + (size_t)m * 256 + k0 + c0);
            const unsigned short* pv = reinterpret_cast<const unsigned short*>(&v);
#pragma unroll
            for (int i = 0; i < 8; i++) As[c0 + i][r] = b2f(pv[i]);
        }
        for (int l = t; l < 32 * 64; l += 256) {
            int r = l >> 6, c = l & 63;
            int kk = k0 + r;                       // storage index
            int half = kk >> 7, cs = (kk & 127) >> 3, ni = kk & 7;
            int ck = half * 128 + ni * 16 + cs;    // actual channel
            Bs[r][c] = (c < 40) ? B[ck * 40 + c] : 0.f;
        }
        __syncthreads();
#pragma unroll
        for (int kk = 0; kk < 32; kk++) {
            float a = As[kk][row];
#pragma unroll
            for (int j = 0; j < 16; j++) acc[j] += a * Bs[kk][cg * 16 + j];
        }
        __syncthreads();
    }
    int m = m0 + row;
    float pl = 0.f, pr = 0.f;
#pragma unroll
    for (int j = 0; j < 16; j++) {
        int col = cg * 16 + j;
        if (col < 40) { pl += acc[j] * al2[col]; pr += acc[j] * ar2[col]; }
    }
    Pl[cg][row] = pl; Pr[cg][row] = pr;
    if (m < M) {
#pragma unroll
        for (int j = 0; j < 16; j++) C[(size_t)m * 64 + cg * 16 + j] = f2b(acc[j]);
    }
    __syncthreads();
    if (cg == 0 && m < M) {
        el2[m] = Pl[0][row] + Pl[1][row] + Pl[2][row];
        er2[m] = Pr[0][row] + Pr[1][row] + Pr[2][row];
    }
}

// ---------------- CSR build: histogram, scan, scatter ----------------
__global__ void hist_k(const int* __restrict__ dst, int* __restrict__ deg) {
    int e = blockIdx.x * blockDim.x + threadIdx.x;
    if (e < N_EDGES) atomicAdd(&deg[dst[e]], 1);
}

__global__ void scan1_k(const int* __restrict__ deg, int* __restrict__ offs,
                        int* __restrict__ bsum, int n) {
    __shared__ int s[256];
    int tid = threadIdx.x;
    int i = blockIdx.x * 256 + tid;
    int v = (i < n) ? deg[i] : 0;
    s[tid] = v;
    __syncthreads();
    for (int d = 1; d < 256; d <<= 1) {
        int t = (tid >= d) ? s[tid - d] : 0;
        __syncthreads();
        s[tid] += t;
        __syncthreads();
    }
    if (i < n) offs[i] = s[tid] - v;
    if (tid == 255) bsum[blockIdx.x] = s[255];
}

__global__ void scan2_k(int* __restrict__ bsum, int nb) {
    __shared__ int s[256];
    int tid = threadIdx.x;
    int v = (tid < nb) ? bsum[tid] : 0;
    s[tid] = v;
    __syncthreads();
    for (int d = 1; d < 256; d <<= 1) {
        int t = (tid >= d) ? s[tid - d] : 0;
        __syncthreads();
        s[tid] += t;
        __syncthreads();
    }
    if (tid < nb) bsum[tid] = s[tid] - v;
}

__global__ void scan3_k(int* __restrict__ offs, const int* __restrict__ bsum,
                        int* __restrict__ cur, int n) {
    int i = blockIdx.x * 256 + threadIdx.x;
    if (i < n) { offs[i] += bsum[blockIdx.x]; cur[i] = 0; }
    if (i == 0) offs[n] = N_EDGES;
}

__global__ void scatter_k(const int* __restrict__ src, const int* __restrict__ dst,
                          const int* __restrict__ offs, int* __restrict__ cur,
                          int* __restrict__ ssorted) {
    int e = blockIdx.x * blockDim.x + threadIdx.x;
    if (e < N_EDGES) {
        int d = dst[e];
        int p = atomicAdd(&cur[d], 1);
        ssorted[offs[d] + p] = src[e];
    }
}

// ---------------- layer-1 attention aggregate (permuted fp8 gather) ------
__global__ __launch_bounds__(256) void agg1_k(const unsigned char* __restrict__ feat8,
                                              const float* __restrict__ el,
                                              const float* __restrict__ er,
                                              const int* __restrict__ offs,
                                              const int* __restrict__ ssorted,
                                              unsigned short* __restrict__ h1) {
    __shared__ float sa[4][CAP1 * 8];
    __shared__ int   ss[4][CAP1];
    int t = threadIdx.x;
    int wv = t >> 6, lane = t & 63;
    int n = blockIdx.x * 4 + wv;
    if (n >= N_NODES) return;
    int beg = offs[n];
    int deg = offs[n + 1] - beg;
    int eloc = lane >> 3, h = lane & 7;
    int h0 = (lane >> 5) * 4 + 2 * (lane & 1);   // head of bytes 0,1 at offset 4*lane (h0+1 for bytes 2,3)
    float er_h = er[n * 8 + h];

    float acc0 = 0.f, acc1 = 0.f, acc2 = 0.f, acc3 = 0.f;

    if (deg <= CAP1) {
        // pass A: exp-sum (e bounded, no max-sub), stash ee and src in LDS
        float ssum = 0.f;
        for (int c0 = 0; c0 < deg; c0 += 8) {
            int idx = c0 + eloc;
            bool act = idx < deg;
            float ee = 0.f;
            if (act) {
                int s = ssorted[beg + idx];
                if (h == 0) ss[wv][idx] = s;
                ee = __expf(leaky(el[s * 8 + h] + er_h));
                sa[wv][idx * 8 + h] = ee;
            }
            float sc = ee;
            sc += __shfl_xor(sc, 8);
            sc += __shfl_xor(sc, 16);
            sc += __shfl_xor(sc, 32);
            ssum += sc;
        }
        float inv = 1.f / ssum;
        float iv0 = __shfl(inv, h0), iv1 = __shfl(inv, h0 + 1);
        asm volatile("s_waitcnt lgkmcnt(0)" ::: "memory");
        // pass B: 16 edges per batch, 4B fp8 per lane (permuted channels)
        for (int c0 = 0; c0 < deg; c0 += 16) {
            int nr = deg - c0; if (nr > 16) nr = 16;
            unsigned u[16]; float2 av[16];
#pragma unroll
            for (int j = 0; j < 16; j++) {
                if (j < nr) {
                    int sj = ss[wv][c0 + j];
                    av[j] = *reinterpret_cast<const float2*>(&sa[wv][(c0 + j) * 8 + h0]);
                    u[j] = *reinterpret_cast<const unsigned*>(feat8 + (size_t)sj * 256 + 4 * lane);
                }
            }
#pragma unroll
            for (int j = 0; j < 16; j++) {
                if (j < nr) {
                    float w0 = av[j].x * iv0, w1 = av[j].y * iv1;
                    floatx2 lo = __builtin_amdgcn_cvt_pk_f32_fp8((int)u[j], false);
                    floatx2 hi = __builtin_amdgcn_cvt_pk_f32_fp8((int)u[j], true);
                    acc0 += w0 * lo.x;
                    acc1 += w0 * lo.y;
                    acc2 += w1 * hi.x;
                    acc3 += w1 * hi.y;
                }
            }
        }
    } else {
        // fallback (deg > CAP1): recompute alphas
        float ssum = 0.f;
        for (int c0 = 0; c0 < deg; c0 += 8) {
            bool act = (c0 + eloc) < deg;
            float ee = 0.f;
            if (act) {
                int s = ssorted[beg + c0 + eloc];
                ee = __expf(leaky(el[s * 8 + h] + er_h));
            }
            float sc = ee;
            sc += __shfl_xor(sc, 8);
            sc += __shfl_xor(sc, 16);
            sc += __shfl_xor(sc, 32);
            ssum += sc;
        }
        float inv = 1.f / ssum;
        float iv0 = __shfl(inv, h0), iv1 = __shfl(inv, h0 + 1);
        for (int c0 = 0; c0 < deg; c0 += 8) {
            int nr = deg - c0; if (nr > 8) nr = 8;
            int s = 0; float a = 0.f;
            if (eloc < nr) {
                s = ssorted[beg + c0 + eloc];
                a = __expf(leaky(el[s * 8 + h] + er_h));
            }
#pragma unroll
            for (int j = 0; j < 8; j++) {
                if (j < nr) {
                    int   sj = __shfl(s, j * 8);
                    float a0 = __shfl(a, j * 8 + h0) * iv0;
                    float a1 = __shfl(a, j * 8 + h0 + 1) * iv1;
                    unsigned u = *reinterpret_cast<const unsigned*>(feat8 + (size_t)sj * 256 + 4 * lane);
                    floatx2 lo = __builtin_amdgcn_cvt_pk_f32_fp8((int)u, false);
                    floatx2 hi = __builtin_amdgcn_cvt_pk_f32_fp8((int)u, true);
                    acc0 += a0 * lo.x;
                    acc1 += a0 * lo.y;
                    acc2 += a1 * hi.x;
                    acc3 += a1 * hi.y;
                }
            }
        }
    }
    ushort4 o;
    o.x = f2b(fmaxf(acc0, 0.f));   // fused relu; h1 kept in permuted layout
    o.y = f2b(fmaxf(acc1, 0.f));
    o.z = f2b(fmaxf(acc2, 0.f));
    o.w = f2b(fmaxf(acc3, 0.f));
    *reinterpret_cast<ushort4*>(h1 + (size_t)n * 256 + 4 * lane) = o;
}

// ---------------- layer-2 attention aggregate + log_softmax ----------------
__global__ __launch_bounds__(256) void agg2_k(const unsigned short* __restrict__ feat2p,
                                              const float* __restrict__ el2,
                                              const float* __restrict__ er2,
                                              const int* __restrict__ offs,
                                              const int* __restrict__ ssorted,
                                              float* __restrict__ out) {
    __shared__ float sa[4][CAP2];
    __shared__ int   ss[4][CAP2];
    int t = threadIdx.x;
    int wv = t >> 6, lane = t & 63;
    int n = blockIdx.x * 4 + wv;
    if (n >= N_NODES) return;
    int beg = offs[n];
    int deg = offs[n + 1] - beg;
    float ern = er2[n];
    int eloc = lane >> 3, c8 = lane & 7;

    float acc[8] = {};
    if (deg <= CAP2) {
        float ssum = 0.f;
        for (int c0 = 0; c0 < deg; c0 += 64) {
            int idx = c0 + lane;
            bool act = idx < deg;
            float ee = 0.f;
            if (act) {
                int s = ssorted[beg + idx];
                ss[wv][idx] = s;
                ee = __expf(leaky(el2[s] + ern));
                sa[wv][idx] = ee;
            }
            float sc = ee;
#pragma unroll
            for (int d = 1; d < 64; d <<= 1) sc += __shfl_xor(sc, d);
            ssum += sc;
        }
        float inv = 1.f / ssum;
        asm volatile("s_waitcnt lgkmcnt(0)" ::: "memory");
        for (int c0 = 0; c0 < deg; c0 += 16) {
            int i0 = c0 + eloc, i1 = c0 + 8 + eloc;
            uint4 v0 = make_uint4(0, 0, 0, 0), v1 = make_uint4(0, 0, 0, 0);
            float w0 = 0.f, w1 = 0.f;
            if (i0 < deg) {
                int s = ss[wv][i0]; w0 = sa[wv][i0] * inv;
                v0 = *reinterpret_cast<const uint4*>(feat2p + (size_t)s * 64 + c8 * 8);
            }
            if (i1 < deg) {
                int s = ss[wv][i1]; w1 = sa[wv][i1] * inv;
                v1 = *reinterpret_cast<const uint4*>(feat2p + (size_t)s * 64 + c8 * 8);
            }
            const unsigned short* p0 = reinterpret_cast<const unsigned short*>(&v0);
            const unsigned short* p1 = reinterpret_cast<const unsigned short*>(&v1);
#pragma unroll
            for (int i = 0; i < 8; i++) acc[i] += w0 * b2f(p0[i]) + w1 * b2f(p1[i]);
        }
    } else {
        float ssum = 0.f;
        for (int c0 = 0; c0 < deg; c0 += 64) {
            bool act = (c0 + lane) < deg;
            float ee = 0.f;
            if (act) ee = __expf(leaky(el2[ssorted[beg + c0 + lane]] + ern));
            float sc = ee;
#pragma unroll
            for (int d = 1; d < 64; d <<= 1) sc += __shfl_xor(sc, d);
            ssum += sc;
        }
        float inv = 1.f / ssum;
        for (int c0 = 0; c0 < deg; c0 += 8) {
            int nr = deg - c0; if (nr > 8) nr = 8;
            if (eloc < nr) {
                int s = ssorted[beg + c0 + eloc];
                float a = __expf(leaky(el2[s] + ern)) * inv;
                uint4 v = *reinterpret_cast<const uint4*>(feat2p + (size_t)s * 64 + c8 * 8);
                const unsigned short* pv = reinterpret_cast<const unsigned short*>(&v);
#pragma unroll
                for (int i = 0; i < 8; i++) acc[i] += a * b2f(pv[i]);
            }
        }
    }
#pragma unroll
    for (int i = 0; i < 8; i++) {
        acc[i] += __shfl_xor(acc[i], 8);
        acc[i] += __shfl_xor(acc[i], 16);
        acc[i] += __shfl_xor(acc[i], 32);
    }
    float lmax = -INFINITY;
    if (c8 < 5) {
#pragma unroll
        for (int i = 0; i < 8; i++) lmax = fmaxf(lmax, acc[i]);
    }
    lmax = fmaxf(lmax, __shfl_xor(lmax, 1));
    lmax = fmaxf(lmax, __shfl_xor(lmax, 2));
    lmax = fmaxf(lmax, __shfl_xor(lmax, 4));
    float lsum = 0.f;
    if (c8 < 5) {
#pragma unroll
        for (int i = 0; i < 8; i++) lsum += __expf(acc[i] - lmax);
    }
    lsum += __shfl_xor(lsum, 1);
    lsum += __shfl_xor(lsum, 2);
    lsum += __shfl_xor(lsum, 4);
    if (eloc == 0 && c8 < 5) {
        float lg = __logf(lsum);
        float* o = out + (size_t)n * 40 + c8 * 8;
#pragma unroll
        for (int i = 0; i < 8; i++) o[i] = acc[i] - lmax - lg;
    }
}

extern "C" void kernel_launch(void* const* d_in, const int* in_sizes, int n_in,
                              void* d_out, int out_size, void* d_ws, size_t ws_size,
                              hipStream_t stream) {
    (void)in_sizes; (void)n_in; (void)out_size; (void)ws_size;
    const float* x   = (const float*)d_in[0];
    const int*   src = (const int*)d_in[1];
    const int*   dst = (const int*)d_in[2];
    const float* W1  = (const float*)d_in[3];
    const float* al1 = (const float*)d_in[4];
    const float* ar1 = (const float*)d_in[5];
    const float* W2  = (const float*)d_in[6];
    const float* al2 = (const float*)d_in[7];
    const float* ar2 = (const float*)d_in[8];
    float* out = (float*)d_out;

    char* ws = (char*)d_ws;
    size_t off = 0;
    auto alloc = [&](size_t bytes) {
        void* p = ws + off;
        off += (bytes + 255) & ~(size_t)255;
        return p;
    };
    unsigned short* w1t    = (unsigned short*)alloc((size_t)256 * 256 * 2);
    unsigned char*  feat8  = (unsigned char*)alloc((size_t)N_NODES * 256);
    unsigned short* h1p    = (unsigned short*)alloc((size_t)N_NODES * 256 * 2);
    unsigned short* feat2p = (unsigned short*)alloc((size_t)N_NODES * 64 * 2);
    float* el1   = (float*)alloc((size_t)N_NODES * 8 * 4);
    float* er1   = (float*)alloc((size_t)N_NODES * 8 * 4);
    float* el2   = (float*)alloc((size_t)N_NODES * 4);
    float* er2   = (float*)alloc((size_t)N_NODES * 4);
    int* deg     = (int*)alloc((size_t)N_NODES * 4);
    int* offs    = (int*)alloc((size_t)(N_NODES + 1) * 4);
    int* cur     = (int*)alloc((size_t)N_NODES * 4);
    int* bsum    = (int*)alloc(1024 * 4);
    int* ssorted = (int*)alloc((size_t)N_EDGES * 4);

    hipMemsetAsync(deg, 0, (size_t)N_NODES * 4, stream);

    cvt_w1t_k<<<256, 256, 0, stream>>>(W1, w1t);

    // CSR by dst
    hist_k<<<(N_EDGES + 255) / 256, 256, 0, stream>>>(dst, deg);
    int nb = (N_NODES + 255) / 256;
    scan1_k<<<nb, 256, 0, stream>>>(deg, offs, bsum, N_NODES);
    scan2_k<<<1, 256, 0, stream>>>(bsum, nb);
    scan3_k<<<nb, 256, 0, stream>>>(offs, bsum, cur, N_NODES);
    scatter_k<<<(N_EDGES + 255) / 256, 256, 0, stream>>>(src, dst, offs, cur, ssorted);

    // layer 1
    gemm1_mfma<<<(N_NODES + 63) / 64, 256, 0, stream>>>(x, w1t, feat8, N_NODES);
    elr1_k<<<(N_NODES * 64 + 255) / 256, 256, 0, stream>>>(feat8, al1, ar1, el1, er1);
    agg1_k<<<(N_NODES + 3) / 4, 256, 0, stream>>>(feat8, el1, er1, offs, ssorted, h1p);

    // layer 2
    gemm2_k<<<(N_NODES + 63) / 64, 256, 0, stream>>>(h1p, W2, al2, ar2, feat2p, el2, er2, N_NODES);
    agg2_k<<<(N_NODES + 3) / 4, 256, 0, stream>>>(feat2p, el2, er2, offs, ssorted, out);
}

// Round 8
// 249.139 us; speedup vs baseline: 2.0876x; 1.0913x over previous
//
#include <hip/hip_runtime.h>
#include <hip/hip_bf16.h>
#include <math.h>

#define N_NODES 50000
#define N_EDGES 800000
#define IN_DIM  256
#define HID     32
#define HEADS   8
#define NCLS    40
#define NEG     0.2f
#define CAP1    128
#define CAP2    128

using short8  = __attribute__((ext_vector_type(8))) short;
using f32x4   = __attribute__((ext_vector_type(4))) float;
using floatx2 = __attribute__((ext_vector_type(2))) float;

__device__ __forceinline__ float leaky(float x) { return x >= 0.f ? x : NEG * x; }
__device__ __forceinline__ unsigned short f2b(float f) {
    unsigned int u = __float_as_uint(f);
    unsigned int r = (u + 0x7fffu + ((u >> 16) & 1u)) >> 16;
    return (unsigned short)r;
}
__device__ __forceinline__ float b2f(unsigned short h) {
    return __uint_as_float((unsigned int)h << 16);
}

// Permuted fp8/bf16 channel storage: channel c = half*128 + ni*16 + csub
// stored at offset s = half*128 + csub*8 + ni.

// W1T[n][k] = bf16(W1[k][n]); W1 is [256][256]
__global__ void cvt_w1t_k(const float* __restrict__ W1, unsigned short* __restrict__ W1T) {
    int k = blockIdx.x, n = threadIdx.x;
    W1T[n * 256 + k] = f2b(W1[k * 256 + n]);
}

// W2T[n][ks] = bf16(W2[perm(ks)][n]) for n<40; rows 40..47 zero.  (48 x 256)
__global__ void cvt_w2t_k(const float* __restrict__ W2, unsigned short* __restrict__ W2T) {
    int n = blockIdx.x;            // 0..47
    int ks = threadIdx.x;          // 0..255 storage index
    int half = ks >> 7, cs = (ks & 127) >> 3, ni = ks & 7;
    int ck = half * 128 + ni * 16 + cs;
    W2T[n * 256 + ks] = (n < 40) ? f2b(W2[ck * 40 + n]) : 0;
}

// ---------------- GEMM1 (MFMA bf16) -> permuted fp8 feat1 ----------------
__global__ __launch_bounds__(256) void gemm1_mfma(const float* __restrict__ A,
                                                  const unsigned short* __restrict__ BT,
                                                  unsigned char* __restrict__ F8, int M) {
    __shared__ unsigned short Asm[2][64][40];
    int t = threadIdx.x;
    int lane = t & 63, w = t >> 6;
    int wr = w >> 1, wc = w & 1;          // wave tile: 32 rows x 128 cols
    int m0 = blockIdx.x * 64;
    int rsub = lane & 15, koff = (lane >> 4) * 8;
    f32x4 acc[2][8] = {};

    int r_t = t >> 2, c8 = (t & 3) * 8;
    const float* ap = A + (size_t)(m0 + r_t) * 256 + c8;
    bool arow_ok = (m0 + r_t) < M;

    float4 s0 = make_float4(0.f, 0.f, 0.f, 0.f), s1 = s0;
    if (arow_ok) { s0 = *reinterpret_cast<const float4*>(ap); s1 = *reinterpret_cast<const float4*>(ap + 4); }
    {
        short8 bb;
        bb[0] = (short)f2b(s0.x); bb[1] = (short)f2b(s0.y); bb[2] = (short)f2b(s0.z); bb[3] = (short)f2b(s0.w);
        bb[4] = (short)f2b(s1.x); bb[5] = (short)f2b(s1.y); bb[6] = (short)f2b(s1.z); bb[7] = (short)f2b(s1.w);
        *reinterpret_cast<short8*>(&Asm[0][r_t][c8]) = bb;
    }
    __syncthreads();

    for (int kt = 0; kt < 8; ++kt) {
        if (kt < 7) {
            s0 = make_float4(0.f, 0.f, 0.f, 0.f); s1 = s0;
            if (arow_ok) {
                const float* p = ap + (kt + 1) * 32;
                s0 = *reinterpret_cast<const float4*>(p);
                s1 = *reinterpret_cast<const float4*>(p + 4);
            }
        }
        short8 b[8], a[2];
#pragma unroll
        for (int ni = 0; ni < 8; ni++)
            b[ni] = *reinterpret_cast<const short8*>(BT + (size_t)(wc * 128 + ni * 16 + rsub) * 256 + kt * 32 + koff);
#pragma unroll
        for (int mi = 0; mi < 2; mi++)
            a[mi] = *reinterpret_cast<const short8*>(&Asm[kt & 1][wr * 32 + mi * 16 + rsub][koff]);
#pragma unroll
        for (int mi = 0; mi < 2; mi++)
#pragma unroll
            for (int ni = 0; ni < 8; ni++)
                acc[mi][ni] = __builtin_amdgcn_mfma_f32_16x16x32_bf16(a[mi], b[ni], acc[mi][ni], 0, 0, 0);
        if (kt < 7) {
            short8 bb;
            bb[0] = (short)f2b(s0.x); bb[1] = (short)f2b(s0.y); bb[2] = (short)f2b(s0.z); bb[3] = (short)f2b(s0.w);
            bb[4] = (short)f2b(s1.x); bb[5] = (short)f2b(s1.y); bb[6] = (short)f2b(s1.z); bb[7] = (short)f2b(s1.w);
            *reinterpret_cast<short8*>(&Asm[(kt + 1) & 1][r_t][c8]) = bb;
            __syncthreads();
        }
    }

    int rgrp = (lane >> 4) * 4, csub = lane & 15;
#pragma unroll
    for (int mi = 0; mi < 2; mi++) {
#pragma unroll
        for (int i = 0; i < 4; i++) {
            int r = m0 + wr * 32 + mi * 16 + rgrp + i;
            if (r < M) {
                int d0 = __builtin_amdgcn_cvt_pk_fp8_f32(acc[mi][0][i], acc[mi][1][i], 0, false);
                d0 = __builtin_amdgcn_cvt_pk_fp8_f32(acc[mi][2][i], acc[mi][3][i], d0, true);
                int d1 = __builtin_amdgcn_cvt_pk_fp8_f32(acc[mi][4][i], acc[mi][5][i], 0, false);
                d1 = __builtin_amdgcn_cvt_pk_fp8_f32(acc[mi][6][i], acc[mi][7][i], d1, true);
                uint2 st; st.x = (unsigned)d0; st.y = (unsigned)d1;
                *reinterpret_cast<uint2*>(F8 + (size_t)r * 256 + wc * 128 + csub * 8) = st;
            }
        }
    }
}

// ---------------- el/er layer 1 from permuted fp8: 1 wave per node ------
__global__ __launch_bounds__(256) void elr1_k(const unsigned char* __restrict__ feat8,
                                              const float* __restrict__ al,
                                              const float* __restrict__ ar,
                                              float* __restrict__ el, float* __restrict__ er) {
    int wid = (blockIdx.x * blockDim.x + threadIdx.x) >> 6;
    int lane = threadIdx.x & 63;
    if (wid >= N_NODES) return;
    unsigned u = *reinterpret_cast<const unsigned*>(feat8 + (size_t)wid * 256 + 4 * lane);
    floatx2 lo = __builtin_amdgcn_cvt_pk_f32_fp8((int)u, false);
    floatx2 hi = __builtin_amdgcn_cvt_pk_f32_fp8((int)u, true);
    int csub = (lane & 31) >> 1;
    int h0 = (lane >> 5) * 4 + 2 * (lane & 1);
    float pl0 = lo.x * al[h0 * 32 + csub] + lo.y * al[h0 * 32 + 16 + csub];
    float pr0 = lo.x * ar[h0 * 32 + csub] + lo.y * ar[h0 * 32 + 16 + csub];
    float pl1 = hi.x * al[(h0 + 1) * 32 + csub] + hi.y * al[(h0 + 1) * 32 + 16 + csub];
    float pr1 = hi.x * ar[(h0 + 1) * 32 + csub] + hi.y * ar[(h0 + 1) * 32 + 16 + csub];
#pragma unroll
    for (int d = 2; d <= 16; d <<= 1) {
        pl0 += __shfl_xor(pl0, d); pr0 += __shfl_xor(pr0, d);
        pl1 += __shfl_xor(pl1, d); pr1 += __shfl_xor(pr1, d);
    }
    if (csub == 0) {
        el[wid * 8 + h0] = pl0; el[wid * 8 + h0 + 1] = pl1;
        er[wid * 8 + h0] = pr0; er[wid * 8 + h0 + 1] = pr1;
    }
}

// ---------------- GEMM2 (MFMA bf16): feat2p[M,64] = h1p[M,256] @ W2 (permuted) ------
__global__ __launch_bounds__(256) void gemm2_mfma(const unsigned short* __restrict__ A,
                                                  const unsigned short* __restrict__ BT,
                                                  unsigned short* __restrict__ C, int M) {
    __shared__ unsigned short Asm[2][64][40];
    int t = threadIdx.x;
    int lane = t & 63, w = t >> 6;        // wave tile: 16 rows x 48 cols
    int m0 = blockIdx.x * 64;
    int rsub = lane & 15, koff = (lane >> 4) * 8;
    f32x4 acc[3] = {};

    int r_t = t >> 2, c8 = (t & 3) * 8;
    const unsigned short* ap = A + (size_t)(m0 + r_t) * 256 + c8;
    bool arow_ok = (m0 + r_t) < M;

    uint4 s0 = make_uint4(0, 0, 0, 0);
    if (arow_ok) s0 = *reinterpret_cast<const uint4*>(ap);
    *reinterpret_cast<uint4*>(&Asm[0][r_t][c8]) = s0;
    __syncthreads();

    for (int kt = 0; kt < 8; ++kt) {
        if (kt < 7) {
            s0 = make_uint4(0, 0, 0, 0);
            if (arow_ok) s0 = *reinterpret_cast<const uint4*>(ap + (kt + 1) * 32);
        }
        short8 b[3], a;
#pragma unroll
        for (int ni = 0; ni < 3; ni++)
            b[ni] = *reinterpret_cast<const short8*>(BT + (size_t)(ni * 16 + rsub) * 256 + kt * 32 + koff);
        a = *reinterpret_cast<const short8*>(&Asm[kt & 1][w * 16 + rsub][koff]);
#pragma unroll
        for (int ni = 0; ni < 3; ni++)
            acc[ni] = __builtin_amdgcn_mfma_f32_16x16x32_bf16(a, b[ni], acc[ni], 0, 0, 0);
        if (kt < 7) {
            *reinterpret_cast<uint4*>(&Asm[(kt + 1) & 1][r_t][c8]) = s0;
            __syncthreads();
        }
    }

    int rgrp = (lane >> 4) * 4, csub = lane & 15;
#pragma unroll
    for (int ni = 0; ni < 3; ni++) {
#pragma unroll
        for (int i = 0; i < 4; i++) {
            int r = m0 + w * 16 + rgrp + i;
            if (r < M) C[(size_t)r * 64 + ni * 16 + csub] = f2b(acc[ni][i]);
        }
    }
}

// ---------------- el/er layer 2 from bf16 feat2p ----------------
__global__ void elr2_k(const unsigned short* __restrict__ feat2p, const float* __restrict__ al,
                       const float* __restrict__ ar, float* __restrict__ el,
                       float* __restrict__ er) {
    int n = blockIdx.x * blockDim.x + threadIdx.x;
    if (n >= N_NODES) return;
    const uint4* p = reinterpret_cast<const uint4*>(feat2p + (size_t)n * 64);
    float sl = 0.f, sr = 0.f;
#pragma unroll
    for (int q = 0; q < 5; q++) {
        uint4 v = p[q];
        const unsigned short* pv = reinterpret_cast<const unsigned short*>(&v);
#pragma unroll
        for (int i = 0; i < 8; i++) {
            float fv = b2f(pv[i]);
            sl += fv * al[q * 8 + i];
            sr += fv * ar[q * 8 + i];
        }
    }
    el[n] = sl; er[n] = sr;
}

// ---------------- CSR build: histogram, scan, scatter ----------------
__global__ void hist_k(const int* __restrict__ dst, int* __restrict__ deg) {
    int e = blockIdx.x * blockDim.x + threadIdx.x;
    if (e < N_EDGES) atomicAdd(&deg[dst[e]], 1);
}

__global__ void scan1_k(const int* __restrict__ deg, int* __restrict__ offs,
                        int* __restrict__ bsum, int n) {
    __shared__ int s[256];
    int tid = threadIdx.x;
    int i = blockIdx.x * 256 + tid;
    int v = (i < n) ? deg[i] : 0;
    s[tid] = v;
    __syncthreads();
    for (int d = 1; d < 256; d <<= 1) {
        int t = (tid >= d) ? s[tid - d] : 0;
        __syncthreads();
        s[tid] += t;
        __syncthreads();
    }
    if (i < n) offs[i] = s[tid] - v;
    if (tid == 255) bsum[blockIdx.x] = s[255];
}

__global__ void scan2_k(int* __restrict__ bsum, int nb) {
    __shared__ int s[256];
    int tid = threadIdx.x;
    int v = (tid < nb) ? bsum[tid] : 0;
    s[tid] = v;
    __syncthreads();
    for (int d = 1; d < 256; d <<= 1) {
        int t = (tid >= d) ? s[tid - d] : 0;
        __syncthreads();
        s[tid] += t;
        __syncthreads();
    }
    if (tid < nb) bsum[tid] = s[tid] - v;
}

__global__ void scan3_k(int* __restrict__ offs, const int* __restrict__ bsum,
                        int* __restrict__ cur, int n) {
    int i = blockIdx.x * 256 + threadIdx.x;
    if (i < n) { offs[i] += bsum[blockIdx.x]; cur[i] = 0; }
    if (i == 0) offs[n] = N_EDGES;
}

__global__ void scatter_k(const int* __restrict__ src, const int* __restrict__ dst,
                          const int* __restrict__ offs, int* __restrict__ cur,
                          int* __restrict__ ssorted) {
    int e = blockIdx.x * blockDim.x + threadIdx.x;
    if (e < N_EDGES) {
        int d = dst[e];
        int p = atomicAdd(&cur[d], 1);
        ssorted[offs[d] + p] = src[e];
    }
}

// ---------------- layer-1 attention aggregate (permuted fp8 gather) ------
__global__ __launch_bounds__(256) void agg1_k(const unsigned char* __restrict__ feat8,
                                              const float* __restrict__ el,
                                              const float* __restrict__ er,
                                              const int* __restrict__ offs,
                                              const int* __restrict__ ssorted,
                                              unsigned short* __restrict__ h1) {
    __shared__ float sa[4][CAP1 * 8];
    __shared__ int   ss[4][CAP1];
    int t = threadIdx.x;
    int wv = t >> 6, lane = t & 63;
    int n = blockIdx.x * 4 + wv;
    if (n >= N_NODES) return;
    int beg = offs[n];
    int deg = offs[n + 1] - beg;
    int eloc = lane >> 3, h = lane & 7;
    int h0 = (lane >> 5) * 4 + 2 * (lane & 1);
    float er_h = er[n * 8 + h];

    float acc0 = 0.f, acc1 = 0.f, acc2 = 0.f, acc3 = 0.f;

    if (deg <= CAP1) {
        float ssum = 0.f;
        for (int c0 = 0; c0 < deg; c0 += 8) {
            int idx = c0 + eloc;
            bool act = idx < deg;
            float ee = 0.f;
            if (act) {
                int s = ssorted[beg + idx];
                if (h == 0) ss[wv][idx] = s;
                ee = __expf(leaky(el[s * 8 + h] + er_h));
                sa[wv][idx * 8 + h] = ee;
            }
            float sc = ee;
            sc += __shfl_xor(sc, 8);
            sc += __shfl_xor(sc, 16);
            sc += __shfl_xor(sc, 32);
            ssum += sc;
        }
        float inv = 1.f / ssum;
        float iv0 = __shfl(inv, h0), iv1 = __shfl(inv, h0 + 1);
        asm volatile("s_waitcnt lgkmcnt(0)" ::: "memory");
        for (int c0 = 0; c0 < deg; c0 += 16) {
            int nr = deg - c0; if (nr > 16) nr = 16;
            unsigned u[16]; float2 av[16];
#pragma unroll
            for (int j = 0; j < 16; j++) {
                if (j < nr) {
                    int sj = ss[wv][c0 + j];
                    av[j] = *reinterpret_cast<const float2*>(&sa[wv][(c0 + j) * 8 + h0]);
                    u[j] = *reinterpret_cast<const unsigned*>(feat8 + (size_t)sj * 256 + 4 * lane);
                }
            }
#pragma unroll
            for (int j = 0; j < 16; j++) {
                if (j < nr) {
                    float w0 = av[j].x * iv0, w1 = av[j].y * iv1;
                    floatx2 lo = __builtin_amdgcn_cvt_pk_f32_fp8((int)u[j], false);
                    floatx2 hi = __builtin_amdgcn_cvt_pk_f32_fp8((int)u[j], true);
                    acc0 += w0 * lo.x;
                    acc1 += w0 * lo.y;
                    acc2 += w1 * hi.x;
                    acc3 += w1 * hi.y;
                }
            }
        }
    } else {
        float ssum = 0.f;
        for (int c0 = 0; c0 < deg; c0 += 8) {
            bool act = (c0 + eloc) < deg;
            float ee = 0.f;
            if (act) {
                int s = ssorted[beg + c0 + eloc];
                ee = __expf(leaky(el[s * 8 + h] + er_h));
            }
            float sc = ee;
            sc += __shfl_xor(sc, 8);
            sc += __shfl_xor(sc, 16);
            sc += __shfl_xor(sc, 32);
            ssum += sc;
        }
        float inv = 1.f / ssum;
        float iv0 = __shfl(inv, h0), iv1 = __shfl(inv, h0 + 1);
        for (int c0 = 0; c0 < deg; c0 += 8) {
            int nr = deg - c0; if (nr > 8) nr = 8;
            int s = 0; float a = 0.f;
            if (eloc < nr) {
                s = ssorted[beg + c0 + eloc];
                a = __expf(leaky(el[s * 8 + h] + er_h));
            }
#pragma unroll
            for (int j = 0; j < 8; j++) {
                if (j < nr) {
                    int   sj = __shfl(s, j * 8);
                    float a0 = __shfl(a, j * 8 + h0) * iv0;
                    float a1 = __shfl(a, j * 8 + h0 + 1) * iv1;
                    unsigned u = *reinterpret_cast<const unsigned*>(feat8 + (size_t)sj * 256 + 4 * lane);
                    floatx2 lo = __builtin_amdgcn_cvt_pk_f32_fp8((int)u, false);
                    floatx2 hi = __builtin_amdgcn_cvt_pk_f32_fp8((int)u, true);
                    acc0 += a0 * lo.x;
                    acc1 += a0 * lo.y;
                    acc2 += a1 * hi.x;
                    acc3 += a1 * hi.y;
                }
            }
        }
    }
    ushort4 o;
    o.x = f2b(fmaxf(acc0, 0.f));
    o.y = f2b(fmaxf(acc1, 0.f));
    o.z = f2b(fmaxf(acc2, 0.f));
    o.w = f2b(fmaxf(acc3, 0.f));
    *reinterpret_cast<ushort4*>(h1 + (size_t)n * 256 + 4 * lane) = o;
}

// ---------------- layer-2 attention aggregate + log_softmax ----------------
__global__ __launch_bounds__(256) void agg2_k(const unsigned short* __restrict__ feat2p,
                                              const float* __restrict__ el2,
                                              const float* __restrict__ er2,
                                              const int* __restrict__ offs,
                                              const int* __restrict__ ssorted,
                                              float* __restrict__ out) {
    __shared__ float sa[4][CAP2];
    __shared__ int   ss[4][CAP2];
    int t = threadIdx.x;
    int wv = t >> 6, lane = t & 63;
    int n = blockIdx.x * 4 + wv;
    if (n >= N_NODES) return;
    int beg = offs[n];
    int deg = offs[n + 1] - beg;
    float ern = er2[n];
    int eloc = lane >> 3, c8 = lane & 7;

    float acc[8] = {};
    if (deg <= CAP2) {
        float ssum = 0.f;
        for (int c0 = 0; c0 < deg; c0 += 64) {
            int idx = c0 + lane;
            bool act = idx < deg;
            float ee = 0.f;
            if (act) {
                int s = ssorted[beg + idx];
                ss[wv][idx] = s;
                ee = __expf(leaky(el2[s] + ern));
                sa[wv][idx] = ee;
            }
            float sc = ee;
#pragma unroll
            for (int d = 1; d < 64; d <<= 1) sc += __shfl_xor(sc, d);
            ssum += sc;
        }
        float inv = 1.f / ssum;
        asm volatile("s_waitcnt lgkmcnt(0)" ::: "memory");
        for (int c0 = 0; c0 < deg; c0 += 16) {
            int i0 = c0 + eloc, i1 = c0 + 8 + eloc;
            uint4 v0 = make_uint4(0, 0, 0, 0), v1 = make_uint4(0, 0, 0, 0);
            float w0 = 0.f, w1 = 0.f;
            if (i0 < deg) {
                int s = ss[wv][i0]; w0 = sa[wv][i0] * inv;
                v0 = *reinterpret_cast<const uint4*>(feat2p + (size_t)s * 64 + c8 * 8);
            }
            if (i1 < deg) {
                int s = ss[wv][i1]; w1 = sa[wv][i1] * inv;
                v1 = *reinterpret_cast<const uint4*>(feat2p + (size_t)s * 64 + c8 * 8);
            }
            const unsigned short* p0 = reinterpret_cast<const unsigned short*>(&v0);
            const unsigned short* p1 = reinterpret_cast<const unsigned short*>(&v1);
#pragma unroll
            for (int i = 0; i < 8; i++) acc[i] += w0 * b2f(p0[i]) + w1 * b2f(p1[i]);
        }
    } else {
        float ssum = 0.f;
        for (int c0 = 0; c0 < deg; c0 += 64) {
            bool act = (c0 + lane) < deg;
            float ee = 0.f;
            if (act) ee = __expf(leaky(el2[ssorted[beg + c0 + lane]] + ern));
            float sc = ee;
#pragma unroll
            for (int d = 1; d < 64; d <<= 1) sc += __shfl_xor(sc, d);
            ssum += sc;
        }
        float inv = 1.f / ssum;
        for (int c0 = 0; c0 < deg; c0 += 8) {
            int nr = deg - c0; if (nr > 8) nr = 8;
            if (eloc < nr) {
                int s = ssorted[beg + c0 + eloc];
                float a = __expf(leaky(el2[s] + ern)) * inv;
                uint4 v = *reinterpret_cast<const uint4*>(feat2p + (size_t)s * 64 + c8 * 8);
                const unsigned short* pv = reinterpret_cast<const unsigned short*>(&v);
#pragma unroll
                for (int i = 0; i < 8; i++) acc[i] += a * b2f(pv[i]);
            }
        }
    }
#pragma unroll
    for (int i = 0; i < 8; i++) {
        acc[i] += __shfl_xor(acc[i], 8);
        acc[i] += __shfl_xor(acc[i], 16);
        acc[i] += __shfl_xor(acc[i], 32);
    }
    float lmax = -INFINITY;
    if (c8 < 5) {
#pragma unroll
        for (int i = 0; i < 8; i++) lmax = fmaxf(lmax, acc[i]);
    }
    lmax = fmaxf(lmax, __shfl_xor(lmax, 1));
    lmax = fmaxf(lmax, __shfl_xor(lmax, 2));
    lmax = fmaxf(lmax, __shfl_xor(lmax, 4));
    float lsum = 0.f;
    if (c8 < 5) {
#pragma unroll
        for (int i = 0; i < 8; i++) lsum += __expf(acc[i] - lmax);
    }
    lsum += __shfl_xor(lsum, 1);
    lsum += __shfl_xor(lsum, 2);
    lsum += __shfl_xor(lsum, 4);
    if (eloc == 0 && c8 < 5) {
        float lg = __logf(lsum);
        float* o = out + (size_t)n * 40 + c8 * 8;
#pragma unroll
        for (int i = 0; i < 8; i++) o[i] = acc[i] - lmax - lg;
    }
}

extern "C" void kernel_launch(void* const* d_in, const int* in_sizes, int n_in,
                              void* d_out, int out_size, void* d_ws, size_t ws_size,
                              hipStream_t stream) {
    (void)in_sizes; (void)n_in; (void)out_size; (void)ws_size;
    const float* x   = (const float*)d_in[0];
    const int*   src = (const int*)d_in[1];
    const int*   dst = (const int*)d_in[2];
    const float* W1  = (const float*)d_in[3];
    const float* al1 = (const float*)d_in[4];
    const float* ar1 = (const float*)d_in[5];
    const float* W2  = (const float*)d_in[6];
    const float* al2 = (const float*)d_in[7];
    const float* ar2 = (const float*)d_in[8];
    float* out = (float*)d_out;

    char* ws = (char*)d_ws;
    size_t off = 0;
    auto alloc = [&](size_t bytes) {
        void* p = ws + off;
        off += (bytes + 255) & ~(size_t)255;
        return p;
    };
    unsigned short* w1t    = (unsigned short*)alloc((size_t)256 * 256 * 2);
    unsigned short* w2t    = (unsigned short*)alloc((size_t)48 * 256 * 2);
    unsigned char*  feat8  = (unsigned char*)alloc((size_t)N_NODES * 256);
    unsigned short* h1p    = (unsigned short*)alloc((size_t)N_NODES * 256 * 2);
    unsigned short* feat2p = (unsigned short*)alloc((size_t)N_NODES * 64 * 2);
    float* el1   = (float*)alloc((size_t)N_NODES * 8 * 4);
    float* er1   = (float*)alloc((size_t)N_NODES * 8 * 4);
    float* el2   = (float*)alloc((size_t)N_NODES * 4);
    float* er2   = (float*)alloc((size_t)N_NODES * 4);
    int* deg     = (int*)alloc((size_t)N_NODES * 4);
    int* offs    = (int*)alloc((size_t)(N_NODES + 1) * 4);
    int* cur     = (int*)alloc((size_t)N_NODES * 4);
    int* bsum    = (int*)alloc(1024 * 4);
    int* ssorted = (int*)alloc((size_t)N_EDGES * 4);

    hipMemsetAsync(deg, 0, (size_t)N_NODES * 4, stream);
    hipMemsetAsync(feat2p, 0, (size_t)N_NODES * 64 * 2, stream);

    cvt_w1t_k<<<256, 256, 0, stream>>>(W1, w1t);
    cvt_w2t_k<<<48, 256, 0, stream>>>(W2, w2t);

    // CSR by dst
    hist_k<<<(N_EDGES + 255) / 256, 256, 0, stream>>>(dst, deg);
    int nb = (N_NODES + 255) / 256;
    scan1_k<<<nb, 256, 0, stream>>>(deg, offs, bsum, N_NODES);
    scan2_k<<<1, 256, 0, stream>>>(bsum, nb);
    scan3_k<<<nb, 256, 0, stream>>>(offs, bsum, cur, N_NODES);
    scatter_k<<<(N_EDGES + 255) / 256, 256, 0, stream>>>(src, dst, offs, cur, ssorted);

    // layer 1
    gemm1_mfma<<<(N_NODES + 63) / 64, 256, 0, stream>>>(x, w1t, feat8, N_NODES);
    elr1_k<<<(N_NODES * 64 + 255) / 256, 256, 0, stream>>>(feat8, al1, ar1, el1, er1);
    agg1_k<<<(N_NODES + 3) / 4, 256, 0, stream>>>(feat8, el1, er1, offs, ssorted, h1p);

    // layer 2
    gemm2_mfma<<<(N_NODES + 63) / 64, 256, 0, stream>>>(h1p, w2t, feat2p, N_NODES);
    elr2_k<<<(N_NODES + 255) / 256, 256, 0, stream>>>(feat2p, al2, ar2, el2, er2);
    agg2_k<<<(N_NODES + 3) / 4, 256, 0, stream>>>(feat2p, el2, er2, offs, ssorted, out);
}

// Round 9
// 218.714 us; speedup vs baseline: 2.3781x; 1.1391x over previous
//
#include <hip/hip_runtime.h>
#include <hip/hip_bf16.h>
#include <math.h>

#define N_NODES 50000
#define N_EDGES 800000
#define IN_DIM  256
#define HID     32
#define HEADS   8
#define NCLS    40
#define NEG     0.2f
#define CAP1    128
#define CAP2    128

using short8  = __attribute__((ext_vector_type(8))) short;
using f32x4   = __attribute__((ext_vector_type(4))) float;
using floatx2 = __attribute__((ext_vector_type(2))) float;

__device__ __forceinline__ float leaky(float x) { return x >= 0.f ? x : NEG * x; }
__device__ __forceinline__ unsigned short f2b(float f) {
    unsigned int u = __float_as_uint(f);
    unsigned int r = (u + 0x7fffu + ((u >> 16) & 1u)) >> 16;
    return (unsigned short)r;
}
__device__ __forceinline__ float b2f(unsigned short h) {
    return __uint_as_float((unsigned int)h << 16);
}

// Permuted fp8/bf16 channel storage: channel c = half*128 + ni*16 + csub
// stored at offset s = half*128 + csub*8 + ni.

// Combined weight conversion:
//  BTile[kt][n][k2] = bf16(W1[kt*32+k2][n])  (8 x 256 x 32, contiguous per kt)
//  W2T[n][ks] = bf16(W2[perm(ks)][n]) for n<40; rows 40..47 zero. (48 x 256)
__global__ void cvt_w_k(const float* __restrict__ W1, const float* __restrict__ W2,
                        unsigned short* __restrict__ BTile, unsigned short* __restrict__ W2T) {
    int n = blockIdx.x;            // 0..255
    int k = threadIdx.x;           // 0..255
    BTile[(size_t)(k >> 5) * 8192 + n * 32 + (k & 31)] = f2b(W1[k * 256 + n]);
    if (n < 48) {
        int half = k >> 7, cs = (k & 127) >> 3, ni = k & 7;
        int ck = half * 128 + ni * 16 + cs;
        W2T[n * 256 + k] = (n < 40) ? f2b(W2[ck * 40 + n]) : (unsigned short)0;
    }
}

// ---------------- GEMM1 (MFMA bf16, A+B LDS dbuf) -> permuted fp8 feat1 ----------------
__global__ __launch_bounds__(256) void gemm1_mfma(const float* __restrict__ A,
                                                  const unsigned short* __restrict__ BTile,
                                                  unsigned char* __restrict__ F8, int M) {
    __shared__ unsigned short Asm[2][64][40];
    __shared__ unsigned short Bsm[2][256][40];
    int t = threadIdx.x;
    int lane = t & 63, w = t >> 6;
    int wr = w >> 1, wc = w & 1;          // wave tile: 32 rows x 128 cols
    int m0 = blockIdx.x * 64;
    int rsub = lane & 15, koff = (lane >> 4) * 8;
    f32x4 acc[2][8] = {};

    // A staging: thread covers row t>>2, 8 f32 at col (t&3)*8
    int ar = t >> 2, ac = (t & 3) * 8;
    const float* ap = A + (size_t)(m0 + ar) * 256 + ac;
    bool aok = (m0 + ar) < M;
    // B staging: thread covers n = t, all 32 k (64B contiguous in BTile)
    const unsigned short* bp = BTile + (size_t)t * 32;

    float4 a0 = make_float4(0.f, 0.f, 0.f, 0.f), a1 = a0;
    if (aok) { a0 = *reinterpret_cast<const float4*>(ap); a1 = *reinterpret_cast<const float4*>(ap + 4); }
    uint4 b0 = *reinterpret_cast<const uint4*>(bp);
    uint4 b1 = *reinterpret_cast<const uint4*>(bp + 8);
    uint4 b2 = *reinterpret_cast<const uint4*>(bp + 16);
    uint4 b3 = *reinterpret_cast<const uint4*>(bp + 24);
    {
        short8 bb;
        bb[0] = (short)f2b(a0.x); bb[1] = (short)f2b(a0.y); bb[2] = (short)f2b(a0.z); bb[3] = (short)f2b(a0.w);
        bb[4] = (short)f2b(a1.x); bb[5] = (short)f2b(a1.y); bb[6] = (short)f2b(a1.z); bb[7] = (short)f2b(a1.w);
        *reinterpret_cast<short8*>(&Asm[0][ar][ac]) = bb;
        *reinterpret_cast<uint4*>(&Bsm[0][t][0])  = b0;
        *reinterpret_cast<uint4*>(&Bsm[0][t][8])  = b1;
        *reinterpret_cast<uint4*>(&Bsm[0][t][16]) = b2;
        *reinterpret_cast<uint4*>(&Bsm[0][t][24]) = b3;
    }
    __syncthreads();

    for (int kt = 0; kt < 8; ++kt) {
        if (kt < 7) {
            a0 = make_float4(0.f, 0.f, 0.f, 0.f); a1 = a0;
            if (aok) {
                const float* p = ap + (kt + 1) * 32;
                a0 = *reinterpret_cast<const float4*>(p);
                a1 = *reinterpret_cast<const float4*>(p + 4);
            }
            const unsigned short* nb = bp + (size_t)(kt + 1) * 8192;
            b0 = *reinterpret_cast<const uint4*>(nb);
            b1 = *reinterpret_cast<const uint4*>(nb + 8);
            b2 = *reinterpret_cast<const uint4*>(nb + 16);
            b3 = *reinterpret_cast<const uint4*>(nb + 24);
        }
        short8 a[2], b[8];
#pragma unroll
        for (int mi = 0; mi < 2; mi++)
            a[mi] = *reinterpret_cast<const short8*>(&Asm[kt & 1][wr * 32 + mi * 16 + rsub][koff]);
#pragma unroll
        for (int ni = 0; ni < 8; ni++)
            b[ni] = *reinterpret_cast<const short8*>(&Bsm[kt & 1][wc * 128 + ni * 16 + rsub][koff]);
#pragma unroll
        for (int mi = 0; mi < 2; mi++)
#pragma unroll
            for (int ni = 0; ni < 8; ni++)
                acc[mi][ni] = __builtin_amdgcn_mfma_f32_16x16x32_bf16(a[mi], b[ni], acc[mi][ni], 0, 0, 0);
        if (kt < 7) {
            int nb2 = (kt + 1) & 1;
            short8 bb;
            bb[0] = (short)f2b(a0.x); bb[1] = (short)f2b(a0.y); bb[2] = (short)f2b(a0.z); bb[3] = (short)f2b(a0.w);
            bb[4] = (short)f2b(a1.x); bb[5] = (short)f2b(a1.y); bb[6] = (short)f2b(a1.z); bb[7] = (short)f2b(a1.w);
            *reinterpret_cast<short8*>(&Asm[nb2][ar][ac]) = bb;
            *reinterpret_cast<uint4*>(&Bsm[nb2][t][0])  = b0;
            *reinterpret_cast<uint4*>(&Bsm[nb2][t][8])  = b1;
            *reinterpret_cast<uint4*>(&Bsm[nb2][t][16]) = b2;
            *reinterpret_cast<uint4*>(&Bsm[nb2][t][24]) = b3;
            __syncthreads();
        }
    }

    // epilogue: permuted layout -> lane's 8 values are 8 contiguous bytes
    int rgrp = (lane >> 4) * 4, csub = lane & 15;
#pragma unroll
    for (int mi = 0; mi < 2; mi++) {
#pragma unroll
        for (int i = 0; i < 4; i++) {
            int r = m0 + wr * 32 + mi * 16 + rgrp + i;
            if (r < M) {
                int d0 = __builtin_amdgcn_cvt_pk_fp8_f32(acc[mi][0][i], acc[mi][1][i], 0, false);
                d0 = __builtin_amdgcn_cvt_pk_fp8_f32(acc[mi][2][i], acc[mi][3][i], d0, true);
                int d1 = __builtin_amdgcn_cvt_pk_fp8_f32(acc[mi][4][i], acc[mi][5][i], 0, false);
                d1 = __builtin_amdgcn_cvt_pk_fp8_f32(acc[mi][6][i], acc[mi][7][i], d1, true);
                uint2 st; st.x = (unsigned)d0; st.y = (unsigned)d1;
                *reinterpret_cast<uint2*>(F8 + (size_t)r * 256 + wc * 128 + csub * 8) = st;
            }
        }
    }
}

// ---------------- el/er layer 1 from permuted fp8: 1 wave per node ------
__global__ __launch_bounds__(256) void elr1_k(const unsigned char* __restrict__ feat8,
                                              const float* __restrict__ al,
                                              const float* __restrict__ ar,
                                              float* __restrict__ el, float* __restrict__ er) {
    int wid = (blockIdx.x * blockDim.x + threadIdx.x) >> 6;
    int lane = threadIdx.x & 63;
    if (wid >= N_NODES) return;
    unsigned u = *reinterpret_cast<const unsigned*>(feat8 + (size_t)wid * 256 + 4 * lane);
    floatx2 lo = __builtin_amdgcn_cvt_pk_f32_fp8((int)u, false);
    floatx2 hi = __builtin_amdgcn_cvt_pk_f32_fp8((int)u, true);
    int csub = (lane & 31) >> 1;
    int h0 = (lane >> 5) * 4 + 2 * (lane & 1);
    float pl0 = lo.x * al[h0 * 32 + csub] + lo.y * al[h0 * 32 + 16 + csub];
    float pr0 = lo.x * ar[h0 * 32 + csub] + lo.y * ar[h0 * 32 + 16 + csub];
    float pl1 = hi.x * al[(h0 + 1) * 32 + csub] + hi.y * al[(h0 + 1) * 32 + 16 + csub];
    float pr1 = hi.x * ar[(h0 + 1) * 32 + csub] + hi.y * ar[(h0 + 1) * 32 + 16 + csub];
#pragma unroll
    for (int d = 2; d <= 16; d <<= 1) {
        pl0 += __shfl_xor(pl0, d); pr0 += __shfl_xor(pr0, d);
        pl1 += __shfl_xor(pl1, d); pr1 += __shfl_xor(pr1, d);
    }
    if (csub == 0) {
        el[wid * 8 + h0] = pl0; el[wid * 8 + h0 + 1] = pl1;
        er[wid * 8 + h0] = pr0; er[wid * 8 + h0 + 1] = pr1;
    }
}

// ---------------- GEMM2 (MFMA bf16) + fused el2/er2 ----------------
__global__ __launch_bounds__(256) void gemm2_mfma(const unsigned short* __restrict__ A,
                                                  const unsigned short* __restrict__ BT,
                                                  const float* __restrict__ al2,
                                                  const float* __restrict__ ar2,
                                                  unsigned short* __restrict__ C,
                                                  float* __restrict__ el2,
                                                  float* __restrict__ er2, int M) {
    __shared__ unsigned short Asm[2][64][40];
    int t = threadIdx.x;
    int lane = t & 63, w = t >> 6;        // wave tile: 16 rows x 48 cols
    int m0 = blockIdx.x * 64;
    int rsub = lane & 15, koff = (lane >> 4) * 8;
    f32x4 acc[3] = {};

    int r_t = t >> 2, c8 = (t & 3) * 8;
    const unsigned short* ap = A + (size_t)(m0 + r_t) * 256 + c8;
    bool arow_ok = (m0 + r_t) < M;

    uint4 s0 = make_uint4(0, 0, 0, 0);
    if (arow_ok) s0 = *reinterpret_cast<const uint4*>(ap);
    *reinterpret_cast<uint4*>(&Asm[0][r_t][c8]) = s0;
    __syncthreads();

    for (int kt = 0; kt < 8; ++kt) {
        if (kt < 7) {
            s0 = make_uint4(0, 0, 0, 0);
            if (arow_ok) s0 = *reinterpret_cast<const uint4*>(ap + (kt + 1) * 32);
        }
        short8 b[3], a;
#pragma unroll
        for (int ni = 0; ni < 3; ni++)
            b[ni] = *reinterpret_cast<const short8*>(BT + (size_t)(ni * 16 + rsub) * 256 + kt * 32 + koff);
        a = *reinterpret_cast<const short8*>(&Asm[kt & 1][w * 16 + rsub][koff]);
#pragma unroll
        for (int ni = 0; ni < 3; ni++)
            acc[ni] = __builtin_amdgcn_mfma_f32_16x16x32_bf16(a, b[ni], acc[ni], 0, 0, 0);
        if (kt < 7) {
            *reinterpret_cast<uint4*>(&Asm[(kt + 1) & 1][r_t][c8]) = s0;
            __syncthreads();
        }
    }

    int rgrp = (lane >> 4) * 4, csub = lane & 15;
    float alc[3], arc[3];
#pragma unroll
    for (int ni = 0; ni < 3; ni++) {
        int col = ni * 16 + csub;
        alc[ni] = (col < 40) ? al2[col] : 0.f;
        arc[ni] = (col < 40) ? ar2[col] : 0.f;
    }
#pragma unroll
    for (int i = 0; i < 4; i++) {
        int r = m0 + w * 16 + rgrp + i;
        float pl = acc[0][i] * alc[0] + acc[1][i] * alc[1] + acc[2][i] * alc[2];
        float pr = acc[0][i] * arc[0] + acc[1][i] * arc[1] + acc[2][i] * arc[2];
        pl += __shfl_xor(pl, 1); pl += __shfl_xor(pl, 2);
        pl += __shfl_xor(pl, 4); pl += __shfl_xor(pl, 8);
        pr += __shfl_xor(pr, 1); pr += __shfl_xor(pr, 2);
        pr += __shfl_xor(pr, 4); pr += __shfl_xor(pr, 8);
        if (r < M) {
#pragma unroll
            for (int ni = 0; ni < 3; ni++)
                C[(size_t)r * 64 + ni * 16 + csub] = f2b(acc[ni][i]);
            C[(size_t)r * 64 + 48 + csub] = 0;   // zero pad cols 48..63
            if (csub == 0) { el2[r] = pl; er2[r] = pr; }
        }
    }
}

// ---------------- CSR build: histogram, scan, scatter ----------------
__global__ void hist_k(const int* __restrict__ dst, int* __restrict__ deg) {
    int e = blockIdx.x * blockDim.x + threadIdx.x;
    if (e < N_EDGES) atomicAdd(&deg[dst[e]], 1);
}

__global__ void scan1_k(const int* __restrict__ deg, int* __restrict__ offs,
                        int* __restrict__ bsum, int n) {
    __shared__ int s[256];
    int tid = threadIdx.x;
    int i = blockIdx.x * 256 + tid;
    int v = (i < n) ? deg[i] : 0;
    s[tid] = v;
    __syncthreads();
    for (int d = 1; d < 256; d <<= 1) {
        int t = (tid >= d) ? s[tid - d] : 0;
        __syncthreads();
        s[tid] += t;
        __syncthreads();
    }
    if (i < n) offs[i] = s[tid] - v;
    if (tid == 255) bsum[blockIdx.x] = s[255];
}

__global__ void scan2_k(int* __restrict__ bsum, int nb) {
    __shared__ int s[256];
    int tid = threadIdx.x;
    int v = (tid < nb) ? bsum[tid] : 0;
    s[tid] = v;
    __syncthreads();
    for (int d = 1; d < 256; d <<= 1) {
        int t = (tid >= d) ? s[tid - d] : 0;
        __syncthreads();
        s[tid] += t;
        __syncthreads();
    }
    if (tid < nb) bsum[tid] = s[tid] - v;
}

__global__ void scan3_k(int* __restrict__ offs, const int* __restrict__ bsum,
                        int* __restrict__ cur, int n) {
    int i = blockIdx.x * 256 + threadIdx.x;
    if (i < n) { offs[i] += bsum[blockIdx.x]; cur[i] = 0; }
    if (i == 0) offs[n] = N_EDGES;
}

__global__ void scatter_k(const int* __restrict__ src, const int* __restrict__ dst,
                          const int* __restrict__ offs, int* __restrict__ cur,
                          int* __restrict__ ssorted) {
    int e = blockIdx.x * blockDim.x + threadIdx.x;
    if (e < N_EDGES) {
        int d = dst[e];
        int p = atomicAdd(&cur[d], 1);
        ssorted[offs[d] + p] = src[e];
    }
}

// ---------------- layer-1 attention aggregate (permuted fp8 gather) ------
__global__ __launch_bounds__(256) void agg1_k(const unsigned char* __restrict__ feat8,
                                              const float* __restrict__ el,
                                              const float* __restrict__ er,
                                              const int* __restrict__ offs,
                                              const int* __restrict__ ssorted,
                                              unsigned short* __restrict__ h1) {
    __shared__ float sa[4][CAP1 * 8];
    __shared__ int   ss[4][CAP1];
    int t = threadIdx.x;
    int wv = t >> 6, lane = t & 63;
    int n = blockIdx.x * 4 + wv;
    if (n >= N_NODES) return;
    int beg = offs[n];
    int deg = offs[n + 1] - beg;
    int eloc = lane >> 3, h = lane & 7;
    int h0 = (lane >> 5) * 4 + 2 * (lane & 1);
    float er_h = er[n * 8 + h];

    float acc0 = 0.f, acc1 = 0.f, acc2 = 0.f, acc3 = 0.f;

    if (deg <= CAP1) {
        float ssum = 0.f;
        for (int c0 = 0; c0 < deg; c0 += 8) {
            int idx = c0 + eloc;
            bool act = idx < deg;
            float ee = 0.f;
            if (act) {
                int s = ssorted[beg + idx];
                if (h == 0) ss[wv][idx] = s;
                ee = __expf(leaky(el[s * 8 + h] + er_h));
                sa[wv][idx * 8 + h] = ee;
            }
            float sc = ee;
            sc += __shfl_xor(sc, 8);
            sc += __shfl_xor(sc, 16);
            sc += __shfl_xor(sc, 32);
            ssum += sc;
        }
        float inv = 1.f / ssum;
        float iv0 = __shfl(inv, h0), iv1 = __shfl(inv, h0 + 1);
        asm volatile("s_waitcnt lgkmcnt(0)" ::: "memory");
        for (int c0 = 0; c0 < deg; c0 += 16) {
            int nr = deg - c0; if (nr > 16) nr = 16;
            unsigned u[16]; float2 av[16];
#pragma unroll
            for (int j = 0; j < 16; j++) {
                if (j < nr) {
                    int sj = ss[wv][c0 + j];
                    av[j] = *reinterpret_cast<const float2*>(&sa[wv][(c0 + j) * 8 + h0]);
                    u[j] = *reinterpret_cast<const unsigned*>(feat8 + (size_t)sj * 256 + 4 * lane);
                }
            }
#pragma unroll
            for (int j = 0; j < 16; j++) {
                if (j < nr) {
                    float w0 = av[j].x * iv0, w1 = av[j].y * iv1;
                    floatx2 lo = __builtin_amdgcn_cvt_pk_f32_fp8((int)u[j], false);
                    floatx2 hi = __builtin_amdgcn_cvt_pk_f32_fp8((int)u[j], true);
                    acc0 += w0 * lo.x;
                    acc1 += w0 * lo.y;
                    acc2 += w1 * hi.x;
                    acc3 += w1 * hi.y;
                }
            }
        }
    } else {
        float ssum = 0.f;
        for (int c0 = 0; c0 < deg; c0 += 8) {
            bool act = (c0 + eloc) < deg;
            float ee = 0.f;
            if (act) {
                int s = ssorted[beg + c0 + eloc];
                ee = __expf(leaky(el[s * 8 + h] + er_h));
            }
            float sc = ee;
            sc += __shfl_xor(sc, 8);
            sc += __shfl_xor(sc, 16);
            sc += __shfl_xor(sc, 32);
            ssum += sc;
        }
        float inv = 1.f / ssum;
        float iv0 = __shfl(inv, h0), iv1 = __shfl(inv, h0 + 1);
        for (int c0 = 0; c0 < deg; c0 += 8) {
            int nr = deg - c0; if (nr > 8) nr = 8;
            int s = 0; float a = 0.f;
            if (eloc < nr) {
                s = ssorted[beg + c0 + eloc];
                a = __expf(leaky(el[s * 8 + h] + er_h));
            }
#pragma unroll
            for (int j = 0; j < 8; j++) {
                if (j < nr) {
                    int   sj = __shfl(s, j * 8);
                    float a0 = __shfl(a, j * 8 + h0) * iv0;
                    float a1 = __shfl(a, j * 8 + h0 + 1) * iv1;
                    unsigned u = *reinterpret_cast<const unsigned*>(feat8 + (size_t)sj * 256 + 4 * lane);
                    floatx2 lo = __builtin_amdgcn_cvt_pk_f32_fp8((int)u, false);
                    floatx2 hi = __builtin_amdgcn_cvt_pk_f32_fp8((int)u, true);
                    acc0 += a0 * lo.x;
                    acc1 += a0 * lo.y;
                    acc2 += a1 * hi.x;
                    acc3 += a1 * hi.y;
                }
            }
        }
    }
    ushort4 o;
    o.x = f2b(fmaxf(acc0, 0.f));
    o.y = f2b(fmaxf(acc1, 0.f));
    o.z = f2b(fmaxf(acc2, 0.f));
    o.w = f2b(fmaxf(acc3, 0.f));
    *reinterpret_cast<ushort4*>(h1 + (size_t)n * 256 + 4 * lane) = o;
}

// ---------------- layer-2 attention aggregate + log_softmax ----------------
__global__ __launch_bounds__(256) void agg2_k(const unsigned short* __restrict__ feat2p,
                                              const float* __restrict__ el2,
                                              const float* __restrict__ er2,
                                              const int* __restrict__ offs,
                                              const int* __restrict__ ssorted,
                                              float* __restrict__ out) {
    __shared__ float sa[4][CAP2];
    __shared__ int   ss[4][CAP2];
    int t = threadIdx.x;
    int wv = t >> 6, lane = t & 63;
    int n = blockIdx.x * 4 + wv;
    if (n >= N_NODES) return;
    int beg = offs[n];
    int deg = offs[n + 1] - beg;
    float ern = er2[n];
    int eloc = lane >> 3, c8 = lane & 7;

    float acc[8] = {};
    if (deg <= CAP2) {
        float ssum = 0.f;
        for (int c0 = 0; c0 < deg; c0 += 64) {
            int idx = c0 + lane;
            bool act = idx < deg;
            float ee = 0.f;
            if (act) {
                int s = ssorted[beg + idx];
                ss[wv][idx] = s;
                ee = __expf(leaky(el2[s] + ern));
                sa[wv][idx] = ee;
            }
            float sc = ee;
#pragma unroll
            for (int d = 1; d < 64; d <<= 1) sc += __shfl_xor(sc, d);
            ssum += sc;
        }
        float inv = 1.f / ssum;
        asm volatile("s_waitcnt lgkmcnt(0)" ::: "memory");
        for (int c0 = 0; c0 < deg; c0 += 16) {
            int i0 = c0 + eloc, i1 = c0 + 8 + eloc;
            uint4 v0 = make_uint4(0, 0, 0, 0), v1 = make_uint4(0, 0, 0, 0);
            float w0 = 0.f, w1 = 0.f;
            if (i0 < deg) {
                int s = ss[wv][i0]; w0 = sa[wv][i0] * inv;
                v0 = *reinterpret_cast<const uint4*>(feat2p + (size_t)s * 64 + c8 * 8);
            }
            if (i1 < deg) {
                int s = ss[wv][i1]; w1 = sa[wv][i1] * inv;
                v1 = *reinterpret_cast<const uint4*>(feat2p + (size_t)s * 64 + c8 * 8);
            }
            const unsigned short* p0 = reinterpret_cast<const unsigned short*>(&v0);
            const unsigned short* p1 = reinterpret_cast<const unsigned short*>(&v1);
#pragma unroll
            for (int i = 0; i < 8; i++) acc[i] += w0 * b2f(p0[i]) + w1 * b2f(p1[i]);
        }
    } else {
        float ssum = 0.f;
        for (int c0 = 0; c0 < deg; c0 += 64) {
            bool act = (c0 + lane) < deg;
            float ee = 0.f;
            if (act) ee = __expf(leaky(el2[ssorted[beg + c0 + lane]] + ern));
            float sc = ee;
#pragma unroll
            for (int d = 1; d < 64; d <<= 1) sc += __shfl_xor(sc, d);
            ssum += sc;
        }
        float inv = 1.f / ssum;
        for (int c0 = 0; c0 < deg; c0 += 8) {
            int nr = deg - c0; if (nr > 8) nr = 8;
            if (eloc < nr) {
                int s = ssorted[beg + c0 + eloc];
                float a = __expf(leaky(el2[s] + ern)) * inv;
                uint4 v = *reinterpret_cast<const uint4*>(feat2p + (size_t)s * 64 + c8 * 8);
                const unsigned short* pv = reinterpret_cast<const unsigned short*>(&v);
#pragma unroll
                for (int i = 0; i < 8; i++) acc[i] += a * b2f(pv[i]);
            }
        }
    }
#pragma unroll
    for (int i = 0; i < 8; i++) {
        acc[i] += __shfl_xor(acc[i], 8);
        acc[i] += __shfl_xor(acc[i], 16);
        acc[i] += __shfl_xor(acc[i], 32);
    }
    float lmax = -INFINITY;
    if (c8 < 5) {
#pragma unroll
        for (int i = 0; i < 8; i++) lmax = fmaxf(lmax, acc[i]);
    }
    lmax = fmaxf(lmax, __shfl_xor(lmax, 1));
    lmax = fmaxf(lmax, __shfl_xor(lmax, 2));
    lmax = fmaxf(lmax, __shfl_xor(lmax, 4));
    float lsum = 0.f;
    if (c8 < 5) {
#pragma unroll
        for (int i = 0; i < 8; i++) lsum += __expf(acc[i] - lmax);
    }
    lsum += __shfl_xor(lsum, 1);
    lsum += __shfl_xor(lsum, 2);
    lsum += __shfl_xor(lsum, 4);
    if (eloc == 0 && c8 < 5) {
        float lg = __logf(lsum);
        float* o = out + (size_t)n * 40 + c8 * 8;
#pragma unroll
        for (int i = 0; i < 8; i++) o[i] = acc[i] - lmax - lg;
    }
}

extern "C" void kernel_launch(void* const* d_in, const int* in_sizes, int n_in,
                              void* d_out, int out_size, void* d_ws, size_t ws_size,
                              hipStream_t stream) {
    (void)in_sizes; (void)n_in; (void)out_size; (void)ws_size;
    const float* x   = (const float*)d_in[0];
    const int*   src = (const int*)d_in[1];
    const int*   dst = (const int*)d_in[2];
    const float* W1  = (const float*)d_in[3];
    const float* al1 = (const float*)d_in[4];
    const float* ar1 = (const float*)d_in[5];
    const float* W2  = (const float*)d_in[6];
    const float* al2 = (const float*)d_in[7];
    const float* ar2 = (const float*)d_in[8];
    float* out = (float*)d_out;

    char* ws = (char*)d_ws;
    size_t off = 0;
    auto alloc = [&](size_t bytes) {
        void* p = ws + off;
        off += (bytes + 255) & ~(size_t)255;
        return p;
    };
    unsigned short* w1tile = (unsigned short*)alloc((size_t)8 * 256 * 32 * 2);
    unsigned short* w2t    = (unsigned short*)alloc((size_t)48 * 256 * 2);
    unsigned char*  feat8  = (unsigned char*)alloc((size_t)N_NODES * 256);
    unsigned short* h1p    = (unsigned short*)alloc((size_t)N_NODES * 256 * 2);
    unsigned short* feat2p = (unsigned short*)alloc((size_t)N_NODES * 64 * 2);
    float* el1   = (float*)alloc((size_t)N_NODES * 8 * 4);
    float* er1   = (float*)alloc((size_t)N_NODES * 8 * 4);
    float* el2   = (float*)alloc((size_t)N_NODES * 4);
    float* er2   = (float*)alloc((size_t)N_NODES * 4);
    int* deg     = (int*)alloc((size_t)N_NODES * 4);
    int* offs    = (int*)alloc((size_t)(N_NODES + 1) * 4);
    int* cur     = (int*)alloc((size_t)N_NODES * 4);
    int* bsum    = (int*)alloc(1024 * 4);
    int* ssorted = (int*)alloc((size_t)N_EDGES * 4);

    hipMemsetAsync(deg, 0, (size_t)N_NODES * 4, stream);

    cvt_w_k<<<256, 256, 0, stream>>>(W1, W2, w1tile, w2t);

    // CSR by dst
    hist_k<<<(N_EDGES + 255) / 256, 256, 0, stream>>>(dst, deg);
    int nb = (N_NODES + 255) / 256;
    scan1_k<<<nb, 256, 0, stream>>>(deg, offs, bsum, N_NODES);
    scan2_k<<<1, 256, 0, stream>>>(bsum, nb);
    scan3_k<<<nb, 256, 0, stream>>>(offs, bsum, cur, N_NODES);
    scatter_k<<<(N_EDGES + 255) / 256, 256, 0, stream>>>(src, dst, offs, cur, ssorted);

    // layer 1
    gemm1_mfma<<<(N_NODES + 63) / 64, 256, 0, stream>>>(x, w1tile, feat8, N_NODES);
    elr1_k<<<(N_NODES * 64 + 255) / 256, 256, 0, stream>>>(feat8, al1, ar1, el1, er1);
    agg1_k<<<(N_NODES + 3) / 4, 256, 0, stream>>>(feat8, el1, er1, offs, ssorted, h1p);

    // layer 2
    gemm2_mfma<<<(N_NODES + 63) / 64, 256, 0, stream>>>(h1p, w2t, al2, ar2, feat2p, el2, er2, N_NODES);
    agg2_k<<<(N_NODES + 3) / 4, 256, 0, stream>>>(feat2p, el2, er2, offs, ssorted, out);
}